// Round 12
// baseline (932.767 us; speedup 1.0000x reference)
//
#include <hip/hip_runtime.h>
#include <hip/hip_bf16.h>
#include <math.h>

typedef __hip_bfloat16 bf16;
typedef __attribute__((ext_vector_type(8))) short s8v;
typedef __attribute__((ext_vector_type(4))) short s4v;
typedef __attribute__((ext_vector_type(4))) float f32x4;
typedef __attribute__((ext_vector_type(2))) _Float16 h2;

// ---------------- problem constants ----------------
constexpr int CB   = 2;            // batch
constexpr int CH   = 224, CW = 224;
constexpr int NHW  = 56;           // H/WS
constexpr int NPATCH = CB * NHW * NHW;   // 6272
constexpr int TOKPB  = CH * CW;          // 50176 tokens per batch
constexpr int MTOK   = CB * TOKPB;       // 100352 rows
constexpr size_t SECSZ = 19267584;       // elems per q/k/v f16 section

// ---------------- ws layout (BYTE offsets) ----------------
constexpr size_t B_T0  = 0;                         // 19267584 bf16
constexpr size_t B_P2  = B_T0 + 38535168;           // QF/KF/VF f16 (3x38.5MB); later HID bf16
constexpr size_t B_P3  = B_P2 + 115605504;          // 19267584 bf16 (ATT -> OCAB)
constexpr size_t B_P4  = B_P3 + 38535168;           // 19267584 bf16 (OMID -> C2)
constexpr size_t B_WF1 = B_P4 + 38535168;           // conv1 frag weights
constexpr size_t B_WF2 = B_WF1 + 1327104;           // conv2 frag weights
constexpr size_t B_W3F = B_WF2 + 1327104;           // conv3 1x1 frag weights
constexpr size_t B_WQ  = B_W3F + 147456;            // qkv_w frag
constexpr size_t B_WP  = B_WQ + 221184;             // proj_w frag
constexpr size_t B_WG1 = B_WP + 73728;              // fc1_w frag
constexpr size_t B_WG2 = B_WG1 + 147456;            // fc2_w frag
constexpr size_t WS_NEEDED = B_WG2 + 147456;        // 234,602,496 B

// ---------------- type helpers ----------------
__device__ __forceinline__ float ldf(const float* p) { return *p; }
__device__ __forceinline__ float ldf(const bf16* p)  { return __bfloat162float(*p); }
__device__ __forceinline__ void  stf(float* p, float v) { *p = v; }
__device__ __forceinline__ void  stf(bf16* p, float v)  { *p = __float2bfloat16(v); }
__device__ __forceinline__ unsigned short f2bf(float f) {
    unsigned u = __builtin_bit_cast(unsigned, f);
    unsigned r = (u + 0x7fffu + ((u >> 16) & 1u)) >> 16;
    return (unsigned short)r;
}
__device__ __forceinline__ float bf2f(short s) {
    unsigned u = ((unsigned)(unsigned short)s) << 16;
    return __builtin_bit_cast(float, u);
}

// ---------------- weight pre-pack kernels ----------------
__global__ void build_wf_kernel(const float* __restrict__ w, short* __restrict__ wf) {
    int o = blockIdx.x * 256 + threadIdx.x;
    if (o >= 331776) return;
    int within = o & 511, frag = o >> 9;
    int l = within >> 3, j = within & 7;
    int nt = frag % 12, t2 = frag / 12, ks = t2 % 6, tap = t2 / 6;
    int co = nt * 16 + (l & 15);
    int ci = ks * 32 + (l >> 4) * 8 + j;
    wf[o] = (short)f2bf(w[(co * 192 + ci) * 9 + tap]);
}
__global__ void build_wgemm_kernel(const float* __restrict__ w, short* __restrict__ wf,
                                   int K, int N) {
    int o = blockIdx.x * 256 + threadIdx.x;
    if (o >= K * N) return;
    int j = o & 7, l = (o >> 3) & 63, f = o >> 9;
    int ntiles = N >> 4;
    int kt = f / ntiles, nt = f % ntiles;
    int k = kt * 32 + (l >> 4) * 8 + j;
    int col = nt * 16 + (l & 15);
    wf[o] = (short)f2bf(w[(size_t)k * N + col]);
}
__global__ void build_w3f_kernel(const float* __restrict__ w, short* __restrict__ wf) {
    int o = blockIdx.x * 256 + threadIdx.x;
    if (o >= 36864) return;
    int j = o & 7, l = (o >> 3) & 63, f = o >> 9;   // f = kt*12 + ct
    int kt = f / 12, ct = f % 12;
    int co = ct * 16 + (l & 15);
    int ci = kt * 32 + (l >> 4) * 8 + j;
    wf[o] = (short)f2bf(w[co * 192 + ci]);
}

// ---------------- conv3x3 (4x4 patches) + groupnorm (+silu), MFMA ----------------
// 4 patches/block, 256 threads. Wave w owns PATCH w x all 12 nt-tiles:
//  - all 4 waves load identical B-fragments -> L1 dedup of L2 traffic
//  - 1 A ds_read per (tap,ks) instead of 4
//  - GN stats wave-local (butterfly broadcast), no LDS atomics / stats barriers
template <bool FIRST>
__global__ __launch_bounds__(256, 4) void conv_mfma_kernel(
    const void* __restrict__ srcv, const short* __restrict__ wf,
    const float* __restrict__ bias, const float* __restrict__ gng,
    const float* __restrict__ gnb, bf16* __restrict__ dst)
{
    __shared__ short xs[13056];          // 4 patches * 17 rows * 384B (row 16 = zeros), swizzled
    const int tid  = threadIdx.x;
    const int lane = tid & 63, wid = tid >> 6;
    const int n0   = blockIdx.x * 4;

    for (int u = tid; u < 4 * 192; u += 256) {       // zero rows
        int q = u / 192;
        xs[q * 3264 + 3072 + (u % 192)] = 0;
    }

    if constexpr (FIRST) {
        const float4* sp = (const float4*)((const float*)srcv + (size_t)n0 * 3072);
        #pragma unroll
        for (int u = 0; u < 12; ++u) {
            int idx = u * 256 + tid;                 // float4 index, 3072 total
            float4 v = sp[idx];
            int q = idx / 768;
            int li = (idx % 768) * 4;                // li = ci*16 + p
            int ci = li >> 4, p0 = li & 15;
            float vv[4] = { v.x, v.y, v.z, v.w };
            #pragma unroll
            for (int k = 0; k < 4; ++k) {
                int row = p0 + k;
                int ba = q * 6528 + ((row * 384 + ci * 2) ^ ((row & 7) << 4));
                *(short*)((char*)xs + ba) = (short)f2bf(vv[k]);
            }
        }
    } else {
        const s8v* sp8 = (const s8v*)((const bf16*)srcv + (size_t)n0 * 3072);
        #pragma unroll
        for (int u = 0; u < 6; ++u) {
            int li = u * 256 + tid;                  // 1536 s8v units
            int r = li / 24, ch = li % 24;
            int q = r >> 4, rl = r & 15;
            s8v val = sp8[li];
            int ba = q * 6528 + ((rl * 384 + ch * 16) ^ ((rl & 7) << 4));
            *(s8v*)((char*)xs + ba) = val;
        }
    }
    __syncthreads();

    const int q   = wid;             // this wave's patch
    const int cl  = lane & 15;       // A-row (= output pos) / C-col (= co within tile)
    const int kg  = lane >> 4;
    f32x4 acc[12];
    #pragma unroll
    for (int t = 0; t < 12; ++t) {
        float bv = bias[t * 16 + cl];
        acc[t] = (f32x4){ bv, bv, bv, bv };
    }

    const int pi = cl >> 2, pj = cl & 3;
    const s8v* wf8 = (const s8v*)wf;

    for (int tap = 0; tap < 9; ++tap) {
        const int di = tap / 3, dj = tap % 3;
        const int ii = pi + di - 1, jj = pj + dj - 1;
        const bool valid = (ii >= 0 && ii < 4 && jj >= 0 && jj < 4);
        const int nr  = valid ? (ii * 4 + jj) : 16;   // row 16 = zero row
        const int rb  = nr * 384;
        const int swz = (nr & 7) << 4;
        #pragma unroll
        for (int ks = 0; ks < 6; ++ks) {
            const s8v* bp = wf8 + (size_t)((tap * 6 + ks) * 12) * 64 + lane;
            const int inner = (rb + ks * 64 + kg * 16) ^ swz;
            s8v a = *(const s8v*)((const char*)xs + q * 6528 + inner);
            #pragma unroll
            for (int t = 0; t < 12; ++t) {
                acc[t] = __builtin_amdgcn_mfma_f32_16x16x32_bf16(a, bp[t * 64], acc[t], 0, 0, 0);
            }
        }
    }

    // wave-local GN stats: group g spans acc[2g], acc[2g+1] (16 pos x 32 co = 512 vals)
    float mu6[6], rs6[6];
    #pragma unroll
    for (int g = 0; g < 6; ++g) {
        f32x4 A0 = acc[2 * g], A1 = acc[2 * g + 1];
        float s  = A0[0] + A0[1] + A0[2] + A0[3] + A1[0] + A1[1] + A1[2] + A1[3];
        float s2 = A0[0]*A0[0] + A0[1]*A0[1] + A0[2]*A0[2] + A0[3]*A0[3]
                 + A1[0]*A1[0] + A1[1]*A1[1] + A1[2]*A1[2] + A1[3]*A1[3];
        #pragma unroll
        for (int off = 32; off; off >>= 1) { s += __shfl_xor(s, off); s2 += __shfl_xor(s2, off); }
        float mu  = s * (1.f / 512.f);
        float var = s2 * (1.f / 512.f) - mu * mu;
        mu6[g] = mu; rs6[g] = rsqrtf(var + 1e-5f);
    }
    __syncthreads();                 // all MFMA reads of xs done; safe to overwrite

    if constexpr (FIRST) {
        // normalize + SiLU -> swizzled LDS [64 tok][192 co], then coalesced 16B stores
        #pragma unroll
        for (int t = 0; t < 12; ++t) {
            const int co = t * 16 + cl, g = t >> 1;
            const float gg = gng[co], gb = gnb[co];
            const float mu = mu6[g], rs = rs6[g];
            #pragma unroll
            for (int r = 0; r < 4; ++r) {
                float v = (acc[t][r] - mu) * rs * gg + gb;
                v = v / (1.f + __expf(-v));      // silu (fast exp)
                int row = q * 16 + kg * 4 + r;
                int ba = (row * 384 + co * 2) ^ ((row & 7) << 4);
                *(short*)((char*)xs + ba) = (short)f2bf(v);
            }
        }
        __syncthreads();
        bf16* dp = dst + (size_t)n0 * 3072;          // token-major [tok][192], contiguous block
        #pragma unroll
        for (int u = 0; u < 6; ++u) {
            int li = u * 256 + tid;                  // 1536 s8v units
            int row = li / 24, g2 = li % 24;
            int ba = (row * 384 + g2 * 16) ^ ((row & 7) << 4);
            s8v val = *(const s8v*)((const char*)xs + ba);
            *(s8v*)(dp + (size_t)row * 192 + g2 * 8) = val;
        }
    } else {
        #pragma unroll
        for (int t = 0; t < 12; ++t) {
            const int co = t * 16 + cl, g = t >> 1;
            const float gg = gng[co], gb = gnb[co];
            const float mu = mu6[g], rs = rs6[g];
            #pragma unroll
            for (int r = 0; r < 4; ++r) {
                float v = (acc[t][r] - mu) * rs * gg + gb;
                xs[q * 3072 + co * 16 + kg * 4 + r] = (short)f2bf(v);
            }
        }
        __syncthreads();
        s4v* dp = (s4v*)(dst + (size_t)n0 * 3072);
        const s4v* sps = (const s4v*)xs;
        #pragma unroll
        for (int u = 0; u < 12; ++u) {
            dp[u * 256 + tid] = sps[u * 256 + tid];
        }
    }
}

// ---------------- MFMA GEMM, single-pass over an N-range, LDS-transpose epilogue ----
template <bool RES, bool GELU_ACT, bool LN, bool QKVOUT, int NKT>
__global__ __launch_bounds__(256) void gemm_mfma_kernel(
    const bf16* __restrict__ A, const short* __restrict__ wfb,
    const float* __restrict__ bias, const bf16* __restrict__ res,
    void* __restrict__ out, int N,
    const float* __restrict__ lng, const float* __restrict__ lnb)
{
    __shared__ short ls[8192];           // [128 rows][64 cols] 2B, XOR-swizzled
    const int tid = threadIdx.x, lane = tid & 63, wid = tid >> 6;
    const int m0 = blockIdx.x * 128;
    const int cl = lane & 15, kg = lane >> 4;
    constexpr int K = NKT * 32;
    const int ntiles = N >> 4;
    const int ntsec = ntiles / gridDim.y;
    const int ntbeg = blockIdx.y * ntsec;

    // load this thread's two A-rows (rows r0, r0+16) as fragments, once
    s8v af0[NKT], af1[NKT];
    const int r0 = m0 + wid * 32 + cl;
    #pragma unroll
    for (int kt = 0; kt < NKT; ++kt) {
        af0[kt] = *(const s8v*)(A + (size_t)r0 * K + kt * 32 + kg * 8);
        af1[kt] = *(const s8v*)(A + (size_t)(r0 + 16) * K + kt * 32 + kg * 8);
    }
    if constexpr (LN) {
        static_assert(!LN || NKT == 6, "LN requires K==192");
        #pragma unroll
        for (int r = 0; r < 2; ++r) {
            s8v* af = r ? af1 : af0;
            float s = 0.f, s2 = 0.f;
            #pragma unroll
            for (int kt = 0; kt < NKT; ++kt)
                #pragma unroll
                for (int j = 0; j < 8; ++j) {
                    float v = bf2f(af[kt][j]);
                    s += v; s2 += v * v;
                }
            s  += __shfl_xor(s, 16);  s2 += __shfl_xor(s2, 16);
            s  += __shfl_xor(s, 32);  s2 += __shfl_xor(s2, 32);
            const float mu = s * (1.f / 192.f);
            const float rs = rsqrtf(s2 * (1.f / 192.f) - mu * mu + 1e-5f);
            #pragma unroll
            for (int kt = 0; kt < NKT; ++kt) {
                const float* gp = lng + kt * 32 + kg * 8;
                const float* bp = lnb + kt * 32 + kg * 8;
                #pragma unroll
                for (int j = 0; j < 8; ++j) {
                    float v = (bf2f(af[kt][j]) - mu) * rs * gp[j] + bp[j];
                    af[kt][j] = (short)f2bf(v);
                }
            }
        }
    }

    const s8v* wf8 = (const s8v*)wfb;
    for (int nt0 = ntbeg; nt0 < ntbeg + ntsec; nt0 += 4) {
        const int n0 = nt0 * 16;
        f32x4 acc[2][4];
        #pragma unroll
        for (int nf = 0; nf < 4; ++nf) {
            float bv = bias[n0 + nf * 16 + cl];
            acc[0][nf] = (f32x4){ bv, bv, bv, bv };
            acc[1][nf] = (f32x4){ bv, bv, bv, bv };
        }
        #pragma unroll
        for (int kt = 0; kt < NKT; ++kt) {
            #pragma unroll
            for (int nf = 0; nf < 4; ++nf) {
                s8v b = wf8[(size_t)(kt * ntiles + nt0 + nf) * 64 + lane];
                acc[0][nf] = __builtin_amdgcn_mfma_f32_16x16x32_bf16(af0[kt], b, acc[0][nf], 0, 0, 0);
                acc[1][nf] = __builtin_amdgcn_mfma_f32_16x16x32_bf16(af1[kt], b, acc[1][nf], 0, 0, 0);
            }
        }

        // ---- epilogue: acc -> LDS (2B, swizzled) -> 16B coalesced stores ----
        __syncthreads();                 // previous chunk's readback done
        #pragma unroll
        for (int rf = 0; rf < 2; ++rf) {
            #pragma unroll
            for (int nf = 0; nf < 4; ++nf) {
                const int lcol = nf * 16 + cl;
                #pragma unroll
                for (int r = 0; r < 4; ++r) {
                    const int lrow = wid * 32 + rf * 16 + kg * 4 + r;
                    float v = acc[rf][nf][r];
                    if (GELU_ACT) v = 0.5f * v * (1.f + erff(v * 0.70710678118f));
                    short sv;
                    if constexpr (QKVOUT) sv = __builtin_bit_cast(short, (_Float16)v);
                    else                  sv = (short)f2bf(v);
                    int ba = (lrow * 128 + lcol * 2) ^ ((lrow & 7) << 4);
                    *(short*)((char*)ls + ba) = sv;
                }
            }
        }
        __syncthreads();
        #pragma unroll
        for (int p = 0; p < 4; ++p) {
            const int lrow = p * 32 + (tid >> 3);
            const int g = tid & 7;
            int ba = (lrow * 128 + g * 16) ^ ((lrow & 7) << 4);
            s8v val = *(const s8v*)((const char*)ls + ba);
            const int row = m0 + lrow;
            const int col0 = n0 + g * 8;
            if constexpr (QKVOUT) {
                const int sec = n0 / 192;        // 64-col chunk never crosses a section
                const int c0 = col0 - sec * 192, h = c0 >> 5, d0 = c0 & 31;
                const int bb2 = row / TOKPB, t = row - bb2 * TOKPB;
                *(s8v*)((_Float16*)out + (size_t)sec * SECSZ +
                        ((size_t)(bb2 * 6 + h) * TOKPB + t) * 32 + d0) = val;
            } else if constexpr (RES) {
                s8v rv = *(const s8v*)(res + (size_t)row * N + col0);
                s8v ov;
                #pragma unroll
                for (int e = 0; e < 8; ++e) ov[e] = (short)f2bf(bf2f(val[e]) + bf2f(rv[e]));
                *(s8v*)((bf16*)out + (size_t)row * N + col0) = ov;
            } else {
                *(s8v*)((bf16*)out + (size_t)row * N + col0) = val;
            }
        }
    }
}

// ---------------- overlapping-window attention (f16 head-major inputs) ----------------
constexpr int HSTR = 1160;   // per-head LDS stride in shorts (36*32 + 8 pad)
__global__ __launch_bounds__(128) void attn_kernel(
    const _Float16* __restrict__ qf, const float* __restrict__ rpb,
    bf16* __restrict__ out)
{
    __shared__ short kh[6 * HSTR];
    __shared__ short vh[6 * HSTR];
    const int w = blockIdx.x;
    const int b = w / (NHW * NHW), wi = w % (NHW * NHW);
    const int nhi = wi / NHW, nwi = wi % NHW;
    const int tid = threadIdx.x;
    const int r0 = nhi * 4 - 1, c0 = nwi * 4 - 1;
    const _Float16* kfb = qf + SECSZ;
    const _Float16* vfb = qf + 2 * SECSZ;

    // stage K and V: 2*864 units of 16B, pure copy (no conversion)
    #pragma unroll
    for (int it = 0; it < 14; ++it) {
        int v = tid + it * 128;
        if (v < 1728) {
            int kv = v >= 864 ? 1 : 0;
            int u = v - kv * 864;
            int h = u / 144, rem = u % 144, kj = rem >> 2, d0 = (rem & 3) * 8;
            int rr = r0 + kj / 6, cc = c0 + kj % 6;
            s8v val = { 0, 0, 0, 0, 0, 0, 0, 0 };
            if (rr >= 0 && rr < CH && cc >= 0 && cc < CW) {
                const _Float16* src = kv ? vfb : kfb;
                val = *(const s8v*)(src + ((size_t)(b * 6 + h) * TOKPB + rr * CW + cc) * 32 + d0);
            }
            short* dst = kv ? vh : kh;
            *(s8v*)(dst + h * HSTR + kj * 32 + d0) = val;
        }
    }
    __syncthreads();

    if (tid < 96) {
        const int h = tid >> 4, qi = tid & 15;
        const int qr = nhi * 4 + (qi >> 2), qc = nwi * 4 + (qi & 3);
        const _Float16* qp = qf + ((size_t)(b * 6 + h) * TOKPB + qr * CW + qc) * 32;
        h2 qh[16];
        #pragma unroll
        for (int u = 0; u < 4; ++u) {
            uint4 qa = *(const uint4*)(qp + u * 8);
            qh[u * 4 + 0] = __builtin_bit_cast(h2, qa.x);
            qh[u * 4 + 1] = __builtin_bit_cast(h2, qa.y);
            qh[u * 4 + 2] = __builtin_bit_cast(h2, qa.z);
            qh[u * 4 + 3] = __builtin_bit_cast(h2, qa.w);
        }

        float sc[36];
        const short* khb = kh + h * HSTR;
        #pragma unroll
        for (int kj = 0; kj < 36; ++kj) {
            const uint4* kp = (const uint4*)(khb + kj * 32);
            uint4 k0 = kp[0], k1 = kp[1], k2 = kp[2], k3 = kp[3];
            unsigned kwv[16] = { k0.x, k0.y, k0.z, k0.w, k1.x, k1.y, k1.z, k1.w,
                                 k2.x, k2.y, k2.z, k2.w, k3.x, k3.y, k3.z, k3.w };
            float a0 = 0.f, a1 = 0.f, a2 = 0.f, a3 = 0.f;
            #pragma unroll
            for (int e = 0; e < 4; ++e) {
                a0 = __builtin_amdgcn_fdot2(__builtin_bit_cast(h2, kwv[4*e+0]), qh[4*e+0], a0, false);
                a1 = __builtin_amdgcn_fdot2(__builtin_bit_cast(h2, kwv[4*e+1]), qh[4*e+1], a1, false);
                a2 = __builtin_amdgcn_fdot2(__builtin_bit_cast(h2, kwv[4*e+2]), qh[4*e+2], a2, false);
                a3 = __builtin_amdgcn_fdot2(__builtin_bit_cast(h2, kwv[4*e+3]), qh[4*e+3], a3, false);
            }
            const int rel0 = kj / 6 - (qi >> 2) + 3;
            const int rel1 = kj % 6 - (qi & 3) + 3;
            sc[kj] = ((a0 + a1) + (a2 + a3)) * 0.17677669529f + rpb[(rel0 * 9 + rel1) * 6 + h];
        }
        float mx = -1e30f;
        #pragma unroll
        for (int kj = 0; kj < 36; ++kj) mx = fmaxf(mx, sc[kj]);
        float sum = 0.f;
        #pragma unroll
        for (int kj = 0; kj < 36; ++kj) { sc[kj] = __expf(sc[kj] - mx); sum += sc[kj]; }
        const float inv = 1.f / sum;

        h2 o2[16];
        #pragma unroll
        for (int e = 0; e < 16; ++e) o2[e] = (h2){ (_Float16)0.f, (_Float16)0.f };
        const short* vhb = vh + h * HSTR;
        #pragma unroll
        for (int kj = 0; kj < 36; ++kj) {
            const uint4* vp = (const uint4*)(vhb + kj * 32);
            uint4 v0 = vp[0], v1 = vp[1], v2 = vp[2], v3 = vp[3];
            unsigned vwv[16] = { v0.x, v0.y, v0.z, v0.w, v1.x, v1.y, v1.z, v1.w,
                                 v2.x, v2.y, v2.z, v2.w, v3.x, v3.y, v3.z, v3.w };
            const _Float16 ph = (_Float16)sc[kj];
            const h2 ph2 = { ph, ph };
            #pragma unroll
            for (int e = 0; e < 16; ++e)
                o2[e] = __builtin_bit_cast(h2, vwv[e]) * ph2 + o2[e];
        }
        bf16* op = out + ((size_t)(b * TOKPB + qr * CW + qc)) * 192 + h * 32;
        #pragma unroll
        for (int u = 0; u < 8; ++u) {
            s4v pk;
            #pragma unroll
            for (int e = 0; e < 2; ++e) {
                h2 ov = o2[u * 2 + e];
                pk[2 * e]     = (short)f2bf((float)ov[0] * inv);
                pk[2 * e + 1] = (short)f2bf((float)ov[1] * inv);
            }
            *(s4v*)((bf16*)op + u * 4) = pk;
        }
    }
}

// ---------------- final: out = relu(C2 + conv1x1(x)), MFMA ----------------
__global__ __launch_bounds__(256, 4) void final_mfma_kernel(
    const float* __restrict__ x, const short* __restrict__ w3f,
    const float* __restrict__ b3, const bf16* __restrict__ c2,
    float* __restrict__ out)
{
    __shared__ short xs2[12288];      // [64 pix][192 ci] bf16, row-swizzled
    const int pix0 = blockIdx.x * 64;
    const int b    = blockIdx.y;
    const int tid = threadIdx.x, lane = tid & 63, wid = tid >> 6;
    const int cl = lane & 15, kg = lane >> 4;
    const float* xb = x + (size_t)b * (192 * TOKPB);

    #pragma unroll
    for (int u = 0; u < 12; ++u) {
        int idx = u * 256 + tid;                  // 3072 float4
        int ci = idx >> 4, p4 = (idx & 15) << 2;
        float4 v = *(const float4*)(xb + (size_t)ci * TOKPB + pix0 + p4);
        float vv[4] = { v.x, v.y, v.z, v.w };
        #pragma unroll
        for (int k = 0; k < 4; ++k) {
            int row = p4 + k;
            int ba = (row * 384 + ci * 2) ^ ((row & 7) << 4);
            *(short*)((char*)xs2 + ba) = (short)f2bf(vv[k]);
        }
    }
    __syncthreads();

    const int ctb = wid * 3;
    f32x4 acc[3][4] = {};
    const s8v* wf8 = (const s8v*)w3f;

    #pragma unroll
    for (int kt = 0; kt < 6; ++kt) {
        s8v a0 = wf8[(size_t)(kt * 12 + ctb + 0) * 64 + lane];
        s8v a1 = wf8[(size_t)(kt * 12 + ctb + 1) * 64 + lane];
        s8v a2 = wf8[(size_t)(kt * 12 + ctb + 2) * 64 + lane];
        #pragma unroll
        for (int pt = 0; pt < 4; ++pt) {
            int row = pt * 16 + cl;
            int ba = (row * 384 + kt * 64 + kg * 16) ^ ((row & 7) << 4);
            s8v bfr = *(const s8v*)((const char*)xs2 + ba);
            acc[0][pt] = __builtin_amdgcn_mfma_f32_16x16x32_bf16(a0, bfr, acc[0][pt], 0, 0, 0);
            acc[1][pt] = __builtin_amdgcn_mfma_f32_16x16x32_bf16(a1, bfr, acc[1][pt], 0, 0, 0);
            acc[2][pt] = __builtin_amdgcn_mfma_f32_16x16x32_bf16(a2, bfr, acc[2][pt], 0, 0, 0);
        }
    }

    #pragma unroll
    for (int t = 0; t < 3; ++t) {
        #pragma unroll
        for (int r = 0; r < 4; ++r) {
            const int co = (ctb + t) * 16 + kg * 4 + r;
            const float bb = b3[co];
            const size_t rowbase = (size_t)b * (192 * TOKPB) + (size_t)co * TOKPB + pix0;
            #pragma unroll
            for (int pt = 0; pt < 4; ++pt) {
                const size_t f = rowbase + pt * 16 + cl;
                float v = acc[t][pt][r] + bb + bf2f(__builtin_bit_cast(short, c2[f]));
                out[f] = fmaxf(v, 0.f);
            }
        }
    }
}

// ---------------- host launch ----------------
extern "C" void kernel_launch(void* const* d_in, const int* in_sizes, int n_in,
                              void* d_out, int out_size, void* d_ws, size_t ws_size,
                              hipStream_t stream)
{
    if (ws_size < WS_NEEDED) return;

    const float* x       = (const float*)d_in[0];
    const float* conv1_w = (const float*)d_in[1];
    const float* conv1_b = (const float*)d_in[2];
    const float* gn1_g   = (const float*)d_in[3];
    const float* gn1_b   = (const float*)d_in[4];
    const float* conv2_w = (const float*)d_in[5];
    const float* conv2_b = (const float*)d_in[6];
    const float* gn2_g   = (const float*)d_in[7];
    const float* gn2_b   = (const float*)d_in[8];
    const float* conv3_w = (const float*)d_in[9];
    const float* conv3_b = (const float*)d_in[10];
    const float* ln1_g   = (const float*)d_in[11];
    const float* ln1_b   = (const float*)d_in[12];
    const float* qkv_w   = (const float*)d_in[13];
    const float* qkv_b   = (const float*)d_in[14];
    const float* rpb     = (const float*)d_in[15];
    const float* proj_w  = (const float*)d_in[16];
    const float* proj_b  = (const float*)d_in[17];
    const float* ln2_g   = (const float*)d_in[18];
    const float* ln2_b   = (const float*)d_in[19];
    const float* fc1_w   = (const float*)d_in[20];
    const float* fc1_b   = (const float*)d_in[21];
    const float* fc2_w   = (const float*)d_in[22];
    const float* fc2_b   = (const float*)d_in[23];

    char* wsb = (char*)d_ws;
    bf16*  T0  = (bf16*)(wsb + B_T0);
    _Float16* QF = (_Float16*)(wsb + B_P2);   // Q/K/V f16 sections; later HID bf16
    bf16*  HID = (bf16*)(wsb + B_P2);
    bf16*  P3  = (bf16*)(wsb + B_P3);
    bf16*  P4  = (bf16*)(wsb + B_P4);
    short* WF1 = (short*)(wsb + B_WF1);
    short* WF2 = (short*)(wsb + B_WF2);
    short* W3F = (short*)(wsb + B_W3F);
    short* WQ  = (short*)(wsb + B_WQ);
    short* WP  = (short*)(wsb + B_WP);
    short* WG1 = (short*)(wsb + B_WG1);
    short* WG2 = (short*)(wsb + B_WG2);
    float* OUT = (float*)d_out;

    // weight prep
    build_wf_kernel<<<(331776 + 255) / 256, 256, 0, stream>>>(conv1_w, WF1);
    build_wf_kernel<<<(331776 + 255) / 256, 256, 0, stream>>>(conv2_w, WF2);
    build_w3f_kernel<<<(36864 + 255) / 256, 256, 0, stream>>>(conv3_w, W3F);
    build_wgemm_kernel<<<(110592 + 255) / 256, 256, 0, stream>>>(qkv_w, WQ, 192, 576);
    build_wgemm_kernel<<<(36864 + 255) / 256, 256, 0, stream>>>(proj_w, WP, 192, 192);
    build_wgemm_kernel<<<(73728 + 255) / 256, 256, 0, stream>>>(fc1_w, WG1, 192, 384);
    build_wgemm_kernel<<<(73728 + 255) / 256, 256, 0, stream>>>(fc2_w, WG2, 384, 192);

    // stage A: conv1 + gn1 + silu -> T0 (token layout, bf16); 4 patches/block, wave=patch
    conv_mfma_kernel<true><<<NPATCH / 4, 256, 0, stream>>>(x, WF1, conv1_b, gn1_g, gn1_b, T0);
    // stage C: LN1 (fused) + qkv gemm -> QF/KF/VF (f16 head-major); grid.y = 3 sections
    gemm_mfma_kernel<false, false, true, true, 6><<<dim3(MTOK / 128, 3), 256, 0, stream>>>(
        T0, WQ, qkv_b, nullptr, QF, 576, ln1_g, ln1_b);
    // stage D: attention -> P3 (ATT, bf16 token layout)
    attn_kernel<<<NPATCH, 128, 0, stream>>>(QF, rpb, P3);
    // stage E: proj + shortcut(T0) -> P4 (OMID)
    gemm_mfma_kernel<true, false, false, false, 6><<<dim3(MTOK / 128, 1), 256, 0, stream>>>(
        P3, WP, proj_b, T0, P4, 192, nullptr, nullptr);
    // stage G: LN2 (fused) + fc1 + gelu -> HID
    gemm_mfma_kernel<false, true, true, false, 6><<<dim3(MTOK / 128, 1), 256, 0, stream>>>(
        P4, WG1, fc1_b, nullptr, HID, 384, ln2_g, ln2_b);
    // stage H: fc2 + residual(OMID P4) -> P3 (OCAB, bf16 token layout)
    gemm_mfma_kernel<true, false, false, false, 12><<<dim3(MTOK / 128, 1), 256, 0, stream>>>(
        HID, WG2, fc2_b, P4, P3, 192, nullptr, nullptr);
    // stage I: conv2 + gn2 (reads P3 bf16 token layout) -> P4 (C2, bf16 patch-flat)
    conv_mfma_kernel<false><<<NPATCH / 4, 256, 0, stream>>>(P3, WF2, conv2_b, gn2_g, gn2_b, P4);
    // stage J: out = relu(C2 + conv1x1(x)) -> d_out, MFMA
    final_mfma_kernel<<<dim3(TOKPB / 64, CB), 256, 0, stream>>>(x, W3F, conv3_b, P4, OUT);
}

// Round 13
// 601.673 us; speedup vs baseline: 1.5503x; 1.5503x over previous
//
#include <hip/hip_runtime.h>
#include <hip/hip_bf16.h>
#include <math.h>

typedef __hip_bfloat16 bf16;
typedef __attribute__((ext_vector_type(8))) short s8v;
typedef __attribute__((ext_vector_type(4))) short s4v;
typedef __attribute__((ext_vector_type(4))) float f32x4;
typedef __attribute__((ext_vector_type(2))) _Float16 h2;

// ---------------- problem constants ----------------
constexpr int CB   = 2;            // batch
constexpr int CH   = 224, CW = 224;
constexpr int NHW  = 56;           // H/WS
constexpr int NPATCH = CB * NHW * NHW;   // 6272
constexpr int TOKPB  = CH * CW;          // 50176 tokens per batch
constexpr int MTOK   = CB * TOKPB;       // 100352 rows
constexpr size_t SECSZ = 19267584;       // elems per q/k/v f16 section

// ---------------- ws layout (BYTE offsets) ----------------
constexpr size_t B_T0  = 0;                         // 19267584 bf16
constexpr size_t B_P2  = B_T0 + 38535168;           // QF/KF/VF f16 (3x38.5MB); later HID bf16
constexpr size_t B_P3  = B_P2 + 115605504;          // 19267584 bf16 (ATT -> OCAB)
constexpr size_t B_P4  = B_P3 + 38535168;           // 19267584 bf16 (OMID -> C2)
constexpr size_t B_WF1 = B_P4 + 38535168;           // conv1 frag weights
constexpr size_t B_WF2 = B_WF1 + 1327104;           // conv2 frag weights
constexpr size_t B_W3F = B_WF2 + 1327104;           // conv3 1x1 frag weights
constexpr size_t B_WQ  = B_W3F + 147456;            // qkv_w frag
constexpr size_t B_WP  = B_WQ + 221184;             // proj_w frag
constexpr size_t B_WG1 = B_WP + 73728;              // fc1_w frag
constexpr size_t B_WG2 = B_WG1 + 147456;            // fc2_w frag
constexpr size_t WS_NEEDED = B_WG2 + 147456;        // 234,602,496 B

// ---------------- type helpers ----------------
__device__ __forceinline__ float ldf(const float* p) { return *p; }
__device__ __forceinline__ float ldf(const bf16* p)  { return __bfloat162float(*p); }
__device__ __forceinline__ void  stf(float* p, float v) { *p = v; }
__device__ __forceinline__ void  stf(bf16* p, float v)  { *p = __float2bfloat16(v); }
__device__ __forceinline__ unsigned short f2bf(float f) {
    unsigned u = __builtin_bit_cast(unsigned, f);
    unsigned r = (u + 0x7fffu + ((u >> 16) & 1u)) >> 16;
    return (unsigned short)r;
}
__device__ __forceinline__ float bf2f(short s) {
    unsigned u = ((unsigned)(unsigned short)s) << 16;
    return __builtin_bit_cast(float, u);
}

// ---------------- weight pre-pack kernels ----------------
__global__ void build_wf_kernel(const float* __restrict__ w, short* __restrict__ wf) {
    int o = blockIdx.x * 256 + threadIdx.x;
    if (o >= 331776) return;
    int within = o & 511, frag = o >> 9;
    int l = within >> 3, j = within & 7;
    int nt = frag % 12, t2 = frag / 12, ks = t2 % 6, tap = t2 / 6;
    int co = nt * 16 + (l & 15);
    int ci = ks * 32 + (l >> 4) * 8 + j;
    wf[o] = (short)f2bf(w[(co * 192 + ci) * 9 + tap]);
}
__global__ void build_wgemm_kernel(const float* __restrict__ w, short* __restrict__ wf,
                                   int K, int N) {
    int o = blockIdx.x * 256 + threadIdx.x;
    if (o >= K * N) return;
    int j = o & 7, l = (o >> 3) & 63, f = o >> 9;
    int ntiles = N >> 4;
    int kt = f / ntiles, nt = f % ntiles;
    int k = kt * 32 + (l >> 4) * 8 + j;
    int col = nt * 16 + (l & 15);
    wf[o] = (short)f2bf(w[(size_t)k * N + col]);
}
__global__ void build_w3f_kernel(const float* __restrict__ w, short* __restrict__ wf) {
    int o = blockIdx.x * 256 + threadIdx.x;
    if (o >= 36864) return;
    int j = o & 7, l = (o >> 3) & 63, f = o >> 9;   // f = kt*12 + ct
    int kt = f / 12, ct = f % 12;
    int co = ct * 16 + (l & 15);
    int ci = kt * 32 + (l >> 4) * 8 + j;
    wf[o] = (short)f2bf(w[co * 192 + ci]);
}

// ---------------- conv3x3 (4x4 patches) + groupnorm (+silu), MFMA ----------------
// 4 patches/block, 256 threads. Wave w owns nt-tiles 3w..3w+2 (B-frags held in regs,
// reused across 4 patches) — measured-best decomposition (rounds 9/10).
template <bool FIRST>
__global__ __launch_bounds__(256, 4) void conv_mfma_kernel(
    const void* __restrict__ srcv, const short* __restrict__ wf,
    const float* __restrict__ bias, const float* __restrict__ gng,
    const float* __restrict__ gnb, bf16* __restrict__ dst)
{
    __shared__ short xs[13056];          // 4 patches * 17 rows * 384B (row 16 = zeros), swizzled
    __shared__ float gsum[4][6], gsum2[4][6], gmu[4][6], grs[4][6];
    const int tid  = threadIdx.x;
    const int lane = tid & 63, wid = tid >> 6;
    const int n0   = blockIdx.x * 4;

    if (tid < 24) { gsum[tid / 6][tid % 6] = 0.f; gsum2[tid / 6][tid % 6] = 0.f; }
    for (int u = tid; u < 4 * 192; u += 256) {       // zero rows
        int q = u / 192;
        xs[q * 3264 + 3072 + (u % 192)] = 0;
    }

    if constexpr (FIRST) {
        const float4* sp = (const float4*)((const float*)srcv + (size_t)n0 * 3072);
        #pragma unroll
        for (int u = 0; u < 12; ++u) {
            int idx = u * 256 + tid;                 // float4 index, 3072 total
            float4 v = sp[idx];
            int q = idx / 768;
            int li = (idx % 768) * 4;                // li = ci*16 + p
            int ci = li >> 4, p0 = li & 15;
            float vv[4] = { v.x, v.y, v.z, v.w };
            #pragma unroll
            for (int k = 0; k < 4; ++k) {
                int row = p0 + k;
                int ba = q * 6528 + ((row * 384 + ci * 2) ^ ((row & 7) << 4));
                *(short*)((char*)xs + ba) = (short)f2bf(vv[k]);
            }
        }
    } else {
        const s8v* sp8 = (const s8v*)((const bf16*)srcv + (size_t)n0 * 3072);
        #pragma unroll
        for (int u = 0; u < 6; ++u) {
            int li = u * 256 + tid;                  // 1536 s8v units
            int r = li / 24, ch = li % 24;
            int q = r >> 4, rl = r & 15;
            s8v val = sp8[li];
            int ba = q * 6528 + ((rl * 384 + ch * 16) ^ ((rl & 7) << 4));
            *(s8v*)((char*)xs + ba) = val;
        }
    }
    __syncthreads();

    const int ntb = wid * 3;
    const int cl  = lane & 15;
    const int kg  = lane >> 4;
    f32x4 acc[3][4];
    #pragma unroll
    for (int t = 0; t < 3; ++t) {
        float bv = bias[(ntb + t) * 16 + cl];
        #pragma unroll
        for (int q = 0; q < 4; ++q) acc[t][q] = (f32x4){ bv, bv, bv, bv };
    }

    const int pi = cl >> 2, pj = cl & 3;
    const s8v* wf8 = (const s8v*)wf;

    for (int tap = 0; tap < 9; ++tap) {
        const int di = tap / 3, dj = tap % 3;
        const int ii = pi + di - 1, jj = pj + dj - 1;
        const bool valid = (ii >= 0 && ii < 4 && jj >= 0 && jj < 4);
        const int nr  = valid ? (ii * 4 + jj) : 16;   // row 16 = zero row
        const int rb  = nr * 384;
        const int swz = (nr & 7) << 4;
        #pragma unroll
        for (int ks = 0; ks < 6; ++ks) {
            const s8v* bp = wf8 + (size_t)((tap * 6 + ks) * 12) * 64 + lane;
            s8v b0 = bp[(ntb + 0) * 64];
            s8v b1 = bp[(ntb + 1) * 64];
            s8v b2 = bp[(ntb + 2) * 64];
            const int inner = (rb + ks * 64 + kg * 16) ^ swz;
            #pragma unroll
            for (int q = 0; q < 4; ++q) {
                s8v a = *(const s8v*)((const char*)xs + q * 6528 + inner);
                acc[0][q] = __builtin_amdgcn_mfma_f32_16x16x32_bf16(a, b0, acc[0][q], 0, 0, 0);
                acc[1][q] = __builtin_amdgcn_mfma_f32_16x16x32_bf16(a, b1, acc[1][q], 0, 0, 0);
                acc[2][q] = __builtin_amdgcn_mfma_f32_16x16x32_bf16(a, b2, acc[2][q], 0, 0, 0);
            }
        }
    }

    #pragma unroll
    for (int t = 0; t < 3; ++t) {
        const int g = (ntb + t) >> 1;
        #pragma unroll
        for (int q = 0; q < 4; ++q) {
            f32x4 A = acc[t][q];
            float s  = A[0] + A[1] + A[2] + A[3];
            float s2 = A[0]*A[0] + A[1]*A[1] + A[2]*A[2] + A[3]*A[3];
            #pragma unroll
            for (int off = 32; off; off >>= 1) { s += __shfl_xor(s, off); s2 += __shfl_xor(s2, off); }
            if (lane == 0) { atomicAdd(&gsum[q][g], s); atomicAdd(&gsum2[q][g], s2); }
        }
    }
    __syncthreads();
    if (tid < 24) {
        int q = tid / 6, g = tid % 6;
        float mu  = gsum[q][g] * (1.f / 512.f);
        float var = gsum2[q][g] * (1.f / 512.f) - mu * mu;
        gmu[q][g] = mu; grs[q][g] = rsqrtf(var + 1e-5f);
    }
    __syncthreads();

    if constexpr (FIRST) {
        // normalize + SiLU -> swizzled LDS [64 tok][192 co], then coalesced 16B stores
        #pragma unroll
        for (int t = 0; t < 3; ++t) {
            const int co = (ntb + t) * 16 + cl, g = (ntb + t) >> 1;
            const float gg = gng[co], gb = gnb[co];
            #pragma unroll
            for (int q = 0; q < 4; ++q) {
                const float mu = gmu[q][g], rs = grs[q][g];
                #pragma unroll
                for (int r = 0; r < 4; ++r) {
                    float v = (acc[t][q][r] - mu) * rs * gg + gb;
                    v = v / (1.f + __expf(-v));      // silu (fast exp)
                    int row = q * 16 + kg * 4 + r;
                    int ba = (row * 384 + co * 2) ^ ((row & 7) << 4);
                    *(short*)((char*)xs + ba) = (short)f2bf(v);
                }
            }
        }
        __syncthreads();
        bf16* dp = dst + (size_t)n0 * 3072;          // token-major [tok][192], contiguous block
        #pragma unroll
        for (int u = 0; u < 6; ++u) {
            int li = u * 256 + tid;                  // 1536 s8v units
            int row = li / 24, g2 = li % 24;
            int ba = (row * 384 + g2 * 16) ^ ((row & 7) << 4);
            s8v val = *(const s8v*)((const char*)xs + ba);
            *(s8v*)(dp + (size_t)row * 192 + g2 * 8) = val;
        }
    } else {
        #pragma unroll
        for (int t = 0; t < 3; ++t) {
            const int co = (ntb + t) * 16 + cl, g = (ntb + t) >> 1;
            const float gg = gng[co], gb = gnb[co];
            #pragma unroll
            for (int q = 0; q < 4; ++q) {
                const float mu = gmu[q][g], rs = grs[q][g];
                #pragma unroll
                for (int r = 0; r < 4; ++r) {
                    float v = (acc[t][q][r] - mu) * rs * gg + gb;
                    xs[q * 3072 + co * 16 + kg * 4 + r] = (short)f2bf(v);
                }
            }
        }
        __syncthreads();
        s4v* dp = (s4v*)(dst + (size_t)n0 * 3072);
        const s4v* sps = (const s4v*)xs;
        #pragma unroll
        for (int u = 0; u < 12; ++u) {
            dp[u * 256 + tid] = sps[u * 256 + tid];
        }
    }
}

// ---------------- MFMA GEMM, single-pass over an N-range, LDS-transpose epilogue ----
template <bool RES, bool GELU_ACT, bool LN, bool QKVOUT, int NKT>
__global__ __launch_bounds__(256) void gemm_mfma_kernel(
    const bf16* __restrict__ A, const short* __restrict__ wfb,
    const float* __restrict__ bias, const bf16* __restrict__ res,
    void* __restrict__ out, int N,
    const float* __restrict__ lng, const float* __restrict__ lnb)
{
    __shared__ short ls[8192];           // [128 rows][64 cols] 2B, XOR-swizzled
    const int tid = threadIdx.x, lane = tid & 63, wid = tid >> 6;
    const int m0 = blockIdx.x * 128;
    const int cl = lane & 15, kg = lane >> 4;
    constexpr int K = NKT * 32;
    const int ntiles = N >> 4;
    const int ntsec = ntiles / gridDim.y;
    const int ntbeg = blockIdx.y * ntsec;

    // load this thread's two A-rows (rows r0, r0+16) as fragments, once
    s8v af0[NKT], af1[NKT];
    const int r0 = m0 + wid * 32 + cl;
    #pragma unroll
    for (int kt = 0; kt < NKT; ++kt) {
        af0[kt] = *(const s8v*)(A + (size_t)r0 * K + kt * 32 + kg * 8);
        af1[kt] = *(const s8v*)(A + (size_t)(r0 + 16) * K + kt * 32 + kg * 8);
    }
    if constexpr (LN) {
        static_assert(!LN || NKT == 6, "LN requires K==192");
        #pragma unroll
        for (int r = 0; r < 2; ++r) {
            s8v* af = r ? af1 : af0;
            float s = 0.f, s2 = 0.f;
            #pragma unroll
            for (int kt = 0; kt < NKT; ++kt)
                #pragma unroll
                for (int j = 0; j < 8; ++j) {
                    float v = bf2f(af[kt][j]);
                    s += v; s2 += v * v;
                }
            s  += __shfl_xor(s, 16);  s2 += __shfl_xor(s2, 16);
            s  += __shfl_xor(s, 32);  s2 += __shfl_xor(s2, 32);
            const float mu = s * (1.f / 192.f);
            const float rs = rsqrtf(s2 * (1.f / 192.f) - mu * mu + 1e-5f);
            #pragma unroll
            for (int kt = 0; kt < NKT; ++kt) {
                const float* gp = lng + kt * 32 + kg * 8;
                const float* bp = lnb + kt * 32 + kg * 8;
                #pragma unroll
                for (int j = 0; j < 8; ++j) {
                    float v = (bf2f(af[kt][j]) - mu) * rs * gp[j] + bp[j];
                    af[kt][j] = (short)f2bf(v);
                }
            }
        }
    }

    const s8v* wf8 = (const s8v*)wfb;
    for (int nt0 = ntbeg; nt0 < ntbeg + ntsec; nt0 += 4) {
        const int n0 = nt0 * 16;
        f32x4 acc[2][4];
        #pragma unroll
        for (int nf = 0; nf < 4; ++nf) {
            float bv = bias[n0 + nf * 16 + cl];
            acc[0][nf] = (f32x4){ bv, bv, bv, bv };
            acc[1][nf] = (f32x4){ bv, bv, bv, bv };
        }
        #pragma unroll
        for (int kt = 0; kt < NKT; ++kt) {
            #pragma unroll
            for (int nf = 0; nf < 4; ++nf) {
                s8v b = wf8[(size_t)(kt * ntiles + nt0 + nf) * 64 + lane];
                acc[0][nf] = __builtin_amdgcn_mfma_f32_16x16x32_bf16(af0[kt], b, acc[0][nf], 0, 0, 0);
                acc[1][nf] = __builtin_amdgcn_mfma_f32_16x16x32_bf16(af1[kt], b, acc[1][nf], 0, 0, 0);
            }
        }

        // ---- epilogue: acc -> LDS (2B, swizzled) -> 16B coalesced stores ----
        __syncthreads();                 // previous chunk's readback done
        #pragma unroll
        for (int rf = 0; rf < 2; ++rf) {
            #pragma unroll
            for (int nf = 0; nf < 4; ++nf) {
                const int lcol = nf * 16 + cl;
                #pragma unroll
                for (int r = 0; r < 4; ++r) {
                    const int lrow = wid * 32 + rf * 16 + kg * 4 + r;
                    float v = acc[rf][nf][r];
                    if (GELU_ACT) v = 0.5f * v * (1.f + erff(v * 0.70710678118f));
                    short sv;
                    if constexpr (QKVOUT) sv = __builtin_bit_cast(short, (_Float16)v);
                    else                  sv = (short)f2bf(v);
                    int ba = (lrow * 128 + lcol * 2) ^ ((lrow & 7) << 4);
                    *(short*)((char*)ls + ba) = sv;
                }
            }
        }
        __syncthreads();
        #pragma unroll
        for (int p = 0; p < 4; ++p) {
            const int lrow = p * 32 + (tid >> 3);
            const int g = tid & 7;
            int ba = (lrow * 128 + g * 16) ^ ((lrow & 7) << 4);
            s8v val = *(const s8v*)((const char*)ls + ba);
            const int row = m0 + lrow;
            const int col0 = n0 + g * 8;
            if constexpr (QKVOUT) {
                const int sec = n0 / 192;        // 64-col chunk never crosses a section
                const int c0 = col0 - sec * 192, h = c0 >> 5, d0 = c0 & 31;
                const int bb2 = row / TOKPB, t = row - bb2 * TOKPB;
                *(s8v*)((_Float16*)out + (size_t)sec * SECSZ +
                        ((size_t)(bb2 * 6 + h) * TOKPB + t) * 32 + d0) = val;
            } else if constexpr (RES) {
                s8v rv = *(const s8v*)(res + (size_t)row * N + col0);
                s8v ov;
                #pragma unroll
                for (int e = 0; e < 8; ++e) ov[e] = (short)f2bf(bf2f(val[e]) + bf2f(rv[e]));
                *(s8v*)((bf16*)out + (size_t)row * N + col0) = ov;
            } else {
                *(s8v*)((bf16*)out + (size_t)row * N + col0) = val;
            }
        }
    }
}

// ---------------- overlapping-window attention (f16 head-major inputs) ----------------
constexpr int HSTR = 1160;   // per-head LDS stride in shorts (36*32 + 8 pad)
__global__ __launch_bounds__(128) void attn_kernel(
    const _Float16* __restrict__ qf, const float* __restrict__ rpb,
    bf16* __restrict__ out)
{
    __shared__ short kh[6 * HSTR];
    __shared__ short vh[6 * HSTR];
    const int w = blockIdx.x;
    const int b = w / (NHW * NHW), wi = w % (NHW * NHW);
    const int nhi = wi / NHW, nwi = wi % NHW;
    const int tid = threadIdx.x;
    const int r0 = nhi * 4 - 1, c0 = nwi * 4 - 1;
    const _Float16* kfb = qf + SECSZ;
    const _Float16* vfb = qf + 2 * SECSZ;

    // stage K and V: 2*864 units of 16B, pure copy (no conversion)
    #pragma unroll
    for (int it = 0; it < 14; ++it) {
        int v = tid + it * 128;
        if (v < 1728) {
            int kv = v >= 864 ? 1 : 0;
            int u = v - kv * 864;
            int h = u / 144, rem = u % 144, kj = rem >> 2, d0 = (rem & 3) * 8;
            int rr = r0 + kj / 6, cc = c0 + kj % 6;
            s8v val = { 0, 0, 0, 0, 0, 0, 0, 0 };
            if (rr >= 0 && rr < CH && cc >= 0 && cc < CW) {
                const _Float16* src = kv ? vfb : kfb;
                val = *(const s8v*)(src + ((size_t)(b * 6 + h) * TOKPB + rr * CW + cc) * 32 + d0);
            }
            short* dst = kv ? vh : kh;
            *(s8v*)(dst + h * HSTR + kj * 32 + d0) = val;
        }
    }
    __syncthreads();

    if (tid < 96) {
        const int h = tid >> 4, qi = tid & 15;
        const int qr = nhi * 4 + (qi >> 2), qc = nwi * 4 + (qi & 3);
        const _Float16* qp = qf + ((size_t)(b * 6 + h) * TOKPB + qr * CW + qc) * 32;
        h2 qh[16];
        #pragma unroll
        for (int u = 0; u < 4; ++u) {
            uint4 qa = *(const uint4*)(qp + u * 8);
            qh[u * 4 + 0] = __builtin_bit_cast(h2, qa.x);
            qh[u * 4 + 1] = __builtin_bit_cast(h2, qa.y);
            qh[u * 4 + 2] = __builtin_bit_cast(h2, qa.z);
            qh[u * 4 + 3] = __builtin_bit_cast(h2, qa.w);
        }

        float sc[36];
        const short* khb = kh + h * HSTR;
        #pragma unroll
        for (int kj = 0; kj < 36; ++kj) {
            const uint4* kp = (const uint4*)(khb + kj * 32);
            uint4 k0 = kp[0], k1 = kp[1], k2 = kp[2], k3 = kp[3];
            unsigned kwv[16] = { k0.x, k0.y, k0.z, k0.w, k1.x, k1.y, k1.z, k1.w,
                                 k2.x, k2.y, k2.z, k2.w, k3.x, k3.y, k3.z, k3.w };
            float a0 = 0.f, a1 = 0.f, a2 = 0.f, a3 = 0.f;
            #pragma unroll
            for (int e = 0; e < 4; ++e) {
                a0 = __builtin_amdgcn_fdot2(__builtin_bit_cast(h2, kwv[4*e+0]), qh[4*e+0], a0, false);
                a1 = __builtin_amdgcn_fdot2(__builtin_bit_cast(h2, kwv[4*e+1]), qh[4*e+1], a1, false);
                a2 = __builtin_amdgcn_fdot2(__builtin_bit_cast(h2, kwv[4*e+2]), qh[4*e+2], a2, false);
                a3 = __builtin_amdgcn_fdot2(__builtin_bit_cast(h2, kwv[4*e+3]), qh[4*e+3], a3, false);
            }
            const int rel0 = kj / 6 - (qi >> 2) + 3;
            const int rel1 = kj % 6 - (qi & 3) + 3;
            sc[kj] = ((a0 + a1) + (a2 + a3)) * 0.17677669529f + rpb[(rel0 * 9 + rel1) * 6 + h];
        }
        float mx = -1e30f;
        #pragma unroll
        for (int kj = 0; kj < 36; ++kj) mx = fmaxf(mx, sc[kj]);
        float sum = 0.f;
        #pragma unroll
        for (int kj = 0; kj < 36; ++kj) { sc[kj] = __expf(sc[kj] - mx); sum += sc[kj]; }
        const float inv = 1.f / sum;

        h2 o2[16];
        #pragma unroll
        for (int e = 0; e < 16; ++e) o2[e] = (h2){ (_Float16)0.f, (_Float16)0.f };
        const short* vhb = vh + h * HSTR;
        #pragma unroll
        for (int kj = 0; kj < 36; ++kj) {
            const uint4* vp = (const uint4*)(vhb + kj * 32);
            uint4 v0 = vp[0], v1 = vp[1], v2 = vp[2], v3 = vp[3];
            unsigned vwv[16] = { v0.x, v0.y, v0.z, v0.w, v1.x, v1.y, v1.z, v1.w,
                                 v2.x, v2.y, v2.z, v2.w, v3.x, v3.y, v3.z, v3.w };
            const _Float16 ph = (_Float16)sc[kj];
            const h2 ph2 = { ph, ph };
            #pragma unroll
            for (int e = 0; e < 16; ++e)
                o2[e] = __builtin_bit_cast(h2, vwv[e]) * ph2 + o2[e];
        }
        bf16* op = out + ((size_t)(b * TOKPB + qr * CW + qc)) * 192 + h * 32;
        #pragma unroll
        for (int u = 0; u < 8; ++u) {
            s4v pk;
            #pragma unroll
            for (int e = 0; e < 2; ++e) {
                h2 ov = o2[u * 2 + e];
                pk[2 * e]     = (short)f2bf((float)ov[0] * inv);
                pk[2 * e + 1] = (short)f2bf((float)ov[1] * inv);
            }
            *(s4v*)((bf16*)op + u * 4) = pk;
        }
    }
}

// ---------------- final: out = relu(C2 + conv1x1(x)), MFMA ----------------
__global__ __launch_bounds__(256, 4) void final_mfma_kernel(
    const float* __restrict__ x, const short* __restrict__ w3f,
    const float* __restrict__ b3, const bf16* __restrict__ c2,
    float* __restrict__ out)
{
    __shared__ short xs2[12288];      // [64 pix][192 ci] bf16, row-swizzled
    const int pix0 = blockIdx.x * 64;
    const int b    = blockIdx.y;
    const int tid = threadIdx.x, lane = tid & 63, wid = tid >> 6;
    const int cl = lane & 15, kg = lane >> 4;
    const float* xb = x + (size_t)b * (192 * TOKPB);

    #pragma unroll
    for (int u = 0; u < 12; ++u) {
        int idx = u * 256 + tid;                  // 3072 float4
        int ci = idx >> 4, p4 = (idx & 15) << 2;
        float4 v = *(const float4*)(xb + (size_t)ci * TOKPB + pix0 + p4);
        float vv[4] = { v.x, v.y, v.z, v.w };
        #pragma unroll
        for (int k = 0; k < 4; ++k) {
            int row = p4 + k;
            int ba = (row * 384 + ci * 2) ^ ((row & 7) << 4);
            *(short*)((char*)xs2 + ba) = (short)f2bf(vv[k]);
        }
    }
    __syncthreads();

    const int ctb = wid * 3;
    f32x4 acc[3][4] = {};
    const s8v* wf8 = (const s8v*)w3f;

    #pragma unroll
    for (int kt = 0; kt < 6; ++kt) {
        s8v a0 = wf8[(size_t)(kt * 12 + ctb + 0) * 64 + lane];
        s8v a1 = wf8[(size_t)(kt * 12 + ctb + 1) * 64 + lane];
        s8v a2 = wf8[(size_t)(kt * 12 + ctb + 2) * 64 + lane];
        #pragma unroll
        for (int pt = 0; pt < 4; ++pt) {
            int row = pt * 16 + cl;
            int ba = (row * 384 + kt * 64 + kg * 16) ^ ((row & 7) << 4);
            s8v bfr = *(const s8v*)((const char*)xs2 + ba);
            acc[0][pt] = __builtin_amdgcn_mfma_f32_16x16x32_bf16(a0, bfr, acc[0][pt], 0, 0, 0);
            acc[1][pt] = __builtin_amdgcn_mfma_f32_16x16x32_bf16(a1, bfr, acc[1][pt], 0, 0, 0);
            acc[2][pt] = __builtin_amdgcn_mfma_f32_16x16x32_bf16(a2, bfr, acc[2][pt], 0, 0, 0);
        }
    }

    #pragma unroll
    for (int t = 0; t < 3; ++t) {
        #pragma unroll
        for (int r = 0; r < 4; ++r) {
            const int co = (ctb + t) * 16 + kg * 4 + r;
            const float bb = b3[co];
            const size_t rowbase = (size_t)b * (192 * TOKPB) + (size_t)co * TOKPB + pix0;
            #pragma unroll
            for (int pt = 0; pt < 4; ++pt) {
                const size_t f = rowbase + pt * 16 + cl;
                float v = acc[t][pt][r] + bb + bf2f(__builtin_bit_cast(short, c2[f]));
                out[f] = fmaxf(v, 0.f);
            }
        }
    }
}

// ---------------- host launch ----------------
extern "C" void kernel_launch(void* const* d_in, const int* in_sizes, int n_in,
                              void* d_out, int out_size, void* d_ws, size_t ws_size,
                              hipStream_t stream)
{
    if (ws_size < WS_NEEDED) return;

    const float* x       = (const float*)d_in[0];
    const float* conv1_w = (const float*)d_in[1];
    const float* conv1_b = (const float*)d_in[2];
    const float* gn1_g   = (const float*)d_in[3];
    const float* gn1_b   = (const float*)d_in[4];
    const float* conv2_w = (const float*)d_in[5];
    const float* conv2_b = (const float*)d_in[6];
    const float* gn2_g   = (const float*)d_in[7];
    const float* gn2_b   = (const float*)d_in[8];
    const float* conv3_w = (const float*)d_in[9];
    const float* conv3_b = (const float*)d_in[10];
    const float* ln1_g   = (const float*)d_in[11];
    const float* ln1_b   = (const float*)d_in[12];
    const float* qkv_w   = (const float*)d_in[13];
    const float* qkv_b   = (const float*)d_in[14];
    const float* rpb     = (const float*)d_in[15];
    const float* proj_w  = (const float*)d_in[16];
    const float* proj_b  = (const float*)d_in[17];
    const float* ln2_g   = (const float*)d_in[18];
    const float* ln2_b   = (const float*)d_in[19];
    const float* fc1_w   = (const float*)d_in[20];
    const float* fc1_b   = (const float*)d_in[21];
    const float* fc2_w   = (const float*)d_in[22];
    const float* fc2_b   = (const float*)d_in[23];

    char* wsb = (char*)d_ws;
    bf16*  T0  = (bf16*)(wsb + B_T0);
    _Float16* QF = (_Float16*)(wsb + B_P2);   // Q/K/V f16 sections; later HID bf16
    bf16*  HID = (bf16*)(wsb + B_P2);
    bf16*  P3  = (bf16*)(wsb + B_P3);
    bf16*  P4  = (bf16*)(wsb + B_P4);
    short* WF1 = (short*)(wsb + B_WF1);
    short* WF2 = (short*)(wsb + B_WF2);
    short* W3F = (short*)(wsb + B_W3F);
    short* WQ  = (short*)(wsb + B_WQ);
    short* WP  = (short*)(wsb + B_WP);
    short* WG1 = (short*)(wsb + B_WG1);
    short* WG2 = (short*)(wsb + B_WG2);
    float* OUT = (float*)d_out;

    // weight prep
    build_wf_kernel<<<(331776 + 255) / 256, 256, 0, stream>>>(conv1_w, WF1);
    build_wf_kernel<<<(331776 + 255) / 256, 256, 0, stream>>>(conv2_w, WF2);
    build_w3f_kernel<<<(36864 + 255) / 256, 256, 0, stream>>>(conv3_w, W3F);
    build_wgemm_kernel<<<(110592 + 255) / 256, 256, 0, stream>>>(qkv_w, WQ, 192, 576);
    build_wgemm_kernel<<<(36864 + 255) / 256, 256, 0, stream>>>(proj_w, WP, 192, 192);
    build_wgemm_kernel<<<(73728 + 255) / 256, 256, 0, stream>>>(fc1_w, WG1, 192, 384);
    build_wgemm_kernel<<<(73728 + 255) / 256, 256, 0, stream>>>(fc2_w, WG2, 384, 192);

    // stage A: conv1 + gn1 + silu -> T0 (token layout, bf16); measured-best conv shape
    conv_mfma_kernel<true><<<NPATCH / 4, 256, 0, stream>>>(x, WF1, conv1_b, gn1_g, gn1_b, T0);
    // stage C: LN1 (fused) + qkv gemm -> QF/KF/VF (f16 head-major); grid.y = 3 sections
    gemm_mfma_kernel<false, false, true, true, 6><<<dim3(MTOK / 128, 3), 256, 0, stream>>>(
        T0, WQ, qkv_b, nullptr, QF, 576, ln1_g, ln1_b);
    // stage D: attention -> P3 (ATT, bf16 token layout)
    attn_kernel<<<NPATCH, 128, 0, stream>>>(QF, rpb, P3);
    // stage E: proj + shortcut(T0) -> P4 (OMID); grid.y = 1 (measured-best)
    gemm_mfma_kernel<true, false, false, false, 6><<<dim3(MTOK / 128, 1), 256, 0, stream>>>(
        P3, WP, proj_b, T0, P4, 192, nullptr, nullptr);
    // stage G: LN2 (fused) + fc1 + gelu -> HID; grid.y = 1
    gemm_mfma_kernel<false, true, true, false, 6><<<dim3(MTOK / 128, 1), 256, 0, stream>>>(
        P4, WG1, fc1_b, nullptr, HID, 384, ln2_g, ln2_b);
    // stage H: fc2 + residual(OMID P4) -> P3 (OCAB, bf16 token layout); grid.y = 1
    gemm_mfma_kernel<true, false, false, false, 12><<<dim3(MTOK / 128, 1), 256, 0, stream>>>(
        HID, WG2, fc2_b, P4, P3, 192, nullptr, nullptr);
    // stage I: conv2 + gn2 (reads P3 bf16 token layout) -> P4 (C2, bf16 patch-flat)
    conv_mfma_kernel<false><<<NPATCH / 4, 256, 0, stream>>>(P3, WF2, conv2_b, gn2_g, gn2_b, P4);
    // stage J: out = relu(C2 + conv1x1(x)) -> d_out, MFMA
    final_mfma_kernel<<<dim3(TOKPB / 64, CB), 256, 0, stream>>>(x, W3F, conv3_b, P4, OUT);
}

// Round 14
// 576.184 us; speedup vs baseline: 1.6189x; 1.0442x over previous
//
#include <hip/hip_runtime.h>
#include <hip/hip_bf16.h>
#include <math.h>

typedef __hip_bfloat16 bf16;
typedef __attribute__((ext_vector_type(8))) short s8v;
typedef __attribute__((ext_vector_type(4))) short s4v;
typedef __attribute__((ext_vector_type(4))) float f32x4;
typedef __attribute__((ext_vector_type(2))) _Float16 h2;

// ---------------- problem constants ----------------
constexpr int CB   = 2;            // batch
constexpr int CH   = 224, CW = 224;
constexpr int NHW  = 56;           // H/WS
constexpr int NPATCH = CB * NHW * NHW;   // 6272
constexpr int TOKPB  = CH * CW;          // 50176 tokens per batch
constexpr int MTOK   = CB * TOKPB;       // 100352 rows
constexpr size_t SECSZ = 19267584;       // elems per q/k/v f16 section

// ---------------- ws layout (BYTE offsets) ----------------
constexpr size_t B_T0  = 0;                         // 19267584 bf16
constexpr size_t B_P2  = B_T0 + 38535168;           // QF/KF/VF f16 (3x38.5MB); later HID bf16
constexpr size_t B_P3  = B_P2 + 115605504;          // 19267584 bf16 (ATT -> OCAB)
constexpr size_t B_P4  = B_P3 + 38535168;           // 19267584 bf16 (OMID -> C2)
constexpr size_t B_WF1 = B_P4 + 38535168;           // conv1 frag weights
constexpr size_t B_WF2 = B_WF1 + 1327104;           // conv2 frag weights
constexpr size_t B_W3F = B_WF2 + 1327104;           // conv3 1x1 frag weights
constexpr size_t B_WQ  = B_W3F + 147456;            // qkv_w frag
constexpr size_t B_WP  = B_WQ + 221184;             // proj_w frag
constexpr size_t B_WG1 = B_WP + 73728;              // fc1_w frag
constexpr size_t B_WG2 = B_WG1 + 147456;            // fc2_w frag
constexpr size_t WS_NEEDED = B_WG2 + 147456;        // 234,602,496 B

// ---------------- type helpers ----------------
__device__ __forceinline__ float ldf(const float* p) { return *p; }
__device__ __forceinline__ float ldf(const bf16* p)  { return __bfloat162float(*p); }
__device__ __forceinline__ void  stf(float* p, float v) { *p = v; }
__device__ __forceinline__ void  stf(bf16* p, float v)  { *p = __float2bfloat16(v); }
__device__ __forceinline__ unsigned short f2bf(float f) {
    unsigned u = __builtin_bit_cast(unsigned, f);
    unsigned r = (u + 0x7fffu + ((u >> 16) & 1u)) >> 16;
    return (unsigned short)r;
}
__device__ __forceinline__ float bf2f(short s) {
    unsigned u = ((unsigned)(unsigned short)s) << 16;
    return __builtin_bit_cast(float, u);
}

// ---------------- fused weight pre-pack (one launch) ----------------
__device__ __forceinline__ void prep_wf(const float* __restrict__ w, short* __restrict__ wf, int o) {
    int within = o & 511, frag = o >> 9;
    int l = within >> 3, j = within & 7;
    int nt = frag % 12, t2 = frag / 12, ks = t2 % 6, tap = t2 / 6;
    int co = nt * 16 + (l & 15);
    int ci = ks * 32 + (l >> 4) * 8 + j;
    wf[o] = (short)f2bf(w[(co * 192 + ci) * 9 + tap]);
}
__device__ __forceinline__ void prep_wgemm(const float* __restrict__ w, short* __restrict__ wf,
                                           int K, int N, int o) {
    int j = o & 7, l = (o >> 3) & 63, f = o >> 9;
    int ntiles = N >> 4;
    int kt = f / ntiles, nt = f % ntiles;
    int k = kt * 32 + (l >> 4) * 8 + j;
    int col = nt * 16 + (l & 15);
    wf[o] = (short)f2bf(w[(size_t)k * N + col]);
}
__device__ __forceinline__ void prep_w3f(const float* __restrict__ w, short* __restrict__ wf, int o) {
    int j = o & 7, l = (o >> 3) & 63, f = o >> 9;   // f = kt*12 + ct
    int kt = f / 12, ct = f % 12;
    int co = ct * 16 + (l & 15);
    int ci = kt * 32 + (l >> 4) * 8 + j;
    wf[o] = (short)f2bf(w[co * 192 + ci]);
}
__global__ __launch_bounds__(256) void prep_all_kernel(
    const float* __restrict__ conv1_w, short* __restrict__ WF1,
    const float* __restrict__ conv2_w, short* __restrict__ WF2,
    const float* __restrict__ conv3_w, short* __restrict__ W3F,
    const float* __restrict__ qkv_w,   short* __restrict__ WQ,
    const float* __restrict__ proj_w,  short* __restrict__ WP,
    const float* __restrict__ fc1_w,   short* __restrict__ WG1,
    const float* __restrict__ fc2_w,   short* __restrict__ WG2)
{
    int o = blockIdx.x * 256 + threadIdx.x;
    if (o < 331776)            { prep_wf(conv1_w, WF1, o); return; }
    o -= 331776;
    if (o < 331776)            { prep_wf(conv2_w, WF2, o); return; }
    o -= 331776;
    if (o < 36864)             { prep_w3f(conv3_w, W3F, o); return; }
    o -= 36864;
    if (o < 110592)            { prep_wgemm(qkv_w, WQ, 192, 576, o); return; }
    o -= 110592;
    if (o < 36864)             { prep_wgemm(proj_w, WP, 192, 192, o); return; }
    o -= 36864;
    if (o < 73728)             { prep_wgemm(fc1_w, WG1, 192, 384, o); return; }
    o -= 73728;
    if (o < 73728)             { prep_wgemm(fc2_w, WG2, 384, 192, o); return; }
}
constexpr int PREP_TOTAL = 331776 * 2 + 36864 + 110592 + 36864 + 73728 * 2;  // 995328

// ---------------- conv3x3 (4x4 patches) + groupnorm (+silu), MFMA ----------------
// 4 patches/block, 256 threads. Wave w owns nt-tiles 3w..3w+2 (B-frags held in regs,
// reused across 4 patches) — measured-best decomposition (rounds 9/10/13).
template <bool FIRST>
__global__ __launch_bounds__(256, 4) void conv_mfma_kernel(
    const void* __restrict__ srcv, const short* __restrict__ wf,
    const float* __restrict__ bias, const float* __restrict__ gng,
    const float* __restrict__ gnb, bf16* __restrict__ dst)
{
    __shared__ short xs[13056];          // 4 patches * 17 rows * 384B (row 16 = zeros), swizzled
    __shared__ float gsum[4][6], gsum2[4][6], gmu[4][6], grs[4][6];
    const int tid  = threadIdx.x;
    const int lane = tid & 63, wid = tid >> 6;
    const int n0   = blockIdx.x * 4;

    if (tid < 24) { gsum[tid / 6][tid % 6] = 0.f; gsum2[tid / 6][tid % 6] = 0.f; }
    for (int u = tid; u < 4 * 192; u += 256) {       // zero rows
        int q = u / 192;
        xs[q * 3264 + 3072 + (u % 192)] = 0;
    }

    if constexpr (FIRST) {
        const float4* sp = (const float4*)((const float*)srcv + (size_t)n0 * 3072);
        #pragma unroll
        for (int u = 0; u < 12; ++u) {
            int idx = u * 256 + tid;                 // float4 index, 3072 total
            float4 v = sp[idx];
            int q = idx / 768;
            int li = (idx % 768) * 4;                // li = ci*16 + p
            int ci = li >> 4, p0 = li & 15;
            float vv[4] = { v.x, v.y, v.z, v.w };
            #pragma unroll
            for (int k = 0; k < 4; ++k) {
                int row = p0 + k;
                int ba = q * 6528 + ((row * 384 + ci * 2) ^ ((row & 7) << 4));
                *(short*)((char*)xs + ba) = (short)f2bf(vv[k]);
            }
        }
    } else {
        const s8v* sp8 = (const s8v*)((const bf16*)srcv + (size_t)n0 * 3072);
        #pragma unroll
        for (int u = 0; u < 6; ++u) {
            int li = u * 256 + tid;                  // 1536 s8v units
            int r = li / 24, ch = li % 24;
            int q = r >> 4, rl = r & 15;
            s8v val = sp8[li];
            int ba = q * 6528 + ((rl * 384 + ch * 16) ^ ((rl & 7) << 4));
            *(s8v*)((char*)xs + ba) = val;
        }
    }
    __syncthreads();

    const int ntb = wid * 3;
    const int cl  = lane & 15;
    const int kg  = lane >> 4;
    f32x4 acc[3][4];
    #pragma unroll
    for (int t = 0; t < 3; ++t) {
        float bv = bias[(ntb + t) * 16 + cl];
        #pragma unroll
        for (int q = 0; q < 4; ++q) acc[t][q] = (f32x4){ bv, bv, bv, bv };
    }

    const int pi = cl >> 2, pj = cl & 3;
    const s8v* wf8 = (const s8v*)wf;

    for (int tap = 0; tap < 9; ++tap) {
        const int di = tap / 3, dj = tap % 3;
        const int ii = pi + di - 1, jj = pj + dj - 1;
        const bool valid = (ii >= 0 && ii < 4 && jj >= 0 && jj < 4);
        const int nr  = valid ? (ii * 4 + jj) : 16;   // row 16 = zero row
        const int rb  = nr * 384;
        const int swz = (nr & 7) << 4;
        #pragma unroll
        for (int ks = 0; ks < 6; ++ks) {
            const s8v* bp = wf8 + (size_t)((tap * 6 + ks) * 12) * 64 + lane;
            s8v b0 = bp[(ntb + 0) * 64];
            s8v b1 = bp[(ntb + 1) * 64];
            s8v b2 = bp[(ntb + 2) * 64];
            const int inner = (rb + ks * 64 + kg * 16) ^ swz;
            #pragma unroll
            for (int q = 0; q < 4; ++q) {
                s8v a = *(const s8v*)((const char*)xs + q * 6528 + inner);
                acc[0][q] = __builtin_amdgcn_mfma_f32_16x16x32_bf16(a, b0, acc[0][q], 0, 0, 0);
                acc[1][q] = __builtin_amdgcn_mfma_f32_16x16x32_bf16(a, b1, acc[1][q], 0, 0, 0);
                acc[2][q] = __builtin_amdgcn_mfma_f32_16x16x32_bf16(a, b2, acc[2][q], 0, 0, 0);
            }
        }
    }

    #pragma unroll
    for (int t = 0; t < 3; ++t) {
        const int g = (ntb + t) >> 1;
        #pragma unroll
        for (int q = 0; q < 4; ++q) {
            f32x4 A = acc[t][q];
            float s  = A[0] + A[1] + A[2] + A[3];
            float s2 = A[0]*A[0] + A[1]*A[1] + A[2]*A[2] + A[3]*A[3];
            #pragma unroll
            for (int off = 32; off; off >>= 1) { s += __shfl_xor(s, off); s2 += __shfl_xor(s2, off); }
            if (lane == 0) { atomicAdd(&gsum[q][g], s); atomicAdd(&gsum2[q][g], s2); }
        }
    }
    __syncthreads();
    if (tid < 24) {
        int q = tid / 6, g = tid % 6;
        float mu  = gsum[q][g] * (1.f / 512.f);
        float var = gsum2[q][g] * (1.f / 512.f) - mu * mu;
        gmu[q][g] = mu; grs[q][g] = rsqrtf(var + 1e-5f);
    }
    __syncthreads();

    if constexpr (FIRST) {
        // normalize + SiLU -> swizzled LDS [64 tok][192 co], then coalesced 16B stores
        #pragma unroll
        for (int t = 0; t < 3; ++t) {
            const int co = (ntb + t) * 16 + cl, g = (ntb + t) >> 1;
            const float gg = gng[co], gb = gnb[co];
            #pragma unroll
            for (int q = 0; q < 4; ++q) {
                const float mu = gmu[q][g], rs = grs[q][g];
                #pragma unroll
                for (int r = 0; r < 4; ++r) {
                    float v = (acc[t][q][r] - mu) * rs * gg + gb;
                    v = v / (1.f + __expf(-v));      // silu (fast exp)
                    int row = q * 16 + kg * 4 + r;
                    int ba = (row * 384 + co * 2) ^ ((row & 7) << 4);
                    *(short*)((char*)xs + ba) = (short)f2bf(v);
                }
            }
        }
        __syncthreads();
        bf16* dp = dst + (size_t)n0 * 3072;          // token-major [tok][192], contiguous block
        #pragma unroll
        for (int u = 0; u < 6; ++u) {
            int li = u * 256 + tid;                  // 1536 s8v units
            int row = li / 24, g2 = li % 24;
            int ba = (row * 384 + g2 * 16) ^ ((row & 7) << 4);
            s8v val = *(const s8v*)((const char*)xs + ba);
            *(s8v*)(dp + (size_t)row * 192 + g2 * 8) = val;
        }
    } else {
        #pragma unroll
        for (int t = 0; t < 3; ++t) {
            const int co = (ntb + t) * 16 + cl, g = (ntb + t) >> 1;
            const float gg = gng[co], gb = gnb[co];
            #pragma unroll
            for (int q = 0; q < 4; ++q) {
                const float mu = gmu[q][g], rs = grs[q][g];
                #pragma unroll
                for (int r = 0; r < 4; ++r) {
                    float v = (acc[t][q][r] - mu) * rs * gg + gb;
                    xs[q * 3072 + co * 16 + kg * 4 + r] = (short)f2bf(v);
                }
            }
        }
        __syncthreads();
        s4v* dp = (s4v*)(dst + (size_t)n0 * 3072);
        const s4v* sps = (const s4v*)xs;
        #pragma unroll
        for (int u = 0; u < 12; ++u) {
            dp[u * 256 + tid] = sps[u * 256 + tid];
        }
    }
}

// ---------------- MFMA GEMM, single-pass over an N-range, LDS-transpose epilogue ----
template <bool RES, bool GELU_ACT, bool LN, bool QKVOUT, int NKT>
__global__ __launch_bounds__(256) void gemm_mfma_kernel(
    const bf16* __restrict__ A, const short* __restrict__ wfb,
    const float* __restrict__ bias, const bf16* __restrict__ res,
    void* __restrict__ out, int N,
    const float* __restrict__ lng, const float* __restrict__ lnb)
{
    __shared__ short ls[8192];           // [128 rows][64 cols] 2B, XOR-swizzled
    const int tid = threadIdx.x, lane = tid & 63, wid = tid >> 6;
    const int m0 = blockIdx.x * 128;
    const int cl = lane & 15, kg = lane >> 4;
    constexpr int K = NKT * 32;
    const int ntiles = N >> 4;
    const int ntsec = ntiles / gridDim.y;
    const int ntbeg = blockIdx.y * ntsec;

    // load this thread's two A-rows (rows r0, r0+16) as fragments, once
    s8v af0[NKT], af1[NKT];
    const int r0 = m0 + wid * 32 + cl;
    #pragma unroll
    for (int kt = 0; kt < NKT; ++kt) {
        af0[kt] = *(const s8v*)(A + (size_t)r0 * K + kt * 32 + kg * 8);
        af1[kt] = *(const s8v*)(A + (size_t)(r0 + 16) * K + kt * 32 + kg * 8);
    }
    if constexpr (LN) {
        static_assert(!LN || NKT == 6, "LN requires K==192");
        #pragma unroll
        for (int r = 0; r < 2; ++r) {
            s8v* af = r ? af1 : af0;
            float s = 0.f, s2 = 0.f;
            #pragma unroll
            for (int kt = 0; kt < NKT; ++kt)
                #pragma unroll
                for (int j = 0; j < 8; ++j) {
                    float v = bf2f(af[kt][j]);
                    s += v; s2 += v * v;
                }
            s  += __shfl_xor(s, 16);  s2 += __shfl_xor(s2, 16);
            s  += __shfl_xor(s, 32);  s2 += __shfl_xor(s2, 32);
            const float mu = s * (1.f / 192.f);
            const float rs = rsqrtf(s2 * (1.f / 192.f) - mu * mu + 1e-5f);
            #pragma unroll
            for (int kt = 0; kt < NKT; ++kt) {
                const float* gp = lng + kt * 32 + kg * 8;
                const float* bp = lnb + kt * 32 + kg * 8;
                #pragma unroll
                for (int j = 0; j < 8; ++j) {
                    float v = (bf2f(af[kt][j]) - mu) * rs * gp[j] + bp[j];
                    af[kt][j] = (short)f2bf(v);
                }
            }
        }
    }

    const s8v* wf8 = (const s8v*)wfb;
    for (int nt0 = ntbeg; nt0 < ntbeg + ntsec; nt0 += 4) {
        const int n0 = nt0 * 16;
        f32x4 acc[2][4];
        #pragma unroll
        for (int nf = 0; nf < 4; ++nf) {
            float bv = bias[n0 + nf * 16 + cl];
            acc[0][nf] = (f32x4){ bv, bv, bv, bv };
            acc[1][nf] = (f32x4){ bv, bv, bv, bv };
        }
        #pragma unroll
        for (int kt = 0; kt < NKT; ++kt) {
            #pragma unroll
            for (int nf = 0; nf < 4; ++nf) {
                s8v b = wf8[(size_t)(kt * ntiles + nt0 + nf) * 64 + lane];
                acc[0][nf] = __builtin_amdgcn_mfma_f32_16x16x32_bf16(af0[kt], b, acc[0][nf], 0, 0, 0);
                acc[1][nf] = __builtin_amdgcn_mfma_f32_16x16x32_bf16(af1[kt], b, acc[1][nf], 0, 0, 0);
            }
        }

        // ---- epilogue: acc -> LDS (2B, swizzled) -> 16B coalesced stores ----
        __syncthreads();                 // previous chunk's readback done
        #pragma unroll
        for (int rf = 0; rf < 2; ++rf) {
            #pragma unroll
            for (int nf = 0; nf < 4; ++nf) {
                const int lcol = nf * 16 + cl;
                #pragma unroll
                for (int r = 0; r < 4; ++r) {
                    const int lrow = wid * 32 + rf * 16 + kg * 4 + r;
                    float v = acc[rf][nf][r];
                    if (GELU_ACT) v = 0.5f * v * (1.f + erff(v * 0.70710678118f));
                    short sv;
                    if constexpr (QKVOUT) sv = __builtin_bit_cast(short, (_Float16)v);
                    else                  sv = (short)f2bf(v);
                    int ba = (lrow * 128 + lcol * 2) ^ ((lrow & 7) << 4);
                    *(short*)((char*)ls + ba) = sv;
                }
            }
        }
        __syncthreads();
        #pragma unroll
        for (int p = 0; p < 4; ++p) {
            const int lrow = p * 32 + (tid >> 3);
            const int g = tid & 7;
            int ba = (lrow * 128 + g * 16) ^ ((lrow & 7) << 4);
            s8v val = *(const s8v*)((const char*)ls + ba);
            const int row = m0 + lrow;
            const int col0 = n0 + g * 8;
            if constexpr (QKVOUT) {
                const int sec = n0 / 192;        // 64-col chunk never crosses a section
                const int c0 = col0 - sec * 192, h = c0 >> 5, d0 = c0 & 31;
                const int bb2 = row / TOKPB, t = row - bb2 * TOKPB;
                *(s8v*)((_Float16*)out + (size_t)sec * SECSZ +
                        ((size_t)(bb2 * 6 + h) * TOKPB + t) * 32 + d0) = val;
            } else if constexpr (RES) {
                s8v rv = *(const s8v*)(res + (size_t)row * N + col0);
                s8v ov;
                #pragma unroll
                for (int e = 0; e < 8; ++e) ov[e] = (short)f2bf(bf2f(val[e]) + bf2f(rv[e]));
                *(s8v*)((bf16*)out + (size_t)row * N + col0) = ov;
            } else {
                *(s8v*)((bf16*)out + (size_t)row * N + col0) = val;
            }
        }
    }
}

// ---------------- overlapping-window attention (f16 head-major inputs) ----------------
constexpr int HSTR = 1160;   // per-head LDS stride in shorts (36*32 + 8 pad)
__global__ __launch_bounds__(128) void attn_kernel(
    const _Float16* __restrict__ qf, const float* __restrict__ rpb,
    bf16* __restrict__ out)
{
    __shared__ short kh[6 * HSTR];
    __shared__ short vh[6 * HSTR];
    const int w = blockIdx.x;
    const int b = w / (NHW * NHW), wi = w % (NHW * NHW);
    const int nhi = wi / NHW, nwi = wi % NHW;
    const int tid = threadIdx.x;
    const int r0 = nhi * 4 - 1, c0 = nwi * 4 - 1;
    const _Float16* kfb = qf + SECSZ;
    const _Float16* vfb = qf + 2 * SECSZ;

    // stage K and V: 2*864 units of 16B, pure copy (no conversion)
    #pragma unroll
    for (int it = 0; it < 14; ++it) {
        int v = tid + it * 128;
        if (v < 1728) {
            int kv = v >= 864 ? 1 : 0;
            int u = v - kv * 864;
            int h = u / 144, rem = u % 144, kj = rem >> 2, d0 = (rem & 3) * 8;
            int rr = r0 + kj / 6, cc = c0 + kj % 6;
            s8v val = { 0, 0, 0, 0, 0, 0, 0, 0 };
            if (rr >= 0 && rr < CH && cc >= 0 && cc < CW) {
                const _Float16* src = kv ? vfb : kfb;
                val = *(const s8v*)(src + ((size_t)(b * 6 + h) * TOKPB + rr * CW + cc) * 32 + d0);
            }
            short* dst = kv ? vh : kh;
            *(s8v*)(dst + h * HSTR + kj * 32 + d0) = val;
        }
    }
    __syncthreads();

    if (tid < 96) {
        const int h = tid >> 4, qi = tid & 15;
        const int qr = nhi * 4 + (qi >> 2), qc = nwi * 4 + (qi & 3);
        const _Float16* qp = qf + ((size_t)(b * 6 + h) * TOKPB + qr * CW + qc) * 32;
        h2 qh[16];
        #pragma unroll
        for (int u = 0; u < 4; ++u) {
            uint4 qa = *(const uint4*)(qp + u * 8);
            qh[u * 4 + 0] = __builtin_bit_cast(h2, qa.x);
            qh[u * 4 + 1] = __builtin_bit_cast(h2, qa.y);
            qh[u * 4 + 2] = __builtin_bit_cast(h2, qa.z);
            qh[u * 4 + 3] = __builtin_bit_cast(h2, qa.w);
        }

        float sc[36];
        const short* khb = kh + h * HSTR;
        #pragma unroll
        for (int kj = 0; kj < 36; ++kj) {
            const uint4* kp = (const uint4*)(khb + kj * 32);
            uint4 k0 = kp[0], k1 = kp[1], k2 = kp[2], k3 = kp[3];
            unsigned kwv[16] = { k0.x, k0.y, k0.z, k0.w, k1.x, k1.y, k1.z, k1.w,
                                 k2.x, k2.y, k2.z, k2.w, k3.x, k3.y, k3.z, k3.w };
            float a0 = 0.f, a1 = 0.f, a2 = 0.f, a3 = 0.f;
            #pragma unroll
            for (int e = 0; e < 4; ++e) {
                a0 = __builtin_amdgcn_fdot2(__builtin_bit_cast(h2, kwv[4*e+0]), qh[4*e+0], a0, false);
                a1 = __builtin_amdgcn_fdot2(__builtin_bit_cast(h2, kwv[4*e+1]), qh[4*e+1], a1, false);
                a2 = __builtin_amdgcn_fdot2(__builtin_bit_cast(h2, kwv[4*e+2]), qh[4*e+2], a2, false);
                a3 = __builtin_amdgcn_fdot2(__builtin_bit_cast(h2, kwv[4*e+3]), qh[4*e+3], a3, false);
            }
            const int rel0 = kj / 6 - (qi >> 2) + 3;
            const int rel1 = kj % 6 - (qi & 3) + 3;
            sc[kj] = ((a0 + a1) + (a2 + a3)) * 0.17677669529f + rpb[(rel0 * 9 + rel1) * 6 + h];
        }
        float mx = -1e30f;
        #pragma unroll
        for (int kj = 0; kj < 36; ++kj) mx = fmaxf(mx, sc[kj]);
        float sum = 0.f;
        #pragma unroll
        for (int kj = 0; kj < 36; ++kj) { sc[kj] = __expf(sc[kj] - mx); sum += sc[kj]; }
        const float inv = 1.f / sum;

        h2 o2[16];
        #pragma unroll
        for (int e = 0; e < 16; ++e) o2[e] = (h2){ (_Float16)0.f, (_Float16)0.f };
        const short* vhb = vh + h * HSTR;
        #pragma unroll
        for (int kj = 0; kj < 36; ++kj) {
            const uint4* vp = (const uint4*)(vhb + kj * 32);
            uint4 v0 = vp[0], v1 = vp[1], v2 = vp[2], v3 = vp[3];
            unsigned vwv[16] = { v0.x, v0.y, v0.z, v0.w, v1.x, v1.y, v1.z, v1.w,
                                 v2.x, v2.y, v2.z, v2.w, v3.x, v3.y, v3.z, v3.w };
            const _Float16 ph = (_Float16)sc[kj];
            const h2 ph2 = { ph, ph };
            #pragma unroll
            for (int e = 0; e < 16; ++e)
                o2[e] = __builtin_bit_cast(h2, vwv[e]) * ph2 + o2[e];
        }
        bf16* op = out + ((size_t)(b * TOKPB + qr * CW + qc)) * 192 + h * 32;
        #pragma unroll
        for (int u = 0; u < 8; ++u) {
            s4v pk;
            #pragma unroll
            for (int e = 0; e < 2; ++e) {
                h2 ov = o2[u * 2 + e];
                pk[2 * e]     = (short)f2bf((float)ov[0] * inv);
                pk[2 * e + 1] = (short)f2bf((float)ov[1] * inv);
            }
            *(s4v*)((bf16*)op + u * 4) = pk;
        }
    }
}

// ---------------- final: out = relu(C2 + conv1x1(x)), MFMA ----------------
__global__ __launch_bounds__(256, 4) void final_mfma_kernel(
    const float* __restrict__ x, const short* __restrict__ w3f,
    const float* __restrict__ b3, const bf16* __restrict__ c2,
    float* __restrict__ out)
{
    __shared__ short xs2[12288];      // [64 pix][192 ci] bf16, row-swizzled
    const int pix0 = blockIdx.x * 64;
    const int b    = blockIdx.y;
    const int tid = threadIdx.x, lane = tid & 63, wid = tid >> 6;
    const int cl = lane & 15, kg = lane >> 4;
    const float* xb = x + (size_t)b * (192 * TOKPB);

    #pragma unroll
    for (int u = 0; u < 12; ++u) {
        int idx = u * 256 + tid;                  // 3072 float4
        int ci = idx >> 4, p4 = (idx & 15) << 2;
        float4 v = *(const float4*)(xb + (size_t)ci * TOKPB + pix0 + p4);
        float vv[4] = { v.x, v.y, v.z, v.w };
        #pragma unroll
        for (int k = 0; k < 4; ++k) {
            int row = p4 + k;
            int ba = (row * 384 + ci * 2) ^ ((row & 7) << 4);
            *(short*)((char*)xs2 + ba) = (short)f2bf(vv[k]);
        }
    }
    __syncthreads();

    const int ctb = wid * 3;
    f32x4 acc[3][4] = {};
    const s8v* wf8 = (const s8v*)w3f;

    #pragma unroll
    for (int kt = 0; kt < 6; ++kt) {
        s8v a0 = wf8[(size_t)(kt * 12 + ctb + 0) * 64 + lane];
        s8v a1 = wf8[(size_t)(kt * 12 + ctb + 1) * 64 + lane];
        s8v a2 = wf8[(size_t)(kt * 12 + ctb + 2) * 64 + lane];
        #pragma unroll
        for (int pt = 0; pt < 4; ++pt) {
            int row = pt * 16 + cl;
            int ba = (row * 384 + kt * 64 + kg * 16) ^ ((row & 7) << 4);
            s8v bfr = *(const s8v*)((const char*)xs2 + ba);
            acc[0][pt] = __builtin_amdgcn_mfma_f32_16x16x32_bf16(a0, bfr, acc[0][pt], 0, 0, 0);
            acc[1][pt] = __builtin_amdgcn_mfma_f32_16x16x32_bf16(a1, bfr, acc[1][pt], 0, 0, 0);
            acc[2][pt] = __builtin_amdgcn_mfma_f32_16x16x32_bf16(a2, bfr, acc[2][pt], 0, 0, 0);
        }
    }

    #pragma unroll
    for (int t = 0; t < 3; ++t) {
        #pragma unroll
        for (int r = 0; r < 4; ++r) {
            const int co = (ctb + t) * 16 + kg * 4 + r;
            const float bb = b3[co];
            const size_t rowbase = (size_t)b * (192 * TOKPB) + (size_t)co * TOKPB + pix0;
            #pragma unroll
            for (int pt = 0; pt < 4; ++pt) {
                const size_t f = rowbase + pt * 16 + cl;
                float v = acc[t][pt][r] + bb + bf2f(__builtin_bit_cast(short, c2[f]));
                out[f] = fmaxf(v, 0.f);
            }
        }
    }
}

// ---------------- host launch ----------------
extern "C" void kernel_launch(void* const* d_in, const int* in_sizes, int n_in,
                              void* d_out, int out_size, void* d_ws, size_t ws_size,
                              hipStream_t stream)
{
    if (ws_size < WS_NEEDED) return;

    const float* x       = (const float*)d_in[0];
    const float* conv1_w = (const float*)d_in[1];
    const float* conv1_b = (const float*)d_in[2];
    const float* gn1_g   = (const float*)d_in[3];
    const float* gn1_b   = (const float*)d_in[4];
    const float* conv2_w = (const float*)d_in[5];
    const float* conv2_b = (const float*)d_in[6];
    const float* gn2_g   = (const float*)d_in[7];
    const float* gn2_b   = (const float*)d_in[8];
    const float* conv3_w = (const float*)d_in[9];
    const float* conv3_b = (const float*)d_in[10];
    const float* ln1_g   = (const float*)d_in[11];
    const float* ln1_b   = (const float*)d_in[12];
    const float* qkv_w   = (const float*)d_in[13];
    const float* qkv_b   = (const float*)d_in[14];
    const float* rpb     = (const float*)d_in[15];
    const float* proj_w  = (const float*)d_in[16];
    const float* proj_b  = (const float*)d_in[17];
    const float* ln2_g   = (const float*)d_in[18];
    const float* ln2_b   = (const float*)d_in[19];
    const float* fc1_w   = (const float*)d_in[20];
    const float* fc1_b   = (const float*)d_in[21];
    const float* fc2_w   = (const float*)d_in[22];
    const float* fc2_b   = (const float*)d_in[23];

    char* wsb = (char*)d_ws;
    bf16*  T0  = (bf16*)(wsb + B_T0);
    _Float16* QF = (_Float16*)(wsb + B_P2);   // Q/K/V f16 sections; later HID bf16
    bf16*  HID = (bf16*)(wsb + B_P2);
    bf16*  P3  = (bf16*)(wsb + B_P3);
    bf16*  P4  = (bf16*)(wsb + B_P4);
    short* WF1 = (short*)(wsb + B_WF1);
    short* WF2 = (short*)(wsb + B_WF2);
    short* W3F = (short*)(wsb + B_W3F);
    short* WQ  = (short*)(wsb + B_WQ);
    short* WP  = (short*)(wsb + B_WP);
    short* WG1 = (short*)(wsb + B_WG1);
    short* WG2 = (short*)(wsb + B_WG2);
    float* OUT = (float*)d_out;

    // fused weight prep (single launch)
    prep_all_kernel<<<(PREP_TOTAL + 255) / 256, 256, 0, stream>>>(
        conv1_w, WF1, conv2_w, WF2, conv3_w, W3F, qkv_w, WQ, proj_w, WP, fc1_w, WG1, fc2_w, WG2);

    // stage A: conv1 + gn1 + silu -> T0 (token layout, bf16); measured-best conv shape
    conv_mfma_kernel<true><<<NPATCH / 4, 256, 0, stream>>>(x, WF1, conv1_b, gn1_g, gn1_b, T0);
    // stage C: LN1 (fused, once) + qkv gemm -> QF/KF/VF (f16 head-major); grid.y = 1
    gemm_mfma_kernel<false, false, true, true, 6><<<dim3(MTOK / 128, 1), 256, 0, stream>>>(
        T0, WQ, qkv_b, nullptr, QF, 576, ln1_g, ln1_b);
    // stage D: attention -> P3 (ATT, bf16 token layout)
    attn_kernel<<<NPATCH, 128, 0, stream>>>(QF, rpb, P3);
    // stage E: proj + shortcut(T0) -> P4 (OMID); grid.y = 1 (measured-best)
    gemm_mfma_kernel<true, false, false, false, 6><<<dim3(MTOK / 128, 1), 256, 0, stream>>>(
        P3, WP, proj_b, T0, P4, 192, nullptr, nullptr);
    // stage G: LN2 (fused) + fc1 + gelu -> HID; grid.y = 1
    gemm_mfma_kernel<false, true, true, false, 6><<<dim3(MTOK / 128, 1), 256, 0, stream>>>(
        P4, WG1, fc1_b, nullptr, HID, 384, ln2_g, ln2_b);
    // stage H: fc2 + residual(OMID P4) -> P3 (OCAB, bf16 token layout); grid.y = 1
    gemm_mfma_kernel<true, false, false, false, 12><<<dim3(MTOK / 128, 1), 256, 0, stream>>>(
        HID, WG2, fc2_b, P4, P3, 192, nullptr, nullptr);
    // stage I: conv2 + gn2 (reads P3 bf16 token layout) -> P4 (C2, bf16 patch-flat)
    conv_mfma_kernel<false><<<NPATCH / 4, 256, 0, stream>>>(P3, WF2, conv2_b, gn2_g, gn2_b, P4);
    // stage J: out = relu(C2 + conv1x1(x)) -> d_out, MFMA
    final_mfma_kernel<<<dim3(TOKPB / 64, CB), 256, 0, stream>>>(x, W3F, conv3_b, P4, OUT);
}

// Round 15
// 525.622 us; speedup vs baseline: 1.7746x; 1.0962x over previous
//
#include <hip/hip_runtime.h>
#include <hip/hip_bf16.h>
#include <math.h>

typedef __hip_bfloat16 bf16;
typedef __attribute__((ext_vector_type(8))) short s8v;
typedef __attribute__((ext_vector_type(4))) short s4v;
typedef __attribute__((ext_vector_type(4))) float f32x4;
typedef __attribute__((ext_vector_type(2))) _Float16 h2;

// ---------------- problem constants ----------------
constexpr int CB   = 2;            // batch
constexpr int CH   = 224, CW = 224;
constexpr int NHW  = 56;           // H/WS
constexpr int NPATCH = CB * NHW * NHW;   // 6272
constexpr int TOKPB  = CH * CW;          // 50176 tokens per batch
constexpr int MTOK   = CB * TOKPB;       // 100352 rows
constexpr size_t SECSZ = 19267584;       // elems per q/k/v f16 section

// ---------------- ws layout (BYTE offsets) ----------------
constexpr size_t B_T0  = 0;                         // 19267584 bf16
constexpr size_t B_P2  = B_T0 + 38535168;           // QF/KF/VF f16 (3x38.5MB); later HID bf16
constexpr size_t B_P3  = B_P2 + 115605504;          // 19267584 bf16 (OCAB)
constexpr size_t B_P4  = B_P3 + 38535168;           // 19267584 bf16 (OMID -> C2)
constexpr size_t B_WF1 = B_P4 + 38535168;           // conv1 frag weights
constexpr size_t B_WF2 = B_WF1 + 1327104;           // conv2 frag weights
constexpr size_t B_W3F = B_WF2 + 1327104;           // conv3 1x1 frag weights
constexpr size_t B_WQ  = B_W3F + 147456;            // qkv_w frag
constexpr size_t B_WP  = B_WQ + 221184;             // proj_w frag
constexpr size_t B_WG1 = B_WP + 73728;              // fc1_w frag
constexpr size_t B_WG2 = B_WG1 + 147456;            // fc2_w frag
constexpr size_t WS_NEEDED = B_WG2 + 147456;        // 234,602,496 B

// ---------------- type helpers ----------------
__device__ __forceinline__ float ldf(const float* p) { return *p; }
__device__ __forceinline__ float ldf(const bf16* p)  { return __bfloat162float(*p); }
__device__ __forceinline__ void  stf(float* p, float v) { *p = v; }
__device__ __forceinline__ void  stf(bf16* p, float v)  { *p = __float2bfloat16(v); }
__device__ __forceinline__ unsigned short f2bf(float f) {
    unsigned u = __builtin_bit_cast(unsigned, f);
    unsigned r = (u + 0x7fffu + ((u >> 16) & 1u)) >> 16;
    return (unsigned short)r;
}
__device__ __forceinline__ float bf2f(short s) {
    unsigned u = ((unsigned)(unsigned short)s) << 16;
    return __builtin_bit_cast(float, u);
}

// ---------------- fused weight pre-pack (one launch) ----------------
__device__ __forceinline__ void prep_wf(const float* __restrict__ w, short* __restrict__ wf, int o) {
    int within = o & 511, frag = o >> 9;
    int l = within >> 3, j = within & 7;
    int nt = frag % 12, t2 = frag / 12, ks = t2 % 6, tap = t2 / 6;
    int co = nt * 16 + (l & 15);
    int ci = ks * 32 + (l >> 4) * 8 + j;
    wf[o] = (short)f2bf(w[(co * 192 + ci) * 9 + tap]);
}
__device__ __forceinline__ void prep_wgemm(const float* __restrict__ w, short* __restrict__ wf,
                                           int K, int N, int o) {
    int j = o & 7, l = (o >> 3) & 63, f = o >> 9;
    int ntiles = N >> 4;
    int kt = f / ntiles, nt = f % ntiles;
    int k = kt * 32 + (l >> 4) * 8 + j;
    int col = nt * 16 + (l & 15);
    wf[o] = (short)f2bf(w[(size_t)k * N + col]);
}
__device__ __forceinline__ void prep_w3f(const float* __restrict__ w, short* __restrict__ wf, int o) {
    int j = o & 7, l = (o >> 3) & 63, f = o >> 9;   // f = kt*12 + ct
    int kt = f / 12, ct = f % 12;
    int co = ct * 16 + (l & 15);
    int ci = kt * 32 + (l >> 4) * 8 + j;
    wf[o] = (short)f2bf(w[co * 192 + ci]);
}
__global__ __launch_bounds__(256) void prep_all_kernel(
    const float* __restrict__ conv1_w, short* __restrict__ WF1,
    const float* __restrict__ conv2_w, short* __restrict__ WF2,
    const float* __restrict__ conv3_w, short* __restrict__ W3F,
    const float* __restrict__ qkv_w,   short* __restrict__ WQ,
    const float* __restrict__ proj_w,  short* __restrict__ WP,
    const float* __restrict__ fc1_w,   short* __restrict__ WG1,
    const float* __restrict__ fc2_w,   short* __restrict__ WG2)
{
    int o = blockIdx.x * 256 + threadIdx.x;
    if (o < 331776)            { prep_wf(conv1_w, WF1, o); return; }
    o -= 331776;
    if (o < 331776)            { prep_wf(conv2_w, WF2, o); return; }
    o -= 331776;
    if (o < 36864)             { prep_w3f(conv3_w, W3F, o); return; }
    o -= 36864;
    if (o < 110592)            { prep_wgemm(qkv_w, WQ, 192, 576, o); return; }
    o -= 110592;
    if (o < 36864)             { prep_wgemm(proj_w, WP, 192, 192, o); return; }
    o -= 36864;
    if (o < 73728)             { prep_wgemm(fc1_w, WG1, 192, 384, o); return; }
    o -= 73728;
    if (o < 73728)             { prep_wgemm(fc2_w, WG2, 384, 192, o); return; }
}
constexpr int PREP_TOTAL = 331776 * 2 + 36864 + 110592 + 36864 + 73728 * 2;  // 995328

// ---------------- conv3x3 (4x4 patches) + groupnorm (+silu), MFMA ----------------
template <bool FIRST>
__global__ __launch_bounds__(256, 4) void conv_mfma_kernel(
    const void* __restrict__ srcv, const short* __restrict__ wf,
    const float* __restrict__ bias, const float* __restrict__ gng,
    const float* __restrict__ gnb, bf16* __restrict__ dst)
{
    __shared__ short xs[13056];          // 4 patches * 17 rows * 384B (row 16 = zeros), swizzled
    __shared__ float gsum[4][6], gsum2[4][6], gmu[4][6], grs[4][6];
    const int tid  = threadIdx.x;
    const int lane = tid & 63, wid = tid >> 6;
    const int n0   = blockIdx.x * 4;

    if (tid < 24) { gsum[tid / 6][tid % 6] = 0.f; gsum2[tid / 6][tid % 6] = 0.f; }
    for (int u = tid; u < 4 * 192; u += 256) {       // zero rows
        int q = u / 192;
        xs[q * 3264 + 3072 + (u % 192)] = 0;
    }

    if constexpr (FIRST) {
        const float4* sp = (const float4*)((const float*)srcv + (size_t)n0 * 3072);
        #pragma unroll
        for (int u = 0; u < 12; ++u) {
            int idx = u * 256 + tid;                 // float4 index, 3072 total
            float4 v = sp[idx];
            int q = idx / 768;
            int li = (idx % 768) * 4;                // li = ci*16 + p
            int ci = li >> 4, p0 = li & 15;
            float vv[4] = { v.x, v.y, v.z, v.w };
            #pragma unroll
            for (int k = 0; k < 4; ++k) {
                int row = p0 + k;
                int ba = q * 6528 + ((row * 384 + ci * 2) ^ ((row & 7) << 4));
                *(short*)((char*)xs + ba) = (short)f2bf(vv[k]);
            }
        }
    } else {
        const s8v* sp8 = (const s8v*)((const bf16*)srcv + (size_t)n0 * 3072);
        #pragma unroll
        for (int u = 0; u < 6; ++u) {
            int li = u * 256 + tid;                  // 1536 s8v units
            int r = li / 24, ch = li % 24;
            int q = r >> 4, rl = r & 15;
            s8v val = sp8[li];
            int ba = q * 6528 + ((rl * 384 + ch * 16) ^ ((rl & 7) << 4));
            *(s8v*)((char*)xs + ba) = val;
        }
    }
    __syncthreads();

    const int ntb = wid * 3;
    const int cl  = lane & 15;
    const int kg  = lane >> 4;
    f32x4 acc[3][4];
    #pragma unroll
    for (int t = 0; t < 3; ++t) {
        float bv = bias[(ntb + t) * 16 + cl];
        #pragma unroll
        for (int q = 0; q < 4; ++q) acc[t][q] = (f32x4){ bv, bv, bv, bv };
    }

    const int pi = cl >> 2, pj = cl & 3;
    const s8v* wf8 = (const s8v*)wf;

    for (int tap = 0; tap < 9; ++tap) {
        const int di = tap / 3, dj = tap % 3;
        const int ii = pi + di - 1, jj = pj + dj - 1;
        const bool valid = (ii >= 0 && ii < 4 && jj >= 0 && jj < 4);
        const int nr  = valid ? (ii * 4 + jj) : 16;   // row 16 = zero row
        const int rb  = nr * 384;
        const int swz = (nr & 7) << 4;
        #pragma unroll
        for (int ks = 0; ks < 6; ++ks) {
            const s8v* bp = wf8 + (size_t)((tap * 6 + ks) * 12) * 64 + lane;
            s8v b0 = bp[(ntb + 0) * 64];
            s8v b1 = bp[(ntb + 1) * 64];
            s8v b2 = bp[(ntb + 2) * 64];
            const int inner = (rb + ks * 64 + kg * 16) ^ swz;
            #pragma unroll
            for (int q = 0; q < 4; ++q) {
                s8v a = *(const s8v*)((const char*)xs + q * 6528 + inner);
                acc[0][q] = __builtin_amdgcn_mfma_f32_16x16x32_bf16(a, b0, acc[0][q], 0, 0, 0);
                acc[1][q] = __builtin_amdgcn_mfma_f32_16x16x32_bf16(a, b1, acc[1][q], 0, 0, 0);
                acc[2][q] = __builtin_amdgcn_mfma_f32_16x16x32_bf16(a, b2, acc[2][q], 0, 0, 0);
            }
        }
    }

    #pragma unroll
    for (int t = 0; t < 3; ++t) {
        const int g = (ntb + t) >> 1;
        #pragma unroll
        for (int q = 0; q < 4; ++q) {
            f32x4 A = acc[t][q];
            float s  = A[0] + A[1] + A[2] + A[3];
            float s2 = A[0]*A[0] + A[1]*A[1] + A[2]*A[2] + A[3]*A[3];
            #pragma unroll
            for (int off = 32; off; off >>= 1) { s += __shfl_xor(s, off); s2 += __shfl_xor(s2, off); }
            if (lane == 0) { atomicAdd(&gsum[q][g], s); atomicAdd(&gsum2[q][g], s2); }
        }
    }
    __syncthreads();
    if (tid < 24) {
        int q = tid / 6, g = tid % 6;
        float mu  = gsum[q][g] * (1.f / 512.f);
        float var = gsum2[q][g] * (1.f / 512.f) - mu * mu;
        gmu[q][g] = mu; grs[q][g] = rsqrtf(var + 1e-5f);
    }
    __syncthreads();

    if constexpr (FIRST) {
        #pragma unroll
        for (int t = 0; t < 3; ++t) {
            const int co = (ntb + t) * 16 + cl, g = (ntb + t) >> 1;
            const float gg = gng[co], gb = gnb[co];
            #pragma unroll
            for (int q = 0; q < 4; ++q) {
                const float mu = gmu[q][g], rs = grs[q][g];
                #pragma unroll
                for (int r = 0; r < 4; ++r) {
                    float v = (acc[t][q][r] - mu) * rs * gg + gb;
                    v = v / (1.f + __expf(-v));      // silu (fast exp)
                    int row = q * 16 + kg * 4 + r;
                    int ba = (row * 384 + co * 2) ^ ((row & 7) << 4);
                    *(short*)((char*)xs + ba) = (short)f2bf(v);
                }
            }
        }
        __syncthreads();
        bf16* dp = dst + (size_t)n0 * 3072;          // token-major [tok][192], contiguous block
        #pragma unroll
        for (int u = 0; u < 6; ++u) {
            int li = u * 256 + tid;                  // 1536 s8v units
            int row = li / 24, g2 = li % 24;
            int ba = (row * 384 + g2 * 16) ^ ((row & 7) << 4);
            s8v val = *(const s8v*)((const char*)xs + ba);
            *(s8v*)(dp + (size_t)row * 192 + g2 * 8) = val;
        }
    } else {
        #pragma unroll
        for (int t = 0; t < 3; ++t) {
            const int co = (ntb + t) * 16 + cl, g = (ntb + t) >> 1;
            const float gg = gng[co], gb = gnb[co];
            #pragma unroll
            for (int q = 0; q < 4; ++q) {
                const float mu = gmu[q][g], rs = grs[q][g];
                #pragma unroll
                for (int r = 0; r < 4; ++r) {
                    float v = (acc[t][q][r] - mu) * rs * gg + gb;
                    xs[q * 3072 + co * 16 + kg * 4 + r] = (short)f2bf(v);
                }
            }
        }
        __syncthreads();
        s4v* dp = (s4v*)(dst + (size_t)n0 * 3072);
        const s4v* sps = (const s4v*)xs;
        #pragma unroll
        for (int u = 0; u < 12; ++u) {
            dp[u * 256 + tid] = sps[u * 256 + tid];
        }
    }
}

// ---------------- MFMA GEMM, single-pass over an N-range, LDS-transpose epilogue ----
template <bool RES, bool GELU_ACT, bool LN, bool QKVOUT, int NKT>
__global__ __launch_bounds__(256) void gemm_mfma_kernel(
    const bf16* __restrict__ A, const short* __restrict__ wfb,
    const float* __restrict__ bias, const bf16* __restrict__ res,
    void* __restrict__ out, int N,
    const float* __restrict__ lng, const float* __restrict__ lnb)
{
    __shared__ short ls[8192];           // [128 rows][64 cols] 2B, XOR-swizzled
    const int tid = threadIdx.x, lane = tid & 63, wid = tid >> 6;
    const int m0 = blockIdx.x * 128;
    const int cl = lane & 15, kg = lane >> 4;
    constexpr int K = NKT * 32;
    const int ntiles = N >> 4;
    const int ntsec = ntiles / gridDim.y;
    const int ntbeg = blockIdx.y * ntsec;

    // load this thread's two A-rows (rows r0, r0+16) as fragments, once
    s8v af0[NKT], af1[NKT];
    const int r0 = m0 + wid * 32 + cl;
    #pragma unroll
    for (int kt = 0; kt < NKT; ++kt) {
        af0[kt] = *(const s8v*)(A + (size_t)r0 * K + kt * 32 + kg * 8);
        af1[kt] = *(const s8v*)(A + (size_t)(r0 + 16) * K + kt * 32 + kg * 8);
    }
    if constexpr (LN) {
        static_assert(!LN || NKT == 6, "LN requires K==192");
        #pragma unroll
        for (int r = 0; r < 2; ++r) {
            s8v* af = r ? af1 : af0;
            float s = 0.f, s2 = 0.f;
            #pragma unroll
            for (int kt = 0; kt < NKT; ++kt)
                #pragma unroll
                for (int j = 0; j < 8; ++j) {
                    float v = bf2f(af[kt][j]);
                    s += v; s2 += v * v;
                }
            s  += __shfl_xor(s, 16);  s2 += __shfl_xor(s2, 16);
            s  += __shfl_xor(s, 32);  s2 += __shfl_xor(s2, 32);
            const float mu = s * (1.f / 192.f);
            const float rs = rsqrtf(s2 * (1.f / 192.f) - mu * mu + 1e-5f);
            #pragma unroll
            for (int kt = 0; kt < NKT; ++kt) {
                const float* gp = lng + kt * 32 + kg * 8;
                const float* bp = lnb + kt * 32 + kg * 8;
                #pragma unroll
                for (int j = 0; j < 8; ++j) {
                    float v = (bf2f(af[kt][j]) - mu) * rs * gp[j] + bp[j];
                    af[kt][j] = (short)f2bf(v);
                }
            }
        }
    }

    const s8v* wf8 = (const s8v*)wfb;
    for (int nt0 = ntbeg; nt0 < ntbeg + ntsec; nt0 += 4) {
        const int n0 = nt0 * 16;
        f32x4 acc[2][4];
        #pragma unroll
        for (int nf = 0; nf < 4; ++nf) {
            float bv = bias[n0 + nf * 16 + cl];
            acc[0][nf] = (f32x4){ bv, bv, bv, bv };
            acc[1][nf] = (f32x4){ bv, bv, bv, bv };
        }
        #pragma unroll
        for (int kt = 0; kt < NKT; ++kt) {
            #pragma unroll
            for (int nf = 0; nf < 4; ++nf) {
                s8v b = wf8[(size_t)(kt * ntiles + nt0 + nf) * 64 + lane];
                acc[0][nf] = __builtin_amdgcn_mfma_f32_16x16x32_bf16(af0[kt], b, acc[0][nf], 0, 0, 0);
                acc[1][nf] = __builtin_amdgcn_mfma_f32_16x16x32_bf16(af1[kt], b, acc[1][nf], 0, 0, 0);
            }
        }

        // ---- epilogue: acc -> LDS (2B, swizzled) -> 16B coalesced stores ----
        __syncthreads();                 // previous chunk's readback done
        #pragma unroll
        for (int rf = 0; rf < 2; ++rf) {
            #pragma unroll
            for (int nf = 0; nf < 4; ++nf) {
                const int lcol = nf * 16 + cl;
                #pragma unroll
                for (int r = 0; r < 4; ++r) {
                    const int lrow = wid * 32 + rf * 16 + kg * 4 + r;
                    float v = acc[rf][nf][r];
                    if (GELU_ACT) v = 0.5f * v * (1.f + erff(v * 0.70710678118f));
                    short sv;
                    if constexpr (QKVOUT) sv = __builtin_bit_cast(short, (_Float16)v);
                    else                  sv = (short)f2bf(v);
                    int ba = (lrow * 128 + lcol * 2) ^ ((lrow & 7) << 4);
                    *(short*)((char*)ls + ba) = sv;
                }
            }
        }
        __syncthreads();
        #pragma unroll
        for (int p = 0; p < 4; ++p) {
            const int lrow = p * 32 + (tid >> 3);
            const int g = tid & 7;
            int ba = (lrow * 128 + g * 16) ^ ((lrow & 7) << 4);
            s8v val = *(const s8v*)((const char*)ls + ba);
            const int row = m0 + lrow;
            const int col0 = n0 + g * 8;
            if constexpr (QKVOUT) {
                const int sec = n0 / 192;        // 64-col chunk never crosses a section
                const int c0 = col0 - sec * 192, h = c0 >> 5, d0 = c0 & 31;
                const int bb2 = row / TOKPB, t = row - bb2 * TOKPB;
                *(s8v*)((_Float16*)out + (size_t)sec * SECSZ +
                        ((size_t)(bb2 * 6 + h) * TOKPB + t) * 32 + d0) = val;
            } else if constexpr (RES) {
                s8v rv = *(const s8v*)(res + (size_t)row * N + col0);
                s8v ov;
                #pragma unroll
                for (int e = 0; e < 8; ++e) ov[e] = (short)f2bf(bf2f(val[e]) + bf2f(rv[e]));
                *(s8v*)((bf16*)out + (size_t)row * N + col0) = ov;
            } else {
                *(s8v*)((bf16*)out + (size_t)row * N + col0) = val;
            }
        }
    }
}

// ---------------- fused attention + proj + residual ----------------
// one block per window, 128 threads. After PV, K-LDS is reused for the 16x192
// attention tile (swizzled) and V-LDS for the proj output; proj = 2 waves x 6 co-tiles
// of mfma_16x16x32_bf16 against L2-resident WP frags; epilogue adds T0 residual.
constexpr int HSTR = 1160;   // per-head LDS stride in shorts (36*32 + 8 pad)
__global__ __launch_bounds__(128) void attn_proj_kernel(
    const _Float16* __restrict__ qf, const float* __restrict__ rpb,
    const short* __restrict__ wpf, const float* __restrict__ pb,
    const bf16* __restrict__ t0, bf16* __restrict__ omid)
{
    __shared__ __align__(16) short kh[6 * HSTR];
    __shared__ __align__(16) short vh[6 * HSTR];
    const int w = blockIdx.x;
    const int b = w / (NHW * NHW), wi = w % (NHW * NHW);
    const int nhi = wi / NHW, nwi = wi % NHW;
    const int tid = threadIdx.x;
    const int lane = tid & 63, wid = tid >> 6;
    const int r0 = nhi * 4 - 1, c0 = nwi * 4 - 1;
    const _Float16* kfb = qf + SECSZ;
    const _Float16* vfb = qf + 2 * SECSZ;

    // stage K and V: 2*864 units of 16B, pure copy (no conversion)
    #pragma unroll
    for (int it = 0; it < 14; ++it) {
        int v = tid + it * 128;
        if (v < 1728) {
            int kv = v >= 864 ? 1 : 0;
            int u = v - kv * 864;
            int h = u / 144, rem = u % 144, kj = rem >> 2, d0 = (rem & 3) * 8;
            int rr = r0 + kj / 6, cc = c0 + kj % 6;
            s8v val = { 0, 0, 0, 0, 0, 0, 0, 0 };
            if (rr >= 0 && rr < CH && cc >= 0 && cc < CW) {
                const _Float16* src = kv ? vfb : kfb;
                val = *(const s8v*)(src + ((size_t)(b * 6 + h) * TOKPB + rr * CW + cc) * 32 + d0);
            }
            short* dst = kv ? vh : kh;
            *(s8v*)(dst + h * HSTR + kj * 32 + d0) = val;
        }
    }
    __syncthreads();

    h2 o2[16];
    float inv = 0.f;
    if (tid < 96) {
        const int h = tid >> 4, qi = tid & 15;
        const int qr = nhi * 4 + (qi >> 2), qc = nwi * 4 + (qi & 3);
        const _Float16* qp = qf + ((size_t)(b * 6 + h) * TOKPB + qr * CW + qc) * 32;
        h2 qh[16];
        #pragma unroll
        for (int u = 0; u < 4; ++u) {
            uint4 qa = *(const uint4*)(qp + u * 8);
            qh[u * 4 + 0] = __builtin_bit_cast(h2, qa.x);
            qh[u * 4 + 1] = __builtin_bit_cast(h2, qa.y);
            qh[u * 4 + 2] = __builtin_bit_cast(h2, qa.z);
            qh[u * 4 + 3] = __builtin_bit_cast(h2, qa.w);
        }

        float sc[36];
        const short* khb = kh + h * HSTR;
        #pragma unroll
        for (int kj = 0; kj < 36; ++kj) {
            const uint4* kp = (const uint4*)(khb + kj * 32);
            uint4 k0 = kp[0], k1 = kp[1], k2 = kp[2], k3 = kp[3];
            unsigned kwv[16] = { k0.x, k0.y, k0.z, k0.w, k1.x, k1.y, k1.z, k1.w,
                                 k2.x, k2.y, k2.z, k2.w, k3.x, k3.y, k3.z, k3.w };
            float a0 = 0.f, a1 = 0.f, a2 = 0.f, a3 = 0.f;
            #pragma unroll
            for (int e = 0; e < 4; ++e) {
                a0 = __builtin_amdgcn_fdot2(__builtin_bit_cast(h2, kwv[4*e+0]), qh[4*e+0], a0, false);
                a1 = __builtin_amdgcn_fdot2(__builtin_bit_cast(h2, kwv[4*e+1]), qh[4*e+1], a1, false);
                a2 = __builtin_amdgcn_fdot2(__builtin_bit_cast(h2, kwv[4*e+2]), qh[4*e+2], a2, false);
                a3 = __builtin_amdgcn_fdot2(__builtin_bit_cast(h2, kwv[4*e+3]), qh[4*e+3], a3, false);
            }
            const int rel0 = kj / 6 - (qi >> 2) + 3;
            const int rel1 = kj % 6 - (qi & 3) + 3;
            sc[kj] = ((a0 + a1) + (a2 + a3)) * 0.17677669529f + rpb[(rel0 * 9 + rel1) * 6 + h];
        }
        float mx = -1e30f;
        #pragma unroll
        for (int kj = 0; kj < 36; ++kj) mx = fmaxf(mx, sc[kj]);
        float sum = 0.f;
        #pragma unroll
        for (int kj = 0; kj < 36; ++kj) { sc[kj] = __expf(sc[kj] - mx); sum += sc[kj]; }
        inv = 1.f / sum;

        #pragma unroll
        for (int e = 0; e < 16; ++e) o2[e] = (h2){ (_Float16)0.f, (_Float16)0.f };
        const short* vhb = vh + h * HSTR;
        #pragma unroll
        for (int kj = 0; kj < 36; ++kj) {
            const uint4* vp = (const uint4*)(vhb + kj * 32);
            uint4 v0 = vp[0], v1 = vp[1], v2 = vp[2], v3 = vp[3];
            unsigned vwv[16] = { v0.x, v0.y, v0.z, v0.w, v1.x, v1.y, v1.z, v1.w,
                                 v2.x, v2.y, v2.z, v2.w, v3.x, v3.y, v3.z, v3.w };
            const _Float16 ph = (_Float16)sc[kj];
            const h2 ph2 = { ph, ph };
            #pragma unroll
            for (int e = 0; e < 16; ++e)
                o2[e] = __builtin_bit_cast(h2, vwv[e]) * ph2 + o2[e];
        }
    }
    __syncthreads();                     // all QK/PV reads of kh/vh complete

    // write attention tile (16 tok x 192 ch, bf16, XOR-swizzled) into kh region
    if (tid < 96) {
        const int h = tid >> 4, qi = tid & 15;
        #pragma unroll
        for (int u = 0; u < 4; ++u) {    // d0 = u*8
            s8v pk;
            #pragma unroll
            for (int e = 0; e < 4; ++e) {
                h2 ov = o2[u * 4 + e];
                pk[2 * e]     = (short)f2bf((float)ov[0] * inv);
                pk[2 * e + 1] = (short)f2bf((float)ov[1] * inv);
            }
            int ba = (qi * 384 + (h * 32 + u * 8) * 2) ^ ((qi & 7) << 4);
            *(s8v*)((char*)kh + ba) = pk;
        }
    }
    __syncthreads();

    // proj MFMA: wave wid handles co-tiles wid*6 .. wid*6+5
    const int cl = lane & 15, kg = lane >> 4;
    s8v a[6];
    #pragma unroll
    for (int kt = 0; kt < 6; ++kt) {
        int ba = (cl * 384 + kt * 64 + kg * 16) ^ ((cl & 7) << 4);
        a[kt] = *(const s8v*)((const char*)kh + ba);
    }
    f32x4 acc[6];
    const s8v* wp8 = (const s8v*)wpf;
    #pragma unroll
    for (int ctl = 0; ctl < 6; ++ctl) {
        float bv = pb[(wid * 6 + ctl) * 16 + cl];
        acc[ctl] = (f32x4){ bv, bv, bv, bv };
    }
    #pragma unroll
    for (int kt = 0; kt < 6; ++kt) {
        #pragma unroll
        for (int ctl = 0; ctl < 6; ++ctl) {
            s8v bfr = wp8[(size_t)(kt * 12 + wid * 6 + ctl) * 64 + lane];
            acc[ctl] = __builtin_amdgcn_mfma_f32_16x16x32_bf16(a[kt], bfr, acc[ctl], 0, 0, 0);
        }
    }
    // D -> vh (plain [16 tok][192])
    #pragma unroll
    for (int ctl = 0; ctl < 6; ++ctl) {
        const int col = (wid * 6 + ctl) * 16 + cl;
        #pragma unroll
        for (int r = 0; r < 4; ++r) {
            vh[(kg * 4 + r) * 192 + col] = (short)f2bf(acc[ctl][r]);
        }
    }
    __syncthreads();

    // copy out with residual: 384 s8v units (16 rows x 24 groups)
    #pragma unroll
    for (int u = 0; u < 3; ++u) {
        int li = u * 128 + tid;
        int row = li / 24, c8 = (li % 24) * 8;
        int qr = nhi * 4 + (row >> 2), qc = nwi * 4 + (row & 3);
        size_t gb = ((size_t)(b * TOKPB + qr * CW + qc)) * 192 + c8;
        s8v pv = *(const s8v*)(vh + row * 192 + c8);
        s8v rv = *(const s8v*)(t0 + gb);
        s8v ov;
        #pragma unroll
        for (int e = 0; e < 8; ++e) ov[e] = (short)f2bf(bf2f(pv[e]) + bf2f(rv[e]));
        *(s8v*)(omid + gb) = ov;
    }
}

// ---------------- final: out = relu(C2 + conv1x1(x)), MFMA ----------------
__global__ __launch_bounds__(256, 4) void final_mfma_kernel(
    const float* __restrict__ x, const short* __restrict__ w3f,
    const float* __restrict__ b3, const bf16* __restrict__ c2,
    float* __restrict__ out)
{
    __shared__ short xs2[12288];      // [64 pix][192 ci] bf16, row-swizzled
    const int pix0 = blockIdx.x * 64;
    const int b    = blockIdx.y;
    const int tid = threadIdx.x, lane = tid & 63, wid = tid >> 6;
    const int cl = lane & 15, kg = lane >> 4;
    const float* xb = x + (size_t)b * (192 * TOKPB);

    #pragma unroll
    for (int u = 0; u < 12; ++u) {
        int idx = u * 256 + tid;                  // 3072 float4
        int ci = idx >> 4, p4 = (idx & 15) << 2;
        float4 v = *(const float4*)(xb + (size_t)ci * TOKPB + pix0 + p4);
        float vv[4] = { v.x, v.y, v.z, v.w };
        #pragma unroll
        for (int k = 0; k < 4; ++k) {
            int row = p4 + k;
            int ba = (row * 384 + ci * 2) ^ ((row & 7) << 4);
            *(short*)((char*)xs2 + ba) = (short)f2bf(vv[k]);
        }
    }
    __syncthreads();

    const int ctb = wid * 3;
    f32x4 acc[3][4] = {};
    const s8v* wf8 = (const s8v*)w3f;

    #pragma unroll
    for (int kt = 0; kt < 6; ++kt) {
        s8v a0 = wf8[(size_t)(kt * 12 + ctb + 0) * 64 + lane];
        s8v a1 = wf8[(size_t)(kt * 12 + ctb + 1) * 64 + lane];
        s8v a2 = wf8[(size_t)(kt * 12 + ctb + 2) * 64 + lane];
        #pragma unroll
        for (int pt = 0; pt < 4; ++pt) {
            int row = pt * 16 + cl;
            int ba = (row * 384 + kt * 64 + kg * 16) ^ ((row & 7) << 4);
            s8v bfr = *(const s8v*)((const char*)xs2 + ba);
            acc[0][pt] = __builtin_amdgcn_mfma_f32_16x16x32_bf16(a0, bfr, acc[0][pt], 0, 0, 0);
            acc[1][pt] = __builtin_amdgcn_mfma_f32_16x16x32_bf16(a1, bfr, acc[1][pt], 0, 0, 0);
            acc[2][pt] = __builtin_amdgcn_mfma_f32_16x16x32_bf16(a2, bfr, acc[2][pt], 0, 0, 0);
        }
    }

    #pragma unroll
    for (int t = 0; t < 3; ++t) {
        #pragma unroll
        for (int r = 0; r < 4; ++r) {
            const int co = (ctb + t) * 16 + kg * 4 + r;
            const float bb = b3[co];
            const size_t rowbase = (size_t)b * (192 * TOKPB) + (size_t)co * TOKPB + pix0;
            #pragma unroll
            for (int pt = 0; pt < 4; ++pt) {
                const size_t f = rowbase + pt * 16 + cl;
                float v = acc[t][pt][r] + bb + bf2f(__builtin_bit_cast(short, c2[f]));
                out[f] = fmaxf(v, 0.f);
            }
        }
    }
}

// ---------------- host launch ----------------
extern "C" void kernel_launch(void* const* d_in, const int* in_sizes, int n_in,
                              void* d_out, int out_size, void* d_ws, size_t ws_size,
                              hipStream_t stream)
{
    if (ws_size < WS_NEEDED) return;

    const float* x       = (const float*)d_in[0];
    const float* conv1_w = (const float*)d_in[1];
    const float* conv1_b = (const float*)d_in[2];
    const float* gn1_g   = (const float*)d_in[3];
    const float* gn1_b   = (const float*)d_in[4];
    const float* conv2_w = (const float*)d_in[5];
    const float* conv2_b = (const float*)d_in[6];
    const float* gn2_g   = (const float*)d_in[7];
    const float* gn2_b   = (const float*)d_in[8];
    const float* conv3_w = (const float*)d_in[9];
    const float* conv3_b = (const float*)d_in[10];
    const float* ln1_g   = (const float*)d_in[11];
    const float* ln1_b   = (const float*)d_in[12];
    const float* qkv_w   = (const float*)d_in[13];
    const float* qkv_b   = (const float*)d_in[14];
    const float* rpb     = (const float*)d_in[15];
    const float* proj_w  = (const float*)d_in[16];
    const float* proj_b  = (const float*)d_in[17];
    const float* ln2_g   = (const float*)d_in[18];
    const float* ln2_b   = (const float*)d_in[19];
    const float* fc1_w   = (const float*)d_in[20];
    const float* fc1_b   = (const float*)d_in[21];
    const float* fc2_w   = (const float*)d_in[22];
    const float* fc2_b   = (const float*)d_in[23];

    char* wsb = (char*)d_ws;
    bf16*  T0  = (bf16*)(wsb + B_T0);
    _Float16* QF = (_Float16*)(wsb + B_P2);   // Q/K/V f16 sections; later HID bf16
    bf16*  HID = (bf16*)(wsb + B_P2);
    bf16*  P3  = (bf16*)(wsb + B_P3);
    bf16*  P4  = (bf16*)(wsb + B_P4);
    short* WF1 = (short*)(wsb + B_WF1);
    short* WF2 = (short*)(wsb + B_WF2);
    short* W3F = (short*)(wsb + B_W3F);
    short* WQ  = (short*)(wsb + B_WQ);
    short* WP  = (short*)(wsb + B_WP);
    short* WG1 = (short*)(wsb + B_WG1);
    short* WG2 = (short*)(wsb + B_WG2);
    float* OUT = (float*)d_out;

    // fused weight prep (single launch)
    prep_all_kernel<<<(PREP_TOTAL + 255) / 256, 256, 0, stream>>>(
        conv1_w, WF1, conv2_w, WF2, conv3_w, W3F, qkv_w, WQ, proj_w, WP, fc1_w, WG1, fc2_w, WG2);

    // stage A: conv1 + gn1 + silu -> T0 (token layout, bf16)
    conv_mfma_kernel<true><<<NPATCH / 4, 256, 0, stream>>>(x, WF1, conv1_b, gn1_g, gn1_b, T0);
    // stage C: LN1 (fused, once) + qkv gemm -> QF/KF/VF (f16 head-major); grid.y = 1
    gemm_mfma_kernel<false, false, true, true, 6><<<dim3(MTOK / 128, 1), 256, 0, stream>>>(
        T0, WQ, qkv_b, nullptr, QF, 576, ln1_g, ln1_b);
    // stage D+E: attention + proj + shortcut(T0) -> P4 (OMID)
    attn_proj_kernel<<<NPATCH, 128, 0, stream>>>(QF, rpb, WP, proj_b, T0, P4);
    // stage G: LN2 (fused) + fc1 + gelu -> HID
    gemm_mfma_kernel<false, true, true, false, 6><<<dim3(MTOK / 128, 1), 256, 0, stream>>>(
        P4, WG1, fc1_b, nullptr, HID, 384, ln2_g, ln2_b);
    // stage H: fc2 + residual(OMID P4) -> P3 (OCAB, bf16 token layout)
    gemm_mfma_kernel<true, false, false, false, 12><<<dim3(MTOK / 128, 1), 256, 0, stream>>>(
        HID, WG2, fc2_b, P4, P3, 192, nullptr, nullptr);
    // stage I: conv2 + gn2 (reads P3 bf16 token layout) -> P4... wait, P4 holds OMID still needed? No:
    // OMID consumed by stages G (LN2+fc1) and H (residual) which are both done; safe to overwrite.
    conv_mfma_kernel<false><<<NPATCH / 4, 256, 0, stream>>>(P3, WF2, conv2_b, gn2_g, gn2_b, P4);
    // stage J: out = relu(C2 + conv1x1(x)) -> d_out, MFMA
    final_mfma_kernel<<<dim3(TOKPB / 64, CB), 256, 0, stream>>>(x, W3F, conv3_b, P4, OUT);
}

// Round 16
// 506.862 us; speedup vs baseline: 1.8403x; 1.0370x over previous
//
#include <hip/hip_runtime.h>
#include <hip/hip_bf16.h>
#include <math.h>

typedef __hip_bfloat16 bf16;
typedef __attribute__((ext_vector_type(8))) short s8v;
typedef __attribute__((ext_vector_type(4))) short s4v;
typedef __attribute__((ext_vector_type(4))) float f32x4;
typedef __attribute__((ext_vector_type(2))) _Float16 h2;

// ---------------- problem constants ----------------
constexpr int CB   = 2;            // batch
constexpr int CH   = 224, CW = 224;
constexpr int NHW  = 56;           // H/WS
constexpr int NPATCH = CB * NHW * NHW;   // 6272
constexpr int TOKPB  = CH * CW;          // 50176 tokens per batch
constexpr int MTOK   = CB * TOKPB;       // 100352 rows
constexpr size_t SECSZ = 19267584;       // elems per q/k/v f16 section

// ---------------- ws layout (BYTE offsets) ----------------
constexpr size_t B_T0  = 0;                         // 19267584 bf16
constexpr size_t B_P2  = B_T0 + 38535168;           // QF/KF/VF f16 (3x38.5MB); later HID bf16
constexpr size_t B_P3  = B_P2 + 115605504;          // 19267584 bf16 (OCAB)
constexpr size_t B_P4  = B_P3 + 38535168;           // 19267584 bf16 (OMID -> C2)
constexpr size_t B_WF1 = B_P4 + 38535168;           // conv1 frag weights
constexpr size_t B_WF2 = B_WF1 + 1327104;           // conv2 frag weights
constexpr size_t B_W3F = B_WF2 + 1327104;           // conv3 1x1 frag weights
constexpr size_t B_WQ  = B_W3F + 147456;            // qkv_w frag
constexpr size_t B_WP  = B_WQ + 221184;             // proj_w frag
constexpr size_t B_WG1 = B_WP + 73728;              // fc1_w frag
constexpr size_t B_WG2 = B_WG1 + 147456;            // fc2_w frag
constexpr size_t WS_NEEDED = B_WG2 + 147456;        // 234,602,496 B

// ---------------- type helpers ----------------
__device__ __forceinline__ float ldf(const float* p) { return *p; }
__device__ __forceinline__ float ldf(const bf16* p)  { return __bfloat162float(*p); }
__device__ __forceinline__ void  stf(float* p, float v) { *p = v; }
__device__ __forceinline__ void  stf(bf16* p, float v)  { *p = __float2bfloat16(v); }
__device__ __forceinline__ unsigned short f2bf(float f) {
    unsigned u = __builtin_bit_cast(unsigned, f);
    unsigned r = (u + 0x7fffu + ((u >> 16) & 1u)) >> 16;
    return (unsigned short)r;
}
__device__ __forceinline__ float bf2f(short s) {
    unsigned u = ((unsigned)(unsigned short)s) << 16;
    return __builtin_bit_cast(float, u);
}

// ---------------- fused weight pre-pack (one launch) ----------------
__device__ __forceinline__ void prep_wf(const float* __restrict__ w, short* __restrict__ wf, int o) {
    int within = o & 511, frag = o >> 9;
    int l = within >> 3, j = within & 7;
    int nt = frag % 12, t2 = frag / 12, ks = t2 % 6, tap = t2 / 6;
    int co = nt * 16 + (l & 15);
    int ci = ks * 32 + (l >> 4) * 8 + j;
    wf[o] = (short)f2bf(w[(co * 192 + ci) * 9 + tap]);
}
__device__ __forceinline__ void prep_wgemm(const float* __restrict__ w, short* __restrict__ wf,
                                           int K, int N, int o) {
    int j = o & 7, l = (o >> 3) & 63, f = o >> 9;
    int ntiles = N >> 4;
    int kt = f / ntiles, nt = f % ntiles;
    int k = kt * 32 + (l >> 4) * 8 + j;
    int col = nt * 16 + (l & 15);
    wf[o] = (short)f2bf(w[(size_t)k * N + col]);
}
__device__ __forceinline__ void prep_w3f(const float* __restrict__ w, short* __restrict__ wf, int o) {
    int j = o & 7, l = (o >> 3) & 63, f = o >> 9;   // f = kt*12 + ct
    int kt = f / 12, ct = f % 12;
    int co = ct * 16 + (l & 15);
    int ci = kt * 32 + (l >> 4) * 8 + j;
    wf[o] = (short)f2bf(w[co * 192 + ci]);
}
__global__ __launch_bounds__(256) void prep_all_kernel(
    const float* __restrict__ conv1_w, short* __restrict__ WF1,
    const float* __restrict__ conv2_w, short* __restrict__ WF2,
    const float* __restrict__ conv3_w, short* __restrict__ W3F,
    const float* __restrict__ qkv_w,   short* __restrict__ WQ,
    const float* __restrict__ proj_w,  short* __restrict__ WP,
    const float* __restrict__ fc1_w,   short* __restrict__ WG1,
    const float* __restrict__ fc2_w,   short* __restrict__ WG2)
{
    int o = blockIdx.x * 256 + threadIdx.x;
    if (o < 331776)            { prep_wf(conv1_w, WF1, o); return; }
    o -= 331776;
    if (o < 331776)            { prep_wf(conv2_w, WF2, o); return; }
    o -= 331776;
    if (o < 36864)             { prep_w3f(conv3_w, W3F, o); return; }
    o -= 36864;
    if (o < 110592)            { prep_wgemm(qkv_w, WQ, 192, 576, o); return; }
    o -= 110592;
    if (o < 36864)             { prep_wgemm(proj_w, WP, 192, 192, o); return; }
    o -= 36864;
    if (o < 73728)             { prep_wgemm(fc1_w, WG1, 192, 384, o); return; }
    o -= 73728;
    if (o < 73728)             { prep_wgemm(fc2_w, WG2, 384, 192, o); return; }
}
constexpr int PREP_TOTAL = 331776 * 2 + 36864 + 110592 + 36864 + 73728 * 2;  // 995328

// ---------------- conv3x3 (4x4 patches) + groupnorm (+silu), MFMA ----------------
template <bool FIRST>
__global__ __launch_bounds__(256, 4) void conv_mfma_kernel(
    const void* __restrict__ srcv, const short* __restrict__ wf,
    const float* __restrict__ bias, const float* __restrict__ gng,
    const float* __restrict__ gnb, bf16* __restrict__ dst)
{
    __shared__ short xs[13056];          // 4 patches * 17 rows * 384B (row 16 = zeros), swizzled
    __shared__ float gsum[4][6], gsum2[4][6], gmu[4][6], grs[4][6];
    const int tid  = threadIdx.x;
    const int lane = tid & 63, wid = tid >> 6;
    const int n0   = blockIdx.x * 4;

    if (tid < 24) { gsum[tid / 6][tid % 6] = 0.f; gsum2[tid / 6][tid % 6] = 0.f; }
    for (int u = tid; u < 4 * 192; u += 256) {       // zero rows
        int q = u / 192;
        xs[q * 3264 + 3072 + (u % 192)] = 0;
    }

    if constexpr (FIRST) {
        const float4* sp = (const float4*)((const float*)srcv + (size_t)n0 * 3072);
        #pragma unroll
        for (int u = 0; u < 12; ++u) {
            int idx = u * 256 + tid;                 // float4 index, 3072 total
            float4 v = sp[idx];
            int q = idx / 768;
            int li = (idx % 768) * 4;                // li = ci*16 + p
            int ci = li >> 4, p0 = li & 15;
            float vv[4] = { v.x, v.y, v.z, v.w };
            #pragma unroll
            for (int k = 0; k < 4; ++k) {
                int row = p0 + k;
                int ba = q * 6528 + ((row * 384 + ci * 2) ^ ((row & 7) << 4));
                *(short*)((char*)xs + ba) = (short)f2bf(vv[k]);
            }
        }
    } else {
        const s8v* sp8 = (const s8v*)((const bf16*)srcv + (size_t)n0 * 3072);
        #pragma unroll
        for (int u = 0; u < 6; ++u) {
            int li = u * 256 + tid;                  // 1536 s8v units
            int r = li / 24, ch = li % 24;
            int q = r >> 4, rl = r & 15;
            s8v val = sp8[li];
            int ba = q * 6528 + ((rl * 384 + ch * 16) ^ ((rl & 7) << 4));
            *(s8v*)((char*)xs + ba) = val;
        }
    }
    __syncthreads();

    const int ntb = wid * 3;
    const int cl  = lane & 15;
    const int kg  = lane >> 4;
    f32x4 acc[3][4];
    #pragma unroll
    for (int t = 0; t < 3; ++t) {
        float bv = bias[(ntb + t) * 16 + cl];
        #pragma unroll
        for (int q = 0; q < 4; ++q) acc[t][q] = (f32x4){ bv, bv, bv, bv };
    }

    const int pi = cl >> 2, pj = cl & 3;
    const s8v* wf8 = (const s8v*)wf;

    for (int tap = 0; tap < 9; ++tap) {
        const int di = tap / 3, dj = tap % 3;
        const int ii = pi + di - 1, jj = pj + dj - 1;
        const bool valid = (ii >= 0 && ii < 4 && jj >= 0 && jj < 4);
        const int nr  = valid ? (ii * 4 + jj) : 16;   // row 16 = zero row
        const int rb  = nr * 384;
        const int swz = (nr & 7) << 4;
        #pragma unroll
        for (int ks = 0; ks < 6; ++ks) {
            const s8v* bp = wf8 + (size_t)((tap * 6 + ks) * 12) * 64 + lane;
            s8v b0 = bp[(ntb + 0) * 64];
            s8v b1 = bp[(ntb + 1) * 64];
            s8v b2 = bp[(ntb + 2) * 64];
            const int inner = (rb + ks * 64 + kg * 16) ^ swz;
            #pragma unroll
            for (int q = 0; q < 4; ++q) {
                s8v a = *(const s8v*)((const char*)xs + q * 6528 + inner);
                acc[0][q] = __builtin_amdgcn_mfma_f32_16x16x32_bf16(a, b0, acc[0][q], 0, 0, 0);
                acc[1][q] = __builtin_amdgcn_mfma_f32_16x16x32_bf16(a, b1, acc[1][q], 0, 0, 0);
                acc[2][q] = __builtin_amdgcn_mfma_f32_16x16x32_bf16(a, b2, acc[2][q], 0, 0, 0);
            }
        }
    }

    #pragma unroll
    for (int t = 0; t < 3; ++t) {
        const int g = (ntb + t) >> 1;
        #pragma unroll
        for (int q = 0; q < 4; ++q) {
            f32x4 A = acc[t][q];
            float s  = A[0] + A[1] + A[2] + A[3];
            float s2 = A[0]*A[0] + A[1]*A[1] + A[2]*A[2] + A[3]*A[3];
            #pragma unroll
            for (int off = 32; off; off >>= 1) { s += __shfl_xor(s, off); s2 += __shfl_xor(s2, off); }
            if (lane == 0) { atomicAdd(&gsum[q][g], s); atomicAdd(&gsum2[q][g], s2); }
        }
    }
    __syncthreads();
    if (tid < 24) {
        int q = tid / 6, g = tid % 6;
        float mu  = gsum[q][g] * (1.f / 512.f);
        float var = gsum2[q][g] * (1.f / 512.f) - mu * mu;
        gmu[q][g] = mu; grs[q][g] = rsqrtf(var + 1e-5f);
    }
    __syncthreads();

    if constexpr (FIRST) {
        #pragma unroll
        for (int t = 0; t < 3; ++t) {
            const int co = (ntb + t) * 16 + cl, g = (ntb + t) >> 1;
            const float gg = gng[co], gb = gnb[co];
            #pragma unroll
            for (int q = 0; q < 4; ++q) {
                const float mu = gmu[q][g], rs = grs[q][g];
                #pragma unroll
                for (int r = 0; r < 4; ++r) {
                    float v = (acc[t][q][r] - mu) * rs * gg + gb;
                    v = v / (1.f + __expf(-v));      // silu (fast exp)
                    int row = q * 16 + kg * 4 + r;
                    int ba = (row * 384 + co * 2) ^ ((row & 7) << 4);
                    *(short*)((char*)xs + ba) = (short)f2bf(v);
                }
            }
        }
        __syncthreads();
        bf16* dp = dst + (size_t)n0 * 3072;          // token-major [tok][192], contiguous block
        #pragma unroll
        for (int u = 0; u < 6; ++u) {
            int li = u * 256 + tid;                  // 1536 s8v units
            int row = li / 24, g2 = li % 24;
            int ba = (row * 384 + g2 * 16) ^ ((row & 7) << 4);
            s8v val = *(const s8v*)((const char*)xs + ba);
            *(s8v*)(dp + (size_t)row * 192 + g2 * 8) = val;
        }
    } else {
        #pragma unroll
        for (int t = 0; t < 3; ++t) {
            const int co = (ntb + t) * 16 + cl, g = (ntb + t) >> 1;
            const float gg = gng[co], gb = gnb[co];
            #pragma unroll
            for (int q = 0; q < 4; ++q) {
                const float mu = gmu[q][g], rs = grs[q][g];
                #pragma unroll
                for (int r = 0; r < 4; ++r) {
                    float v = (acc[t][q][r] - mu) * rs * gg + gb;
                    xs[q * 3072 + co * 16 + kg * 4 + r] = (short)f2bf(v);
                }
            }
        }
        __syncthreads();
        s4v* dp = (s4v*)(dst + (size_t)n0 * 3072);
        const s4v* sps = (const s4v*)xs;
        #pragma unroll
        for (int u = 0; u < 12; ++u) {
            dp[u * 256 + tid] = sps[u * 256 + tid];
        }
    }
}

// ---------------- MFMA GEMM, single-pass over an N-range, LDS-transpose epilogue ----
template <bool RES, bool GELU_ACT, bool LN, bool QKVOUT, int NKT>
__global__ __launch_bounds__(256) void gemm_mfma_kernel(
    const bf16* __restrict__ A, const short* __restrict__ wfb,
    const float* __restrict__ bias, const bf16* __restrict__ res,
    void* __restrict__ out, int N,
    const float* __restrict__ lng, const float* __restrict__ lnb)
{
    __shared__ short ls[8192];           // [128 rows][64 cols] 2B, XOR-swizzled
    const int tid = threadIdx.x, lane = tid & 63, wid = tid >> 6;
    const int m0 = blockIdx.x * 128;
    const int cl = lane & 15, kg = lane >> 4;
    constexpr int K = NKT * 32;
    const int ntiles = N >> 4;
    const int ntsec = ntiles / gridDim.y;
    const int ntbeg = blockIdx.y * ntsec;

    // load this thread's two A-rows (rows r0, r0+16) as fragments, once
    s8v af0[NKT], af1[NKT];
    const int r0 = m0 + wid * 32 + cl;
    #pragma unroll
    for (int kt = 0; kt < NKT; ++kt) {
        af0[kt] = *(const s8v*)(A + (size_t)r0 * K + kt * 32 + kg * 8);
        af1[kt] = *(const s8v*)(A + (size_t)(r0 + 16) * K + kt * 32 + kg * 8);
    }
    if constexpr (LN) {
        static_assert(!LN || NKT == 6, "LN requires K==192");
        #pragma unroll
        for (int r = 0; r < 2; ++r) {
            s8v* af = r ? af1 : af0;
            float s = 0.f, s2 = 0.f;
            #pragma unroll
            for (int kt = 0; kt < NKT; ++kt)
                #pragma unroll
                for (int j = 0; j < 8; ++j) {
                    float v = bf2f(af[kt][j]);
                    s += v; s2 += v * v;
                }
            s  += __shfl_xor(s, 16);  s2 += __shfl_xor(s2, 16);
            s  += __shfl_xor(s, 32);  s2 += __shfl_xor(s2, 32);
            const float mu = s * (1.f / 192.f);
            const float rs = rsqrtf(s2 * (1.f / 192.f) - mu * mu + 1e-5f);
            #pragma unroll
            for (int kt = 0; kt < NKT; ++kt) {
                const float* gp = lng + kt * 32 + kg * 8;
                const float* bp = lnb + kt * 32 + kg * 8;
                #pragma unroll
                for (int j = 0; j < 8; ++j) {
                    float v = (bf2f(af[kt][j]) - mu) * rs * gp[j] + bp[j];
                    af[kt][j] = (short)f2bf(v);
                }
            }
        }
    }

    const s8v* wf8 = (const s8v*)wfb;
    for (int nt0 = ntbeg; nt0 < ntbeg + ntsec; nt0 += 4) {
        const int n0 = nt0 * 16;
        f32x4 acc[2][4];
        #pragma unroll
        for (int nf = 0; nf < 4; ++nf) {
            float bv = bias[n0 + nf * 16 + cl];
            acc[0][nf] = (f32x4){ bv, bv, bv, bv };
            acc[1][nf] = (f32x4){ bv, bv, bv, bv };
        }
        #pragma unroll
        for (int kt = 0; kt < NKT; ++kt) {
            #pragma unroll
            for (int nf = 0; nf < 4; ++nf) {
                s8v b = wf8[(size_t)(kt * ntiles + nt0 + nf) * 64 + lane];
                acc[0][nf] = __builtin_amdgcn_mfma_f32_16x16x32_bf16(af0[kt], b, acc[0][nf], 0, 0, 0);
                acc[1][nf] = __builtin_amdgcn_mfma_f32_16x16x32_bf16(af1[kt], b, acc[1][nf], 0, 0, 0);
            }
        }

        // ---- epilogue: acc -> LDS (2B, swizzled) -> 16B coalesced stores ----
        __syncthreads();                 // previous chunk's readback done
        #pragma unroll
        for (int rf = 0; rf < 2; ++rf) {
            #pragma unroll
            for (int nf = 0; nf < 4; ++nf) {
                const int lcol = nf * 16 + cl;
                #pragma unroll
                for (int r = 0; r < 4; ++r) {
                    const int lrow = wid * 32 + rf * 16 + kg * 4 + r;
                    float v = acc[rf][nf][r];
                    if (GELU_ACT) v = 0.5f * v * (1.f + erff(v * 0.70710678118f));
                    short sv;
                    if constexpr (QKVOUT) sv = __builtin_bit_cast(short, (_Float16)v);
                    else                  sv = (short)f2bf(v);
                    int ba = (lrow * 128 + lcol * 2) ^ ((lrow & 7) << 4);
                    *(short*)((char*)ls + ba) = sv;
                }
            }
        }
        __syncthreads();
        #pragma unroll
        for (int p = 0; p < 4; ++p) {
            const int lrow = p * 32 + (tid >> 3);
            const int g = tid & 7;
            int ba = (lrow * 128 + g * 16) ^ ((lrow & 7) << 4);
            s8v val = *(const s8v*)((const char*)ls + ba);
            const int row = m0 + lrow;
            const int col0 = n0 + g * 8;
            if constexpr (QKVOUT) {
                const int sec = n0 / 192;        // 64-col chunk never crosses a section
                const int c0 = col0 - sec * 192, h = c0 >> 5, d0 = c0 & 31;
                const int bb2 = row / TOKPB, t = row - bb2 * TOKPB;
                *(s8v*)((_Float16*)out + (size_t)sec * SECSZ +
                        ((size_t)(bb2 * 6 + h) * TOKPB + t) * 32 + d0) = val;
            } else if constexpr (RES) {
                s8v rv = *(const s8v*)(res + (size_t)row * N + col0);
                s8v ov;
                #pragma unroll
                for (int e = 0; e < 8; ++e) ov[e] = (short)f2bf(bf2f(val[e]) + bf2f(rv[e]));
                *(s8v*)((bf16*)out + (size_t)row * N + col0) = ov;
            } else {
                *(s8v*)((bf16*)out + (size_t)row * N + col0) = val;
            }
        }
    }
}

// ---------------- fused attention + proj + residual, 192 threads ----------------
// 96 (head,token) jobs x 2 key-splits (18 keys each); pair combine via shfl_xor(1).
// After PV, kh region holds the 16x192 attention tile (swizzled); proj = 3 waves x
// 4 co-tiles of mfma_16x16x32_bf16; epilogue adds T0 residual.
constexpr int HSTR = 1160;   // per-head LDS stride in shorts (36*32 + 8 pad)
__global__ __launch_bounds__(192) void attn_proj_kernel(
    const _Float16* __restrict__ qf, const float* __restrict__ rpb,
    const short* __restrict__ wpf, const float* __restrict__ pb,
    const bf16* __restrict__ t0, bf16* __restrict__ omid)
{
    __shared__ __align__(16) short kh[6 * HSTR];
    __shared__ __align__(16) short vh[6 * HSTR];
    const int w = blockIdx.x;
    const int b = w / (NHW * NHW), wi = w % (NHW * NHW);
    const int nhi = wi / NHW, nwi = wi % NHW;
    const int tid = threadIdx.x;
    const int lane = tid & 63, wid = tid >> 6;
    const int r0 = nhi * 4 - 1, c0 = nwi * 4 - 1;
    const _Float16* kfb = qf + SECSZ;
    const _Float16* vfb = qf + 2 * SECSZ;

    // stage K and V: 1728 units of 16B over 192 threads = 9 iterations
    #pragma unroll
    for (int it = 0; it < 9; ++it) {
        int v = tid + it * 192;
        int kv = v >= 864 ? 1 : 0;
        int u = v - kv * 864;
        int h = u / 144, rem = u % 144, kj = rem >> 2, d0 = (rem & 3) * 8;
        int rr = r0 + kj / 6, cc = c0 + kj % 6;
        s8v val = { 0, 0, 0, 0, 0, 0, 0, 0 };
        if (rr >= 0 && rr < CH && cc >= 0 && cc < CW) {
            const _Float16* src = kv ? vfb : kfb;
            val = *(const s8v*)(src + ((size_t)(b * 6 + h) * TOKPB + rr * CW + cc) * 32 + d0);
        }
        short* dst = kv ? vh : kh;
        *(s8v*)(dst + h * HSTR + kj * 32 + d0) = val;
    }
    __syncthreads();

    // compute: pair = tid>>1 (h,qi), split = tid&1 handles keys [split*18, split*18+18)
    const int pair = tid >> 1, split = tid & 1;
    const int h = pair >> 4, qi = pair & 15;
    const int qr = nhi * 4 + (qi >> 2), qc = nwi * 4 + (qi & 3);
    const _Float16* qp = qf + ((size_t)(b * 6 + h) * TOKPB + qr * CW + qc) * 32;
    h2 qh[16];
    #pragma unroll
    for (int u = 0; u < 4; ++u) {
        uint4 qa = *(const uint4*)(qp + u * 8);
        qh[u * 4 + 0] = __builtin_bit_cast(h2, qa.x);
        qh[u * 4 + 1] = __builtin_bit_cast(h2, qa.y);
        qh[u * 4 + 2] = __builtin_bit_cast(h2, qa.z);
        qh[u * 4 + 3] = __builtin_bit_cast(h2, qa.w);
    }

    float sc[18];
    const int kbeg = split * 18;
    const short* khb = kh + h * HSTR;
    #pragma unroll
    for (int kk = 0; kk < 18; ++kk) {
        const int kj = kbeg + kk;
        const uint4* kp = (const uint4*)(khb + kj * 32);
        uint4 k0 = kp[0], k1 = kp[1], k2 = kp[2], k3 = kp[3];
        unsigned kwv[16] = { k0.x, k0.y, k0.z, k0.w, k1.x, k1.y, k1.z, k1.w,
                             k2.x, k2.y, k2.z, k2.w, k3.x, k3.y, k3.z, k3.w };
        float a0 = 0.f, a1 = 0.f, a2 = 0.f, a3 = 0.f;
        #pragma unroll
        for (int e = 0; e < 4; ++e) {
            a0 = __builtin_amdgcn_fdot2(__builtin_bit_cast(h2, kwv[4*e+0]), qh[4*e+0], a0, false);
            a1 = __builtin_amdgcn_fdot2(__builtin_bit_cast(h2, kwv[4*e+1]), qh[4*e+1], a1, false);
            a2 = __builtin_amdgcn_fdot2(__builtin_bit_cast(h2, kwv[4*e+2]), qh[4*e+2], a2, false);
            a3 = __builtin_amdgcn_fdot2(__builtin_bit_cast(h2, kwv[4*e+3]), qh[4*e+3], a3, false);
        }
        const int rel0 = kj / 6 - (qi >> 2) + 3;
        const int rel1 = kj % 6 - (qi & 3) + 3;
        sc[kk] = ((a0 + a1) + (a2 + a3)) * 0.17677669529f + rpb[(rel0 * 9 + rel1) * 6 + h];
    }
    float mx = -1e30f;
    #pragma unroll
    for (int kk = 0; kk < 18; ++kk) mx = fmaxf(mx, sc[kk]);
    mx = fmaxf(mx, __shfl_xor(mx, 1));                 // combine pair max
    float sum = 0.f;
    #pragma unroll
    for (int kk = 0; kk < 18; ++kk) { sc[kk] = __expf(sc[kk] - mx); sum += sc[kk]; }
    sum += __shfl_xor(sum, 1);                          // combine pair sum
    const float inv = 1.f / sum;

    h2 o2[16];
    #pragma unroll
    for (int e = 0; e < 16; ++e) o2[e] = (h2){ (_Float16)0.f, (_Float16)0.f };
    const short* vhb = vh + h * HSTR;
    #pragma unroll
    for (int kk = 0; kk < 18; ++kk) {
        const int kj = kbeg + kk;
        const uint4* vp = (const uint4*)(vhb + kj * 32);
        uint4 v0 = vp[0], v1 = vp[1], v2 = vp[2], v3 = vp[3];
        unsigned vwv[16] = { v0.x, v0.y, v0.z, v0.w, v1.x, v1.y, v1.z, v1.w,
                             v2.x, v2.y, v2.z, v2.w, v3.x, v3.y, v3.z, v3.w };
        const _Float16 ph = (_Float16)sc[kk];
        const h2 ph2 = { ph, ph };
        #pragma unroll
        for (int e = 0; e < 16; ++e)
            o2[e] = __builtin_bit_cast(h2, vwv[e]) * ph2 + o2[e];
    }
    // combine pair partial O
    #pragma unroll
    for (int e = 0; e < 16; ++e) {
        unsigned other = __shfl_xor(__builtin_bit_cast(unsigned, o2[e]), 1);
        o2[e] = o2[e] + __builtin_bit_cast(h2, other);
    }
    __syncthreads();                     // all QK/PV reads of kh/vh complete

    // write attention tile (16 tok x 192 ch, bf16, XOR-swizzled) into kh region
    if (split == 0) {
        #pragma unroll
        for (int u = 0; u < 4; ++u) {    // d0 = u*8
            s8v pk;
            #pragma unroll
            for (int e = 0; e < 4; ++e) {
                h2 ov = o2[u * 4 + e];
                pk[2 * e]     = (short)f2bf((float)ov[0] * inv);
                pk[2 * e + 1] = (short)f2bf((float)ov[1] * inv);
            }
            int ba = (qi * 384 + (h * 32 + u * 8) * 2) ^ ((qi & 7) << 4);
            *(s8v*)((char*)kh + ba) = pk;
        }
    }
    __syncthreads();

    // proj MFMA: wave wid handles co-tiles wid*4 .. wid*4+3
    const int cl = lane & 15, kg = lane >> 4;
    s8v a[6];
    #pragma unroll
    for (int kt = 0; kt < 6; ++kt) {
        int ba = (cl * 384 + kt * 64 + kg * 16) ^ ((cl & 7) << 4);
        a[kt] = *(const s8v*)((const char*)kh + ba);
    }
    f32x4 acc[4];
    const s8v* wp8 = (const s8v*)wpf;
    #pragma unroll
    for (int ctl = 0; ctl < 4; ++ctl) {
        float bv = pb[(wid * 4 + ctl) * 16 + cl];
        acc[ctl] = (f32x4){ bv, bv, bv, bv };
    }
    #pragma unroll
    for (int kt = 0; kt < 6; ++kt) {
        #pragma unroll
        for (int ctl = 0; ctl < 4; ++ctl) {
            s8v bfr = wp8[(size_t)(kt * 12 + wid * 4 + ctl) * 64 + lane];
            acc[ctl] = __builtin_amdgcn_mfma_f32_16x16x32_bf16(a[kt], bfr, acc[ctl], 0, 0, 0);
        }
    }
    // D -> vh (plain [16 tok][192])
    #pragma unroll
    for (int ctl = 0; ctl < 4; ++ctl) {
        const int col = (wid * 4 + ctl) * 16 + cl;
        #pragma unroll
        for (int r = 0; r < 4; ++r) {
            vh[(kg * 4 + r) * 192 + col] = (short)f2bf(acc[ctl][r]);
        }
    }
    __syncthreads();

    // copy out with residual: 384 s8v units over 192 threads = 2 iterations
    #pragma unroll
    for (int u = 0; u < 2; ++u) {
        int li = u * 192 + tid;
        int row = li / 24, c8 = (li % 24) * 8;
        int qr2 = nhi * 4 + (row >> 2), qc2 = nwi * 4 + (row & 3);
        size_t gb = ((size_t)(b * TOKPB + qr2 * CW + qc2)) * 192 + c8;
        s8v pv = *(const s8v*)(vh + row * 192 + c8);
        s8v rv = *(const s8v*)(t0 + gb);
        s8v ov;
        #pragma unroll
        for (int e = 0; e < 8; ++e) ov[e] = (short)f2bf(bf2f(pv[e]) + bf2f(rv[e]));
        *(s8v*)(omid + gb) = ov;
    }
}

// ---------------- final: out = relu(C2 + conv1x1(x)), MFMA ----------------
__global__ __launch_bounds__(256, 4) void final_mfma_kernel(
    const float* __restrict__ x, const short* __restrict__ w3f,
    const float* __restrict__ b3, const bf16* __restrict__ c2,
    float* __restrict__ out)
{
    __shared__ short xs2[12288];      // [64 pix][192 ci] bf16, row-swizzled
    const int pix0 = blockIdx.x * 64;
    const int b    = blockIdx.y;
    const int tid = threadIdx.x, lane = tid & 63, wid = tid >> 6;
    const int cl = lane & 15, kg = lane >> 4;
    const float* xb = x + (size_t)b * (192 * TOKPB);

    #pragma unroll
    for (int u = 0; u < 12; ++u) {
        int idx = u * 256 + tid;                  // 3072 float4
        int ci = idx >> 4, p4 = (idx & 15) << 2;
        float4 v = *(const float4*)(xb + (size_t)ci * TOKPB + pix0 + p4);
        float vv[4] = { v.x, v.y, v.z, v.w };
        #pragma unroll
        for (int k = 0; k < 4; ++k) {
            int row = p4 + k;
            int ba = (row * 384 + ci * 2) ^ ((row & 7) << 4);
            *(short*)((char*)xs2 + ba) = (short)f2bf(vv[k]);
        }
    }
    __syncthreads();

    const int ctb = wid * 3;
    f32x4 acc[3][4] = {};
    const s8v* wf8 = (const s8v*)w3f;

    #pragma unroll
    for (int kt = 0; kt < 6; ++kt) {
        s8v a0 = wf8[(size_t)(kt * 12 + ctb + 0) * 64 + lane];
        s8v a1 = wf8[(size_t)(kt * 12 + ctb + 1) * 64 + lane];
        s8v a2 = wf8[(size_t)(kt * 12 + ctb + 2) * 64 + lane];
        #pragma unroll
        for (int pt = 0; pt < 4; ++pt) {
            int row = pt * 16 + cl;
            int ba = (row * 384 + kt * 64 + kg * 16) ^ ((row & 7) << 4);
            s8v bfr = *(const s8v*)((const char*)xs2 + ba);
            acc[0][pt] = __builtin_amdgcn_mfma_f32_16x16x32_bf16(a0, bfr, acc[0][pt], 0, 0, 0);
            acc[1][pt] = __builtin_amdgcn_mfma_f32_16x16x32_bf16(a1, bfr, acc[1][pt], 0, 0, 0);
            acc[2][pt] = __builtin_amdgcn_mfma_f32_16x16x32_bf16(a2, bfr, acc[2][pt], 0, 0, 0);
        }
    }

    #pragma unroll
    for (int t = 0; t < 3; ++t) {
        #pragma unroll
        for (int r = 0; r < 4; ++r) {
            const int co = (ctb + t) * 16 + kg * 4 + r;
            const float bb = b3[co];
            const size_t rowbase = (size_t)b * (192 * TOKPB) + (size_t)co * TOKPB + pix0;
            #pragma unroll
            for (int pt = 0; pt < 4; ++pt) {
                const size_t f = rowbase + pt * 16 + cl;
                float v = acc[t][pt][r] + bb + bf2f(__builtin_bit_cast(short, c2[f]));
                out[f] = fmaxf(v, 0.f);
            }
        }
    }
}

// ---------------- host launch ----------------
extern "C" void kernel_launch(void* const* d_in, const int* in_sizes, int n_in,
                              void* d_out, int out_size, void* d_ws, size_t ws_size,
                              hipStream_t stream)
{
    if (ws_size < WS_NEEDED) return;

    const float* x       = (const float*)d_in[0];
    const float* conv1_w = (const float*)d_in[1];
    const float* conv1_b = (const float*)d_in[2];
    const float* gn1_g   = (const float*)d_in[3];
    const float* gn1_b   = (const float*)d_in[4];
    const float* conv2_w = (const float*)d_in[5];
    const float* conv2_b = (const float*)d_in[6];
    const float* gn2_g   = (const float*)d_in[7];
    const float* gn2_b   = (const float*)d_in[8];
    const float* conv3_w = (const float*)d_in[9];
    const float* conv3_b = (const float*)d_in[10];
    const float* ln1_g   = (const float*)d_in[11];
    const float* ln1_b   = (const float*)d_in[12];
    const float* qkv_w   = (const float*)d_in[13];
    const float* qkv_b   = (const float*)d_in[14];
    const float* rpb     = (const float*)d_in[15];
    const float* proj_w  = (const float*)d_in[16];
    const float* proj_b  = (const float*)d_in[17];
    const float* ln2_g   = (const float*)d_in[18];
    const float* ln2_b   = (const float*)d_in[19];
    const float* fc1_w   = (const float*)d_in[20];
    const float* fc1_b   = (const float*)d_in[21];
    const float* fc2_w   = (const float*)d_in[22];
    const float* fc2_b   = (const float*)d_in[23];

    char* wsb = (char*)d_ws;
    bf16*  T0  = (bf16*)(wsb + B_T0);
    _Float16* QF = (_Float16*)(wsb + B_P2);   // Q/K/V f16 sections; later HID bf16
    bf16*  HID = (bf16*)(wsb + B_P2);
    bf16*  P3  = (bf16*)(wsb + B_P3);
    bf16*  P4  = (bf16*)(wsb + B_P4);
    short* WF1 = (short*)(wsb + B_WF1);
    short* WF2 = (short*)(wsb + B_WF2);
    short* W3F = (short*)(wsb + B_W3F);
    short* WQ  = (short*)(wsb + B_WQ);
    short* WP  = (short*)(wsb + B_WP);
    short* WG1 = (short*)(wsb + B_WG1);
    short* WG2 = (short*)(wsb + B_WG2);
    float* OUT = (float*)d_out;

    // fused weight prep (single launch)
    prep_all_kernel<<<(PREP_TOTAL + 255) / 256, 256, 0, stream>>>(
        conv1_w, WF1, conv2_w, WF2, conv3_w, W3F, qkv_w, WQ, proj_w, WP, fc1_w, WG1, fc2_w, WG2);

    // stage A: conv1 + gn1 + silu -> T0 (token layout, bf16)
    conv_mfma_kernel<true><<<NPATCH / 4, 256, 0, stream>>>(x, WF1, conv1_b, gn1_g, gn1_b, T0);
    // stage C: LN1 (fused, once) + qkv gemm -> QF/KF/VF (f16 head-major)
    gemm_mfma_kernel<false, false, true, true, 6><<<dim3(MTOK / 128, 1), 256, 0, stream>>>(
        T0, WQ, qkv_b, nullptr, QF, 576, ln1_g, ln1_b);
    // stage D+E: attention + proj + shortcut(T0) -> P4 (OMID); 192 threads, pair-split keys
    attn_proj_kernel<<<NPATCH, 192, 0, stream>>>(QF, rpb, WP, proj_b, T0, P4);
    // stage G: LN2 (fused) + fc1 + gelu -> HID
    gemm_mfma_kernel<false, true, true, false, 6><<<dim3(MTOK / 128, 1), 256, 0, stream>>>(
        P4, WG1, fc1_b, nullptr, HID, 384, ln2_g, ln2_b);
    // stage H: fc2 + residual(OMID P4) -> P3 (OCAB, bf16 token layout)
    gemm_mfma_kernel<true, false, false, false, 12><<<dim3(MTOK / 128, 1), 256, 0, stream>>>(
        HID, WG2, fc2_b, P4, P3, 192, nullptr, nullptr);
    // stage I: conv2 + gn2 (reads P3) -> P4 (C2, bf16 patch-flat); OMID already consumed
    conv_mfma_kernel<false><<<NPATCH / 4, 256, 0, stream>>>(P3, WF2, conv2_b, gn2_g, gn2_b, P4);
    // stage J: out = relu(C2 + conv1x1(x)) -> d_out, MFMA
    final_mfma_kernel<<<dim3(TOKPB / 64, CB), 256, 0, stream>>>(x, W3F, conv3_b, P4, OUT);
}

// Round 18
// 503.970 us; speedup vs baseline: 1.8508x; 1.0057x over previous
//
#include <hip/hip_runtime.h>
#include <hip/hip_bf16.h>
#include <math.h>

typedef __hip_bfloat16 bf16;
typedef __attribute__((ext_vector_type(8))) short s8v;
typedef __attribute__((ext_vector_type(4))) short s4v;
typedef __attribute__((ext_vector_type(4))) float f32x4;
typedef __attribute__((ext_vector_type(2))) _Float16 h2;

// ---------------- problem constants ----------------
constexpr int CB   = 2;            // batch
constexpr int CH   = 224, CW = 224;
constexpr int NHW  = 56;           // H/WS
constexpr int NPATCH = CB * NHW * NHW;   // 6272
constexpr int TOKPB  = CH * CW;          // 50176 tokens per batch
constexpr int MTOK   = CB * TOKPB;       // 100352 rows
constexpr size_t SECSZ = 19267584;       // elems per q/k/v f16 section

// ---------------- ws layout (BYTE offsets) ----------------
constexpr size_t B_T0  = 0;                         // 19267584 bf16
constexpr size_t B_P2  = B_T0 + 38535168;           // QF/KF/VF f16 (3x38.5MB); later HID bf16
constexpr size_t B_P3  = B_P2 + 115605504;          // 19267584 bf16 (OCAB)
constexpr size_t B_P4  = B_P3 + 38535168;           // 19267584 bf16 (OMID -> C2)
constexpr size_t B_WF1 = B_P4 + 38535168;           // conv1 frag weights
constexpr size_t B_WF2 = B_WF1 + 1327104;           // conv2 frag weights
constexpr size_t B_W3F = B_WF2 + 1327104;           // conv3 1x1 frag weights
constexpr size_t B_WQ  = B_W3F + 147456;            // qkv_w frag
constexpr size_t B_WP  = B_WQ + 221184;             // proj_w frag
constexpr size_t B_WG1 = B_WP + 73728;              // fc1_w frag
constexpr size_t B_WG2 = B_WG1 + 147456;            // fc2_w frag
constexpr size_t WS_NEEDED = B_WG2 + 147456;        // 234,602,496 B

// ---------------- type helpers ----------------
__device__ __forceinline__ float ldf(const float* p) { return *p; }
__device__ __forceinline__ float ldf(const bf16* p)  { return __bfloat162float(*p); }
__device__ __forceinline__ void  stf(float* p, float v) { *p = v; }
__device__ __forceinline__ void  stf(bf16* p, float v)  { *p = __float2bfloat16(v); }
__device__ __forceinline__ unsigned short f2bf(float f) {
    unsigned u = __builtin_bit_cast(unsigned, f);
    unsigned r = (u + 0x7fffu + ((u >> 16) & 1u)) >> 16;
    return (unsigned short)r;
}
__device__ __forceinline__ float bf2f(short s) {
    unsigned u = ((unsigned)(unsigned short)s) << 16;
    return __builtin_bit_cast(float, u);
}

// ---------------- fused weight pre-pack (one launch) ----------------
__device__ __forceinline__ void prep_wf(const float* __restrict__ w, short* __restrict__ wf, int o) {
    int within = o & 511, frag = o >> 9;
    int l = within >> 3, j = within & 7;
    int nt = frag % 12, t2 = frag / 12, ks = t2 % 6, tap = t2 / 6;
    int co = nt * 16 + (l & 15);
    int ci = ks * 32 + (l >> 4) * 8 + j;
    wf[o] = (short)f2bf(w[(co * 192 + ci) * 9 + tap]);
}
__device__ __forceinline__ void prep_wgemm(const float* __restrict__ w, short* __restrict__ wf,
                                           int K, int N, int o) {
    int j = o & 7, l = (o >> 3) & 63, f = o >> 9;
    int ntiles = N >> 4;
    int kt = f / ntiles, nt = f % ntiles;
    int k = kt * 32 + (l >> 4) * 8 + j;
    int col = nt * 16 + (l & 15);
    wf[o] = (short)f2bf(w[(size_t)k * N + col]);
}
__device__ __forceinline__ void prep_w3f(const float* __restrict__ w, short* __restrict__ wf, int o) {
    int j = o & 7, l = (o >> 3) & 63, f = o >> 9;   // f = kt*12 + ct
    int kt = f / 12, ct = f % 12;
    int co = ct * 16 + (l & 15);
    int ci = kt * 32 + (l >> 4) * 8 + j;
    wf[o] = (short)f2bf(w[co * 192 + ci]);
}
__global__ __launch_bounds__(256) void prep_all_kernel(
    const float* __restrict__ conv1_w, short* __restrict__ WF1,
    const float* __restrict__ conv2_w, short* __restrict__ WF2,
    const float* __restrict__ conv3_w, short* __restrict__ W3F,
    const float* __restrict__ qkv_w,   short* __restrict__ WQ,
    const float* __restrict__ proj_w,  short* __restrict__ WP,
    const float* __restrict__ fc1_w,   short* __restrict__ WG1,
    const float* __restrict__ fc2_w,   short* __restrict__ WG2)
{
    int o = blockIdx.x * 256 + threadIdx.x;
    if (o < 331776)            { prep_wf(conv1_w, WF1, o); return; }
    o -= 331776;
    if (o < 331776)            { prep_wf(conv2_w, WF2, o); return; }
    o -= 331776;
    if (o < 36864)             { prep_w3f(conv3_w, W3F, o); return; }
    o -= 36864;
    if (o < 110592)            { prep_wgemm(qkv_w, WQ, 192, 576, o); return; }
    o -= 110592;
    if (o < 36864)             { prep_wgemm(proj_w, WP, 192, 192, o); return; }
    o -= 36864;
    if (o < 73728)             { prep_wgemm(fc1_w, WG1, 192, 384, o); return; }
    o -= 73728;
    if (o < 73728)             { prep_wgemm(fc2_w, WG2, 384, 192, o); return; }
}
constexpr int PREP_TOTAL = 331776 * 2 + 36864 + 110592 + 36864 + 73728 * 2;  // 995328

// ---------------- conv3x3 (4x4 patches) + groupnorm (+silu), MFMA ----------------
template <bool FIRST>
__global__ __launch_bounds__(256, 4) void conv_mfma_kernel(
    const void* __restrict__ srcv, const short* __restrict__ wf,
    const float* __restrict__ bias, const float* __restrict__ gng,
    const float* __restrict__ gnb, bf16* __restrict__ dst)
{
    __shared__ short xs[13056];          // 4 patches * 17 rows * 384B (row 16 = zeros), swizzled
    __shared__ float gsum[4][6], gsum2[4][6], gmu[4][6], grs[4][6];
    const int tid  = threadIdx.x;
    const int lane = tid & 63, wid = tid >> 6;
    const int n0   = blockIdx.x * 4;

    if (tid < 24) { gsum[tid / 6][tid % 6] = 0.f; gsum2[tid / 6][tid % 6] = 0.f; }
    for (int u = tid; u < 4 * 192; u += 256) {       // zero rows
        int q = u / 192;
        xs[q * 3264 + 3072 + (u % 192)] = 0;
    }

    if constexpr (FIRST) {
        const float4* sp = (const float4*)((const float*)srcv + (size_t)n0 * 3072);
        #pragma unroll
        for (int u = 0; u < 12; ++u) {
            int idx = u * 256 + tid;                 // float4 index, 3072 total
            float4 v = sp[idx];
            int q = idx / 768;
            int li = (idx % 768) * 4;                // li = ci*16 + p
            int ci = li >> 4, p0 = li & 15;
            float vv[4] = { v.x, v.y, v.z, v.w };
            #pragma unroll
            for (int k = 0; k < 4; ++k) {
                int row = p0 + k;
                int ba = q * 6528 + ((row * 384 + ci * 2) ^ ((row & 7) << 4));
                *(short*)((char*)xs + ba) = (short)f2bf(vv[k]);
            }
        }
    } else {
        const s8v* sp8 = (const s8v*)((const bf16*)srcv + (size_t)n0 * 3072);
        #pragma unroll
        for (int u = 0; u < 6; ++u) {
            int li = u * 256 + tid;                  // 1536 s8v units
            int r = li / 24, ch = li % 24;
            int q = r >> 4, rl = r & 15;
            s8v val = sp8[li];
            int ba = q * 6528 + ((rl * 384 + ch * 16) ^ ((rl & 7) << 4));
            *(s8v*)((char*)xs + ba) = val;
        }
    }
    __syncthreads();

    const int ntb = wid * 3;
    const int cl  = lane & 15;
    const int kg  = lane >> 4;
    f32x4 acc[3][4];
    #pragma unroll
    for (int t = 0; t < 3; ++t) {
        float bv = bias[(ntb + t) * 16 + cl];
        #pragma unroll
        for (int q = 0; q < 4; ++q) acc[t][q] = (f32x4){ bv, bv, bv, bv };
    }

    const int pi = cl >> 2, pj = cl & 3;
    const s8v* wf8 = (const s8v*)wf;

    for (int tap = 0; tap < 9; ++tap) {
        const int di = tap / 3, dj = tap % 3;
        const int ii = pi + di - 1, jj = pj + dj - 1;
        const bool valid = (ii >= 0 && ii < 4 && jj >= 0 && jj < 4);
        const int nr  = valid ? (ii * 4 + jj) : 16;   // row 16 = zero row
        const int rb  = nr * 384;
        const int swz = (nr & 7) << 4;
        #pragma unroll
        for (int ks = 0; ks < 6; ++ks) {
            const s8v* bp = wf8 + (size_t)((tap * 6 + ks) * 12) * 64 + lane;
            s8v b0 = bp[(ntb + 0) * 64];
            s8v b1 = bp[(ntb + 1) * 64];
            s8v b2 = bp[(ntb + 2) * 64];
            const int inner = (rb + ks * 64 + kg * 16) ^ swz;
            #pragma unroll
            for (int q = 0; q < 4; ++q) {
                s8v a = *(const s8v*)((const char*)xs + q * 6528 + inner);
                acc[0][q] = __builtin_amdgcn_mfma_f32_16x16x32_bf16(a, b0, acc[0][q], 0, 0, 0);
                acc[1][q] = __builtin_amdgcn_mfma_f32_16x16x32_bf16(a, b1, acc[1][q], 0, 0, 0);
                acc[2][q] = __builtin_amdgcn_mfma_f32_16x16x32_bf16(a, b2, acc[2][q], 0, 0, 0);
            }
        }
    }

    #pragma unroll
    for (int t = 0; t < 3; ++t) {
        const int g = (ntb + t) >> 1;
        #pragma unroll
        for (int q = 0; q < 4; ++q) {
            f32x4 A = acc[t][q];
            float s  = A[0] + A[1] + A[2] + A[3];
            float s2 = A[0]*A[0] + A[1]*A[1] + A[2]*A[2] + A[3]*A[3];
            #pragma unroll
            for (int off = 32; off; off >>= 1) { s += __shfl_xor(s, off); s2 += __shfl_xor(s2, off); }
            if (lane == 0) { atomicAdd(&gsum[q][g], s); atomicAdd(&gsum2[q][g], s2); }
        }
    }
    __syncthreads();
    if (tid < 24) {
        int q = tid / 6, g = tid % 6;
        float mu  = gsum[q][g] * (1.f / 512.f);
        float var = gsum2[q][g] * (1.f / 512.f) - mu * mu;
        gmu[q][g] = mu; grs[q][g] = rsqrtf(var + 1e-5f);
    }
    __syncthreads();

    if constexpr (FIRST) {
        #pragma unroll
        for (int t = 0; t < 3; ++t) {
            const int co = (ntb + t) * 16 + cl, g = (ntb + t) >> 1;
            const float gg = gng[co], gb = gnb[co];
            #pragma unroll
            for (int q = 0; q < 4; ++q) {
                const float mu = gmu[q][g], rs = grs[q][g];
                #pragma unroll
                for (int r = 0; r < 4; ++r) {
                    float v = (acc[t][q][r] - mu) * rs * gg + gb;
                    v = v / (1.f + __expf(-v));      // silu (fast exp)
                    int row = q * 16 + kg * 4 + r;
                    int ba = (row * 384 + co * 2) ^ ((row & 7) << 4);
                    *(short*)((char*)xs + ba) = (short)f2bf(v);
                }
            }
        }
        __syncthreads();
        bf16* dp = dst + (size_t)n0 * 3072;          // token-major [tok][192], contiguous block
        #pragma unroll
        for (int u = 0; u < 6; ++u) {
            int li = u * 256 + tid;                  // 1536 s8v units
            int row = li / 24, g2 = li % 24;
            int ba = (row * 384 + g2 * 16) ^ ((row & 7) << 4);
            s8v val = *(const s8v*)((const char*)xs + ba);
            *(s8v*)(dp + (size_t)row * 192 + g2 * 8) = val;
        }
    } else {
        #pragma unroll
        for (int t = 0; t < 3; ++t) {
            const int co = (ntb + t) * 16 + cl, g = (ntb + t) >> 1;
            const float gg = gng[co], gb = gnb[co];
            #pragma unroll
            for (int q = 0; q < 4; ++q) {
                const float mu = gmu[q][g], rs = grs[q][g];
                #pragma unroll
                for (int r = 0; r < 4; ++r) {
                    float v = (acc[t][q][r] - mu) * rs * gg + gb;
                    xs[q * 3072 + co * 16 + kg * 4 + r] = (short)f2bf(v);
                }
            }
        }
        __syncthreads();
        s4v* dp = (s4v*)(dst + (size_t)n0 * 3072);
        const s4v* sps = (const s4v*)xs;
        #pragma unroll
        for (int u = 0; u < 12; ++u) {
            dp[u * 256 + tid] = sps[u * 256 + tid];
        }
    }
}

// ---------------- MFMA GEMM, single-pass over an N-range, LDS-transpose epilogue ----
template <bool RES, bool GELU_ACT, bool LN, bool QKVOUT, int NKT>
__global__ __launch_bounds__(256) void gemm_mfma_kernel(
    const bf16* __restrict__ A, const short* __restrict__ wfb,
    const float* __restrict__ bias, const bf16* __restrict__ res,
    void* __restrict__ out, int N,
    const float* __restrict__ lng, const float* __restrict__ lnb)
{
    __shared__ short ls[8192];           // [128 rows][64 cols] 2B, XOR-swizzled
    const int tid = threadIdx.x, lane = tid & 63, wid = tid >> 6;
    const int m0 = blockIdx.x * 128;
    const int cl = lane & 15, kg = lane >> 4;
    constexpr int K = NKT * 32;
    const int ntiles = N >> 4;
    const int ntsec = ntiles / gridDim.y;
    const int ntbeg = blockIdx.y * ntsec;

    s8v af0[NKT], af1[NKT];
    const int r0 = m0 + wid * 32 + cl;
    #pragma unroll
    for (int kt = 0; kt < NKT; ++kt) {
        af0[kt] = *(const s8v*)(A + (size_t)r0 * K + kt * 32 + kg * 8);
        af1[kt] = *(const s8v*)(A + (size_t)(r0 + 16) * K + kt * 32 + kg * 8);
    }
    if constexpr (LN) {
        static_assert(!LN || NKT == 6, "LN requires K==192");
        #pragma unroll
        for (int r = 0; r < 2; ++r) {
            s8v* af = r ? af1 : af0;
            float s = 0.f, s2 = 0.f;
            #pragma unroll
            for (int kt = 0; kt < NKT; ++kt)
                #pragma unroll
                for (int j = 0; j < 8; ++j) {
                    float v = bf2f(af[kt][j]);
                    s += v; s2 += v * v;
                }
            s  += __shfl_xor(s, 16);  s2 += __shfl_xor(s2, 16);
            s  += __shfl_xor(s, 32);  s2 += __shfl_xor(s2, 32);
            const float mu = s * (1.f / 192.f);
            const float rs = rsqrtf(s2 * (1.f / 192.f) - mu * mu + 1e-5f);
            #pragma unroll
            for (int kt = 0; kt < NKT; ++kt) {
                const float* gp = lng + kt * 32 + kg * 8;
                const float* bp = lnb + kt * 32 + kg * 8;
                #pragma unroll
                for (int j = 0; j < 8; ++j) {
                    float v = (bf2f(af[kt][j]) - mu) * rs * gp[j] + bp[j];
                    af[kt][j] = (short)f2bf(v);
                }
            }
        }
    }

    const s8v* wf8 = (const s8v*)wfb;
    for (int nt0 = ntbeg; nt0 < ntbeg + ntsec; nt0 += 4) {
        const int n0 = nt0 * 16;
        f32x4 acc[2][4];
        #pragma unroll
        for (int nf = 0; nf < 4; ++nf) {
            float bv = bias[n0 + nf * 16 + cl];
            acc[0][nf] = (f32x4){ bv, bv, bv, bv };
            acc[1][nf] = (f32x4){ bv, bv, bv, bv };
        }
        #pragma unroll
        for (int kt = 0; kt < NKT; ++kt) {
            #pragma unroll
            for (int nf = 0; nf < 4; ++nf) {
                s8v b = wf8[(size_t)(kt * ntiles + nt0 + nf) * 64 + lane];
                acc[0][nf] = __builtin_amdgcn_mfma_f32_16x16x32_bf16(af0[kt], b, acc[0][nf], 0, 0, 0);
                acc[1][nf] = __builtin_amdgcn_mfma_f32_16x16x32_bf16(af1[kt], b, acc[1][nf], 0, 0, 0);
            }
        }

        __syncthreads();
        #pragma unroll
        for (int rf = 0; rf < 2; ++rf) {
            #pragma unroll
            for (int nf = 0; nf < 4; ++nf) {
                const int lcol = nf * 16 + cl;
                #pragma unroll
                for (int r = 0; r < 4; ++r) {
                    const int lrow = wid * 32 + rf * 16 + kg * 4 + r;
                    float v = acc[rf][nf][r];
                    if (GELU_ACT) v = 0.5f * v * (1.f + erff(v * 0.70710678118f));
                    short sv;
                    if constexpr (QKVOUT) sv = __builtin_bit_cast(short, (_Float16)v);
                    else                  sv = (short)f2bf(v);
                    int ba = (lrow * 128 + lcol * 2) ^ ((lrow & 7) << 4);
                    *(short*)((char*)ls + ba) = sv;
                }
            }
        }
        __syncthreads();
        #pragma unroll
        for (int p = 0; p < 4; ++p) {
            const int lrow = p * 32 + (tid >> 3);
            const int g = tid & 7;
            int ba = (lrow * 128 + g * 16) ^ ((lrow & 7) << 4);
            s8v val = *(const s8v*)((const char*)ls + ba);
            const int row = m0 + lrow;
            const int col0 = n0 + g * 8;
            if constexpr (QKVOUT) {
                const int sec = n0 / 192;        // 64-col chunk never crosses a section
                const int c0 = col0 - sec * 192, h = c0 >> 5, d0 = c0 & 31;
                const int bb2 = row / TOKPB, t = row - bb2 * TOKPB;
                *(s8v*)((_Float16*)out + (size_t)sec * SECSZ +
                        ((size_t)(bb2 * 6 + h) * TOKPB + t) * 32 + d0) = val;
            } else if constexpr (RES) {
                s8v rv = *(const s8v*)(res + (size_t)row * N + col0);
                s8v ov;
                #pragma unroll
                for (int e = 0; e < 8; ++e) ov[e] = (short)f2bf(bf2f(val[e]) + bf2f(rv[e]));
                *(s8v*)((bf16*)out + (size_t)row * N + col0) = ov;
            } else {
                *(s8v*)((bf16*)out + (size_t)row * N + col0) = val;
            }
        }
    }
}

// ---------------- fused attention + proj + residual, 192 threads ----------------
// 96 (head,token) jobs x 2 key-splits (18 keys each); pair combine via shfl_xor(1).
// After PV, kh region holds the 16x192 attention tile (swizzled); proj = 3 waves x
// 4 co-tiles of mfma_16x16x32_bf16; epilogue adds T0 residual.
constexpr int HSTR = 1160;   // per-head LDS stride in shorts (36*32 + 8 pad)
__global__ __launch_bounds__(192) void attn_proj_kernel(
    const _Float16* __restrict__ qf, const float* __restrict__ rpb,
    const short* __restrict__ wpf, const float* __restrict__ pb,
    const bf16* __restrict__ t0, bf16* __restrict__ omid)
{
    __shared__ __align__(16) short kh[6 * HSTR];
    __shared__ __align__(16) short vh[6 * HSTR];
    const int w = blockIdx.x;
    const int b = w / (NHW * NHW), wi = w % (NHW * NHW);
    const int nhi = wi / NHW, nwi = wi % NHW;
    const int tid = threadIdx.x;
    const int lane = tid & 63, wid = tid >> 6;
    const int r0 = nhi * 4 - 1, c0 = nwi * 4 - 1;
    const _Float16* kfb = qf + SECSZ;
    const _Float16* vfb = qf + 2 * SECSZ;

    // stage K and V: 1728 units of 16B over 192 threads = 9 iterations
    #pragma unroll
    for (int it = 0; it < 9; ++it) {
        int v = tid + it * 192;
        int kv = v >= 864 ? 1 : 0;
        int u = v - kv * 864;
        int h = u / 144, rem = u % 144, kj = rem >> 2, d0 = (rem & 3) * 8;
        int rr = r0 + kj / 6, cc = c0 + kj % 6;
        s8v val = { 0, 0, 0, 0, 0, 0, 0, 0 };
        if (rr >= 0 && rr < CH && cc >= 0 && cc < CW) {
            const _Float16* src = kv ? vfb : kfb;
            val = *(const s8v*)(src + ((size_t)(b * 6 + h) * TOKPB + rr * CW + cc) * 32 + d0);
        }
        short* dst = kv ? vh : kh;
        *(s8v*)(dst + h * HSTR + kj * 32 + d0) = val;
    }
    __syncthreads();

    // compute: pair = tid>>1 (h,qi), split = tid&1 handles keys [split*18, split*18+18)
    const int pair = tid >> 1, split = tid & 1;
    const int h = pair >> 4, qi = pair & 15;
    const int qr = nhi * 4 + (qi >> 2), qc = nwi * 4 + (qi & 3);
    const _Float16* qp = qf + ((size_t)(b * 6 + h) * TOKPB + qr * CW + qc) * 32;
    h2 qh[16];
    #pragma unroll
    for (int u = 0; u < 4; ++u) {
        uint4 qa = *(const uint4*)(qp + u * 8);
        qh[u * 4 + 0] = __builtin_bit_cast(h2, qa.x);
        qh[u * 4 + 1] = __builtin_bit_cast(h2, qa.y);
        qh[u * 4 + 2] = __builtin_bit_cast(h2, qa.z);
        qh[u * 4 + 3] = __builtin_bit_cast(h2, qa.w);
    }

    float sc[18];
    const int kbeg = split * 18;
    const short* khb = kh + h * HSTR;
    #pragma unroll
    for (int kk = 0; kk < 18; ++kk) {
        const int kj = kbeg + kk;
        const uint4* kp = (const uint4*)(khb + kj * 32);
        uint4 k0 = kp[0], k1 = kp[1], k2 = kp[2], k3 = kp[3];
        unsigned kwv[16] = { k0.x, k0.y, k0.z, k0.w, k1.x, k1.y, k1.z, k1.w,
                             k2.x, k2.y, k2.z, k2.w, k3.x, k3.y, k3.z, k3.w };
        float a0 = 0.f, a1 = 0.f, a2 = 0.f, a3 = 0.f;
        #pragma unroll
        for (int e = 0; e < 4; ++e) {
            a0 = __builtin_amdgcn_fdot2(__builtin_bit_cast(h2, kwv[4*e+0]), qh[4*e+0], a0, false);
            a1 = __builtin_amdgcn_fdot2(__builtin_bit_cast(h2, kwv[4*e+1]), qh[4*e+1], a1, false);
            a2 = __builtin_amdgcn_fdot2(__builtin_bit_cast(h2, kwv[4*e+2]), qh[4*e+2], a2, false);
            a3 = __builtin_amdgcn_fdot2(__builtin_bit_cast(h2, kwv[4*e+3]), qh[4*e+3], a3, false);
        }
        const int rel0 = kj / 6 - (qi >> 2) + 3;
        const int rel1 = kj % 6 - (qi & 3) + 3;
        sc[kk] = ((a0 + a1) + (a2 + a3)) * 0.17677669529f + rpb[(rel0 * 9 + rel1) * 6 + h];
    }
    float mx = -1e30f;
    #pragma unroll
    for (int kk = 0; kk < 18; ++kk) mx = fmaxf(mx, sc[kk]);
    mx = fmaxf(mx, __shfl_xor(mx, 1));                 // combine pair max
    float sum = 0.f;
    #pragma unroll
    for (int kk = 0; kk < 18; ++kk) { sc[kk] = __expf(sc[kk] - mx); sum += sc[kk]; }
    sum += __shfl_xor(sum, 1);                          // combine pair sum
    const float inv = 1.f / sum;

    h2 o2[16];
    #pragma unroll
    for (int e = 0; e < 16; ++e) o2[e] = (h2){ (_Float16)0.f, (_Float16)0.f };
    const short* vhb = vh + h * HSTR;
    #pragma unroll
    for (int kk = 0; kk < 18; ++kk) {
        const int kj = kbeg + kk;
        const uint4* vp = (const uint4*)(vhb + kj * 32);
        uint4 v0 = vp[0], v1 = vp[1], v2 = vp[2], v3 = vp[3];
        unsigned vwv[16] = { v0.x, v0.y, v0.z, v0.w, v1.x, v1.y, v1.z, v1.w,
                             v2.x, v2.y, v2.z, v2.w, v3.x, v3.y, v3.z, v3.w };
        const _Float16 ph = (_Float16)sc[kk];
        const h2 ph2 = { ph, ph };
        #pragma unroll
        for (int e = 0; e < 16; ++e)
            o2[e] = __builtin_bit_cast(h2, vwv[e]) * ph2 + o2[e];
    }
    // combine pair partial O
    #pragma unroll
    for (int e = 0; e < 16; ++e) {
        unsigned other = __shfl_xor(__builtin_bit_cast(unsigned, o2[e]), 1);
        o2[e] = o2[e] + __builtin_bit_cast(h2, other);
    }
    __syncthreads();                     // all QK/PV reads of kh/vh complete

    // write attention tile (16 tok x 192 ch, bf16, XOR-swizzled) into kh region
    if (split == 0) {
        #pragma unroll
        for (int u = 0; u < 4; ++u) {    // d0 = u*8
            s8v pk;
            #pragma unroll
            for (int e = 0; e < 4; ++e) {
                h2 ov = o2[u * 4 + e];
                pk[2 * e]     = (short)f2bf((float)ov[0] * inv);
                pk[2 * e + 1] = (short)f2bf((float)ov[1] * inv);
            }
            int ba = (qi * 384 + (h * 32 + u * 8) * 2) ^ ((qi & 7) << 4);
            *(s8v*)((char*)kh + ba) = pk;
        }
    }
    __syncthreads();

    // proj MFMA: wave wid handles co-tiles wid*4 .. wid*4+3
    const int cl = lane & 15, kg = lane >> 4;
    s8v a[6];
    #pragma unroll
    for (int kt = 0; kt < 6; ++kt) {
        int ba = (cl * 384 + kt * 64 + kg * 16) ^ ((cl & 7) << 4);
        a[kt] = *(const s8v*)((const char*)kh + ba);
    }
    f32x4 acc[4];
    const s8v* wp8 = (const s8v*)wpf;
    #pragma unroll
    for (int ctl = 0; ctl < 4; ++ctl) {
        float bv = pb[(wid * 4 + ctl) * 16 + cl];
        acc[ctl] = (f32x4){ bv, bv, bv, bv };
    }
    #pragma unroll
    for (int kt = 0; kt < 6; ++kt) {
        #pragma unroll
        for (int ctl = 0; ctl < 4; ++ctl) {
            s8v bfr = wp8[(size_t)(kt * 12 + wid * 4 + ctl) * 64 + lane];
            acc[ctl] = __builtin_amdgcn_mfma_f32_16x16x32_bf16(a[kt], bfr, acc[ctl], 0, 0, 0);
        }
    }
    // D -> vh (plain [16 tok][192])
    #pragma unroll
    for (int ctl = 0; ctl < 4; ++ctl) {
        const int col = (wid * 4 + ctl) * 16 + cl;
        #pragma unroll
        for (int r = 0; r < 4; ++r) {
            vh[(kg * 4 + r) * 192 + col] = (short)f2bf(acc[ctl][r]);
        }
    }
    __syncthreads();

    // copy out with residual: 384 s8v units over 192 threads = 2 iterations
    #pragma unroll
    for (int u = 0; u < 2; ++u) {
        int li = u * 192 + tid;
        int row = li / 24, c8 = (li % 24) * 8;
        int qr2 = nhi * 4 + (row >> 2), qc2 = nwi * 4 + (row & 3);
        size_t gb = ((size_t)(b * TOKPB + qr2 * CW + qc2)) * 192 + c8;
        s8v pv = *(const s8v*)(vh + row * 192 + c8);
        s8v rv = *(const s8v*)(t0 + gb);
        s8v ov;
        #pragma unroll
        for (int e = 0; e < 8; ++e) ov[e] = (short)f2bf(bf2f(pv[e]) + bf2f(rv[e]));
        *(s8v*)(omid + gb) = ov;
    }
}

// ---------------- final: out = relu(C2 + conv1x1(x)), MFMA ----------------
__global__ __launch_bounds__(256, 4) void final_mfma_kernel(
    const float* __restrict__ x, const short* __restrict__ w3f,
    const float* __restrict__ b3, const bf16* __restrict__ c2,
    float* __restrict__ out)
{
    __shared__ short xs2[12288];      // [64 pix][192 ci] bf16, row-swizzled
    const int pix0 = blockIdx.x * 64;
    const int b    = blockIdx.y;
    const int tid = threadIdx.x, lane = tid & 63, wid = tid >> 6;
    const int cl = lane & 15, kg = lane >> 4;
    const float* xb = x + (size_t)b * (192 * TOKPB);

    #pragma unroll
    for (int u = 0; u < 12; ++u) {
        int idx = u * 256 + tid;                  // 3072 float4
        int ci = idx >> 4, p4 = (idx & 15) << 2;
        float4 v = *(const float4*)(xb + (size_t)ci * TOKPB + pix0 + p4);
        float vv[4] = { v.x, v.y, v.z, v.w };
        #pragma unroll
        for (int k = 0; k < 4; ++k) {
            int row = p4 + k;
            int ba = (row * 384 + ci * 2) ^ ((row & 7) << 4);
            *(short*)((char*)xs2 + ba) = (short)f2bf(vv[k]);
        }
    }
    __syncthreads();

    const int ctb = wid * 3;
    f32x4 acc[3][4] = {};
    const s8v* wf8 = (const s8v*)w3f;

    #pragma unroll
    for (int kt = 0; kt < 6; ++kt) {
        s8v a0 = wf8[(size_t)(kt * 12 + ctb + 0) * 64 + lane];
        s8v a1 = wf8[(size_t)(kt * 12 + ctb + 1) * 64 + lane];
        s8v a2 = wf8[(size_t)(kt * 12 + ctb + 2) * 64 + lane];
        #pragma unroll
        for (int pt = 0; pt < 4; ++pt) {
            int row = pt * 16 + cl;
            int ba = (row * 384 + kt * 64 + kg * 16) ^ ((row & 7) << 4);
            s8v bfr = *(const s8v*)((const char*)xs2 + ba);
            acc[0][pt] = __builtin_amdgcn_mfma_f32_16x16x32_bf16(a0, bfr, acc[0][pt], 0, 0, 0);
            acc[1][pt] = __builtin_amdgcn_mfma_f32_16x16x32_bf16(a1, bfr, acc[1][pt], 0, 0, 0);
            acc[2][pt] = __builtin_amdgcn_mfma_f32_16x16x32_bf16(a2, bfr, acc[2][pt], 0, 0, 0);
        }
    }

    #pragma unroll
    for (int t = 0; t < 3; ++t) {
        #pragma unroll
        for (int r = 0; r < 4; ++r) {
            const int co = (ctb + t) * 16 + kg * 4 + r;
            const float bb = b3[co];
            const size_t rowbase = (size_t)b * (192 * TOKPB) + (size_t)co * TOKPB + pix0;
            #pragma unroll
            for (int pt = 0; pt < 4; ++pt) {
                const size_t f = rowbase + pt * 16 + cl;
                float v = acc[t][pt][r] + bb + bf2f(__builtin_bit_cast(short, c2[f]));
                out[f] = fmaxf(v, 0.f);
            }
        }
    }
}

// ---------------- host launch ----------------
extern "C" void kernel_launch(void* const* d_in, const int* in_sizes, int n_in,
                              void* d_out, int out_size, void* d_ws, size_t ws_size,
                              hipStream_t stream)
{
    if (ws_size < WS_NEEDED) return;

    const float* x       = (const float*)d_in[0];
    const float* conv1_w = (const float*)d_in[1];
    const float* conv1_b = (const float*)d_in[2];
    const float* gn1_g   = (const float*)d_in[3];
    const float* gn1_b   = (const float*)d_in[4];
    const float* conv2_w = (const float*)d_in[5];
    const float* conv2_b = (const float*)d_in[6];
    const float* gn2_g   = (const float*)d_in[7];
    const float* gn2_b   = (const float*)d_in[8];
    const float* conv3_w = (const float*)d_in[9];
    const float* conv3_b = (const float*)d_in[10];
    const float* ln1_g   = (const float*)d_in[11];
    const float* ln1_b   = (const float*)d_in[12];
    const float* qkv_w   = (const float*)d_in[13];
    const float* qkv_b   = (const float*)d_in[14];
    const float* rpb     = (const float*)d_in[15];
    const float* proj_w  = (const float*)d_in[16];
    const float* proj_b  = (const float*)d_in[17];
    const float* ln2_g   = (const float*)d_in[18];
    const float* ln2_b   = (const float*)d_in[19];
    const float* fc1_w   = (const float*)d_in[20];
    const float* fc1_b   = (const float*)d_in[21];
    const float* fc2_w   = (const float*)d_in[22];
    const float* fc2_b   = (const float*)d_in[23];

    char* wsb = (char*)d_ws;
    bf16*  T0  = (bf16*)(wsb + B_T0);
    _Float16* QF = (_Float16*)(wsb + B_P2);   // Q/K/V f16 sections; later HID bf16
    bf16*  HID = (bf16*)(wsb + B_P2);
    bf16*  P3  = (bf16*)(wsb + B_P3);
    bf16*  P4  = (bf16*)(wsb + B_P4);
    short* WF1 = (short*)(wsb + B_WF1);
    short* WF2 = (short*)(wsb + B_WF2);
    short* W3F = (short*)(wsb + B_W3F);
    short* WQ  = (short*)(wsb + B_WQ);
    short* WP  = (short*)(wsb + B_WP);
    short* WG1 = (short*)(wsb + B_WG1);
    short* WG2 = (short*)(wsb + B_WG2);
    float* OUT = (float*)d_out;

    // fused weight prep (single launch)
    prep_all_kernel<<<(PREP_TOTAL + 255) / 256, 256, 0, stream>>>(
        conv1_w, WF1, conv2_w, WF2, conv3_w, W3F, qkv_w, WQ, proj_w, WP, fc1_w, WG1, fc2_w, WG2);

    // stage A: conv1 + gn1 + silu -> T0 (token layout, bf16)
    conv_mfma_kernel<true><<<NPATCH / 4, 256, 0, stream>>>(x, WF1, conv1_b, gn1_g, gn1_b, T0);
    // stage C: LN1 (fused, once) + qkv gemm -> QF/KF/VF (f16 head-major)
    gemm_mfma_kernel<false, false, true, true, 6><<<dim3(MTOK / 128, 1), 256, 0, stream>>>(
        T0, WQ, qkv_b, nullptr, QF, 576, ln1_g, ln1_b);
    // stage D+E: attention + proj + shortcut(T0) -> P4 (OMID); 192 threads, pair-split keys
    attn_proj_kernel<<<NPATCH, 192, 0, stream>>>(QF, rpb, WP, proj_b, T0, P4);
    // stage G: LN2 (fused) + fc1 + gelu -> HID
    gemm_mfma_kernel<false, true, true, false, 6><<<dim3(MTOK / 128, 1), 256, 0, stream>>>(
        P4, WG1, fc1_b, nullptr, HID, 384, ln2_g, ln2_b);
    // stage H: fc2 + residual(OMID P4) -> P3 (OCAB, bf16 token layout)
    gemm_mfma_kernel<true, false, false, false, 12><<<dim3(MTOK / 128, 1), 256, 0, stream>>>(
        HID, WG2, fc2_b, P4, P3, 192, nullptr, nullptr);
    // stage I: conv2 + gn2 (reads P3) -> P4 (C2, bf16 patch-flat); OMID already consumed
    conv_mfma_kernel<false><<<NPATCH / 4, 256, 0, stream>>>(P3, WF2, conv2_b, gn2_g, gn2_b, P4);
    // stage J: out = relu(C2 + conv1x1(x)) -> d_out, MFMA
    final_mfma_kernel<<<dim3(TOKPB / 64, CB), 256, 0, stream>>>(x, W3F, conv3_b, P4, OUT);
}